// Round 1
// 501.741 us; speedup vs baseline: 1.1466x; 1.1466x over previous
//
#include <hip/hip_runtime.h>

using u16 = unsigned short;
using short8 = __attribute__((ext_vector_type(8))) short;
using f32x4 = __attribute__((ext_vector_type(4))) float;

struct alignas(8) U16x4 { u16 x, y, z, w; };

__device__ __forceinline__ float bf2f(u16 u) {
  return __uint_as_float(((unsigned int)u) << 16);
}
__device__ __forceinline__ u16 f2bf(float f) {
  unsigned int u = __float_as_uint(f);
  unsigned int r = u + 0x7FFFu + ((u >> 16) & 1u);
  return (u16)(r >> 16);
}

// ---------------- K0a: transpose pam_v_w [c][ci] -> wvT [ci][c] --------------
__global__ void k_prep_wv(const float* __restrict__ wv, float* __restrict__ wvT) {
  int idx = blockIdx.x * 256 + threadIdx.x;   // 16384
  int ci = idx >> 7, c = idx & 127;
  wvT[ci * 128 + c] = wv[c * 128 + ci];
}

// ---------------- K0b: conv weights -> bf16, MFMA-fragment order -------------
// Layout: [br][mt(8)][chunk(4)][tap(9)][ks(4)][lane(64)][j(8)]
// A-frag for 16x16x32 bf16: row(co) = lane&15, k = (lane>>4)*8 + j
__global__ void k_prep_w(const float* __restrict__ wa, const float* __restrict__ wc,
                         u16* __restrict__ Wb) {
  int idx = blockIdx.x * 256 + threadIdx.x;   // 2*8*4*9*4*64*8 = 1179648
  int j = idx & 7;
  int l = (idx >> 3) & 63;
  int ks = (idx >> 9) & 3;
  int rest = idx >> 11;          // 0..575
  int tap = rest % 9;
  int rest2 = rest / 9;          // 0..63
  int chunk = rest2 & 3;
  int mt = (rest2 >> 2) & 7;
  int br = rest2 >> 5;
  int co = mt * 16 + (l & 15);
  int ci = chunk * 128 + ks * 32 + (l >> 4) * 8 + j;
  const float* w = br ? wc : wa;
  Wb[idx] = f2bf(w[co * 4608 + ci * 9 + tap]);
}

// ---------------- K1: BN+ReLU both branches, NHWC bf16 out -------------------
// out layout: [b][h][w][c]  (c innermost, 512)
__global__ __launch_bounds__(256) void k_bnrelu2t(const float* __restrict__ x,
    const float* __restrict__ wa, const float* __restrict__ ba,
    const float* __restrict__ ma, const float* __restrict__ va,
    const float* __restrict__ wc, const float* __restrict__ bc,
    const float* __restrict__ mc, const float* __restrict__ vc,
    u16* __restrict__ xa16, u16* __restrict__ xcb16) {
  __shared__ float sA[512], bA[512], sC[512], bC[512];
  __shared__ u16 ta[64 * 136], tc[64 * 136];
  int t = threadIdx.x;
  int h = blockIdx.x, b = blockIdx.y;
  for (int c = t; c < 512; c += 256) {
    float s1 = wa[c] * rsqrtf(va[c] + 1e-5f);
    sA[c] = s1; bA[c] = ba[c] - ma[c] * s1;
    float s2 = wc[c] * rsqrtf(vc[c] + 1e-5f);
    sC[c] = s2; bC[c] = bc[c] - mc[c] * s2;
  }
  __syncthreads();
  const float* xb = x + ((size_t)b << 21) + (h << 6);          // + c*4096 + w
  u16* oa = xa16 + ((size_t)b << 21) + ((size_t)h << 15);      // + w*512 + c
  u16* oc = xcb16 + ((size_t)b << 21) + ((size_t)h << 15);
  int w = t & 63, cg = t >> 6;
  for (int c0 = 0; c0 < 512; c0 += 128) {
#pragma unroll
    for (int i = 0; i < 8; ++i) {
      int cl = cg * 4 + i * 16;       // 0..124, step covers 128 with 4 waves
      int c = c0 + cl;
      const float* xp = xb + (size_t)c * 4096 + w;
      float v0 = xp[0], v1 = xp[4096], v2 = xp[8192], v3 = xp[12288];
      U16x4 pa, pc;
      pa.x = f2bf(fmaxf(fmaf(v0, sA[c], bA[c]), 0.f));
      pa.y = f2bf(fmaxf(fmaf(v1, sA[c + 1], bA[c + 1]), 0.f));
      pa.z = f2bf(fmaxf(fmaf(v2, sA[c + 2], bA[c + 2]), 0.f));
      pa.w = f2bf(fmaxf(fmaf(v3, sA[c + 3], bA[c + 3]), 0.f));
      pc.x = f2bf(fmaxf(fmaf(v0, sC[c], bC[c]), 0.f));
      pc.y = f2bf(fmaxf(fmaf(v1, sC[c + 1], bC[c + 1]), 0.f));
      pc.z = f2bf(fmaxf(fmaf(v2, sC[c + 2], bC[c + 2]), 0.f));
      pc.w = f2bf(fmaxf(fmaf(v3, sC[c + 3], bC[c + 3]), 0.f));
      *(U16x4*)(ta + w * 136 + cl) = pa;
      *(U16x4*)(tc + w * 136 + cl) = pc;
    }
    __syncthreads();
#pragma unroll
    for (int i = 0; i < 4; ++i) {
      int idx = t + i * 256;          // 0..1023
      int ww = idx >> 4, c8 = (idx & 15) << 3;
      *(short8*)(oa + (size_t)ww * 512 + c0 + c8) = *(const short8*)(ta + ww * 136 + c8);
      *(short8*)(oc + (size_t)ww * 512 + c0 + c8) = *(const short8*)(tc + ww * 136 + c8);
    }
    __syncthreads();
  }
}

// ---------------- K2: 3x3 conv, implicit GEMM, NHWC input --------------------
// Block: one output row h, all 128 co, one (b,br). 4 waves: wave w -> co [32w,32w+32).
// LDS: 3 input rows (h-1,h,h+1), zero-padded w in [-1,64], [3][66][136] u16.
// K-loop: 4 ci-chunks of 128; per chunk: stage (2 barriers), 9 taps x 4 ksteps,
// per wave per kstep: 2 A-frag global loads (pre-packed, coalesced 1KB) +
// 4 B-frag ds_read_b128 + 8 MFMA.
__global__ __launch_bounds__(256) void k_conv3n(
    const u16* __restrict__ xa16, const u16* __restrict__ xcb16,
    const u16* __restrict__ Wb,
    float* __restrict__ sa0, float* __restrict__ sc0) {
  __shared__ u16 xs[3 * 66 * 136];
  int t = threadIdx.x;
  int h = blockIdx.x;
  int z = blockIdx.y; int b = z & 1, br = z >> 1;
  const u16* xb = (br ? xcb16 : xa16) + ((size_t)b << 21);     // NHWC
  const u16* wb = Wb + (size_t)br * 589824;
  float* out = (br ? sc0 : sa0) + (((size_t)b * 128) << 12) + (h << 6);

  int lane = t & 63, wave = t >> 6;
  int mi = lane & 15, quad = lane >> 4;

  // zero the two pad columns (w=-1 -> 0, w=64 -> 65) of each dh plane, once
  if (t < 96) {
    int dh = t >> 5, side = (t >> 4) & 1, c8 = t & 15;
    short8 z8 = {0, 0, 0, 0, 0, 0, 0, 0};
    *(short8*)(xs + (dh * 66 + side * 65) * 136 + c8 * 8) = z8;
  }

  f32x4 acc[2][4] = {};

  const u16* wlane = wb + lane * 8;
  const u16* bbase0 = xs + mi * 136 + quad * 8;

  for (int chunk = 0; chunk < 4; ++chunk) {
    int ci0 = chunk << 7;
    __syncthreads();   // previous chunk's readers done (also orders pad zeros)
    // stage 3 rows: [dh][w+1][cl], coalesced short8 global loads
#pragma unroll
    for (int dh = 0; dh < 3; ++dh) {
      int hh = h + dh - 1;
      bool val = (hh >= 0) && (hh < 64);
      const u16* src = xb + (((size_t)hh << 6) << 9) + ci0;
#pragma unroll
      for (int i = 0; i < 4; ++i) {
        int idx = t + i * 256;          // 0..1023
        int w = idx >> 4, c8 = (idx & 15) << 3;
        short8 v = {0, 0, 0, 0, 0, 0, 0, 0};
        if (val) v = *(const short8*)(src + ((size_t)w << 9) + c8);
        *(short8*)(xs + (dh * 66 + 1 + w) * 136 + c8) = v;
      }
    }
    __syncthreads();
    // compute: 9 taps x 4 ksteps, acc += W^T X
    const u16* wchunk = wlane + (size_t)(wave * 2 * 4 + chunk) * 36 * 512;
#pragma unroll
    for (int tap = 0; tap < 9; ++tap) {
      const int dh = tap / 3, dw = tap % 3;
      const u16* bp = bbase0 + (dh * 66 + dw) * 136;
      const u16* wt0 = wchunk + tap * 2048;
      const u16* wt1 = wt0 + 73728;     // next M-tile: +4*36*512
#pragma unroll
      for (int ks = 0; ks < 4; ++ks) {
        short8 a0 = *(const short8*)(wt0 + ks * 512);
        short8 a1 = *(const short8*)(wt1 + ks * 512);
#pragma unroll
        for (int nt = 0; nt < 4; ++nt) {
          short8 bf = *(const short8*)(bp + nt * 2176 + ks * 32);
          acc[0][nt] = __builtin_amdgcn_mfma_f32_16x16x32_bf16(a0, bf, acc[0][nt], 0, 0, 0);
          acc[1][nt] = __builtin_amdgcn_mfma_f32_16x16x32_bf16(a1, bf, acc[1][nt], 0, 0, 0);
        }
      }
    }
  }
  // D layout: col(n) = lane&15, row(co) = quad*4 + r
#pragma unroll
  for (int m = 0; m < 2; ++m)
#pragma unroll
    for (int nt = 0; nt < 4; ++nt)
#pragma unroll
      for (int r = 0; r < 4; ++r) {
        int co = wave * 32 + m * 16 + quad * 4 + r;
        out[((size_t)co << 12) + nt * 16 + mi] = acc[m][nt][r];
      }
}

// ---------------- K3a: 1x1 conv -> q,k ([b][16][4096] f32) -------------------
__global__ void k_qk(const float* __restrict__ sa0,
    const float* __restrict__ wq, const float* __restrict__ bq,
    const float* __restrict__ wk, const float* __restrict__ bk,
    float* __restrict__ qb, float* __restrict__ kb) {
  int n = blockIdx.x * 256 + threadIdx.x;
  int co = blockIdx.y, b = blockIdx.z;
  const float* w; float* dst; float bias;
  if (co < 16) { w = wq + co * 128; bias = bq[co]; dst = qb + ((b * 16 + co) << 12); }
  else { int c2 = co - 16; w = wk + c2 * 128; bias = bk[c2]; dst = kb + ((b * 16 + c2) << 12); }
  const float* s = sa0 + ((size_t)b * 128 << 12) + n;
  float acc = bias;
  for (int ci = 0; ci < 128; ++ci) acc = fmaf(w[ci], s[ci << 12], acc);
  dst[n] = acc;
}

// ---------------- K3b: 1x1 conv -> v, bf16, layout vt16[b][c][n] -------------
__global__ __launch_bounds__(256) void k_vt(const float* __restrict__ sa0,
    const float* __restrict__ wvT, const float* __restrict__ bv,
    u16* __restrict__ vt16) {
  int t = threadIdx.x;
  int n = blockIdx.x * 256 + t;
  int c0 = blockIdx.y * 8;
  int b = blockIdx.z;
  const float* s = sa0 + ((size_t)b * 128 << 12) + n;
  float acc[8];
#pragma unroll
  for (int c = 0; c < 8; ++c) acc[c] = bv[c0 + c];
  for (int ci = 0; ci < 128; ++ci) {
    float xv = s[ci << 12];
    const float* wp = wvT + ci * 128 + c0;
#pragma unroll
    for (int c = 0; c < 8; ++c) acc[c] = fmaf(wp[c], xv, acc[c]);
  }
#pragma unroll
  for (int c = 0; c < 8; ++c)
    vt16[((size_t)(b * 128 + c0 + c) << 12) + n] = f2bf(acc[c]);
}

// ---------------- K4: PAM softmax row stats (max, 1/sum), float4 K loads -----
__global__ __launch_bounds__(256) void k_pam_stats(const float* __restrict__ qb,
    const float* __restrict__ kb, float* __restrict__ rmax, float* __restrict__ rinv) {
  int t = threadIdx.x, lane = t & 63, wid = t >> 6;
  int b = blockIdx.y;
  int n = blockIdx.x * 4 + wid;
  float qreg[16];
  const float* qp = qb + ((size_t)b * 16 << 12) + n;
#pragma unroll
  for (int ch = 0; ch < 16; ++ch) qreg[ch] = qp[ch << 12];
  const float* kp = kb + ((size_t)b * 16 << 12);
  float mx = -1e30f, se = 0.f;
  for (int m4 = lane * 4; m4 < 4096; m4 += 256) {
    float e0 = 0.f, e1 = 0.f, e2 = 0.f, e3 = 0.f;
#pragma unroll
    for (int ch = 0; ch < 16; ++ch) {
      float4 kv = *(const float4*)(kp + (ch << 12) + m4);
      float qv = qreg[ch];
      e0 = fmaf(qv, kv.x, e0); e1 = fmaf(qv, kv.y, e1);
      e2 = fmaf(qv, kv.z, e2); e3 = fmaf(qv, kv.w, e3);
    }
#pragma unroll
    for (int j = 0; j < 4; ++j) {
      float e = j == 0 ? e0 : (j == 1 ? e1 : (j == 2 ? e2 : e3));
      float nm = fmaxf(mx, e);
      se = se * __expf(mx - nm) + __expf(e - nm);
      mx = nm;
    }
  }
#pragma unroll
  for (int off = 32; off >= 1; off >>= 1) {
    float om = __shfl_xor(mx, off);
    float os = __shfl_xor(se, off);
    float nm = fmaxf(mx, om);
    se = se * __expf(mx - nm) + os * __expf(om - nm);
    mx = nm;
  }
  if (lane == 0) { rmax[(b << 12) + n] = mx; rinv[(b << 12) + n] = 1.f / se; }
}

// ---------------- K5: PAM PV via MFMA, 16-n tile, split-m 2-way --------------
__global__ __launch_bounds__(256) void k_pam_pv(const float* __restrict__ qb,
    const float* __restrict__ kb, const u16* __restrict__ vt16,
    const float* __restrict__ rmax, const float* __restrict__ rinv,
    const float* __restrict__ gamma, float* __restrict__ sa1) {
  __shared__ float qs[256];
  __shared__ float ks[1024];
  __shared__ u16 pL[16 * 72];
  __shared__ float mxs[16], invs[16];
  __shared__ float obuf[128 * 17];
  int t = threadIdx.x;
  int b = blockIdx.y, n0 = blockIdx.x * 16;
  int mbeg = blockIdx.z * 2048, mend = mbeg + 2048;
  {
    int ch = t >> 4, r = t & 15;
    qs[t] = qb[((b * 16 + ch) << 12) + n0 + r];
  }
  if (t < 16) { mxs[t] = rmax[(b << 12) + n0 + t]; invs[t] = rinv[(b << 12) + n0 + t]; }
  int lane = t & 63, wave = t >> 6;
  int mi = lane & 15, quad = lane >> 4;
  int c0 = wave * 32;
  f32x4 acc0 = {0.f, 0.f, 0.f, 0.f};
  f32x4 acc1 = {0.f, 0.f, 0.f, 0.f};
  const float* kpb = kb + ((size_t)b * 16 << 12);
  const u16* vb = vt16 + ((size_t)b * 128 << 12);
  for (int idx = t; idx < 1024; idx += 256) {
    int ch = idx >> 6, mm = idx & 63;
    ks[idx] = kpb[(ch << 12) + mbeg + mm];
  }
  __syncthreads();
  int pn = t & 15, pmq = t >> 4;
  for (int m0 = mbeg; m0 < mend; m0 += 64) {
    {
      float e0 = 0.f, e1 = 0.f, e2 = 0.f, e3 = 0.f;
#pragma unroll
      for (int ch = 0; ch < 16; ++ch) {
        float4 kv = *(const float4*)(ks + (ch << 6) + pmq * 4);
        float qv = qs[(ch << 4) + pn];
        e0 = fmaf(qv, kv.x, e0); e1 = fmaf(qv, kv.y, e1);
        e2 = fmaf(qv, kv.z, e2); e3 = fmaf(qv, kv.w, e3);
      }
      float mv = mxs[pn], iv = invs[pn];
      U16x4 pv4;
      pv4.x = f2bf(__expf(fminf(e0 - mv, 0.f)) * iv);
      pv4.y = f2bf(__expf(fminf(e1 - mv, 0.f)) * iv);
      pv4.z = f2bf(__expf(fminf(e2 - mv, 0.f)) * iv);
      pv4.w = f2bf(__expf(fminf(e3 - mv, 0.f)) * iv);
      *(U16x4*)(pL + pn * 72 + pmq * 4) = pv4;
    }
    __syncthreads();
    if (m0 + 64 < mend) {
      int m1 = m0 + 64;
      for (int idx = t; idx < 1024; idx += 256) {
        int ch = idx >> 6, mm = idx & 63;
        ks[idx] = kpb[(ch << 12) + m1 + mm];
      }
    }
#pragma unroll
    for (int kk = 0; kk < 64; kk += 32) {
      short8 bfrag = *(const short8*)(pL + mi * 72 + kk + quad * 8);
      const u16* ap = vb + ((size_t)(c0 + mi) << 12) + m0 + kk + quad * 8;
      short8 a0 = *(const short8*)ap;
      short8 a1 = *(const short8*)(ap + ((size_t)16 << 12));
      acc0 = __builtin_amdgcn_mfma_f32_16x16x32_bf16(a0, bfrag, acc0, 0, 0, 0);
      acc1 = __builtin_amdgcn_mfma_f32_16x16x32_bf16(a1, bfrag, acc1, 0, 0, 0);
    }
    __syncthreads();
  }
#pragma unroll
  for (int r = 0; r < 4; ++r) {
    obuf[(c0 + quad * 4 + r) * 17 + mi] = acc0[r];
    obuf[(c0 + 16 + quad * 4 + r) * 17 + mi] = acc1[r];
  }
  __syncthreads();
  float g = gamma[0];
  for (int idx = t; idx < 2048; idx += 256) {
    int c = idx >> 4, nn = idx & 15;
    size_t o = ((size_t)(b * 128 + c) << 12) + n0 + nn;
    atomicAdd(&sa1[o], g * obuf[c * 17 + nn]);
  }
}

// ---------------- K6a: CAM Gram energy, block per row c, all threads ---------
__global__ __launch_bounds__(256) void k_cam_energy(const float* __restrict__ f,
                                                    float* __restrict__ energy) {
  __shared__ float fc[4096];
  __shared__ float part[256];
  int t = threadIdx.x;
  int c = blockIdx.x, b = blockIdx.y;
  const float* fr = f + ((size_t)(b * 128 + c) << 12);
  for (int i = t; i < 4096; i += 256) fc[i] = fr[i];
  __syncthreads();
  int d = t & 127, seg = t >> 7;
  const float* fd = f + ((size_t)(b * 128 + d) << 12) + seg * 2048;
  const float* fcs = fc + seg * 2048;
  float acc = 0.f;
  for (int nn = 0; nn < 2048; ++nn) acc = fmaf(fcs[nn], fd[nn], acc);
  part[t] = acc;
  __syncthreads();
  if (t < 128)
    energy[((b * 128 + c) << 7) + t] = part[t] + part[t + 128];
}

// ---------------- K6b: CAM softmax row (attn = softmax(rowmax - e)) ----------
__global__ void k_cam_softmax(const float* __restrict__ energy, float* __restrict__ attn) {
  int lane = threadIdx.x;
  int c = blockIdx.x, b = blockIdx.y;
  const float* e = energy + ((b * 128 + c) << 7);
  float e0 = e[lane], e1 = e[lane + 64];
  float mn = fminf(e0, e1);
#pragma unroll
  for (int off = 32; off >= 1; off >>= 1) mn = fminf(mn, __shfl_xor(mn, off));
  float p0 = __expf(fminf(mn - e0, 0.f)), p1 = __expf(fminf(mn - e1, 0.f));
  float s = p0 + p1;
#pragma unroll
  for (int off = 32; off >= 1; off >>= 1) s += __shfl_xor(s, off);
  float inv = 1.f / s;
  float* a = attn + ((b * 128 + c) << 7);
  a[lane] = p0 * inv;
  a[lane + 64] = p1 * inv;
}

// ---------------- K7: CAM out + residual -------------------------------------
__global__ __launch_bounds__(256) void k_cam_out(const float* __restrict__ f,
    const float* __restrict__ attn, const float* __restrict__ gamma,
    float* __restrict__ sc1) {
  __shared__ float at2[128 * 16];
  int t = threadIdx.x;
  int b = blockIdx.z, c0 = blockIdx.y * 16;
  int n = blockIdx.x * 256 + t;
  for (int idx = t; idx < 2048; idx += 256) {
    int d = idx >> 4, cc = idx & 15;
    at2[idx] = attn[((b * 128 + c0 + cc) << 7) + d];
  }
  __syncthreads();
  float acc[16] = {};
  const float* fb = f + ((size_t)b * 128 << 12) + n;
  for (int d = 0; d < 128; ++d) {
    float fv = fb[d << 12];
    const float* ap = at2 + d * 16;
#pragma unroll
    for (int cc = 0; cc < 16; ++cc) acc[cc] = fmaf(ap[cc], fv, acc[cc]);
  }
  float g = gamma[0];
#pragma unroll
  for (int cc = 0; cc < 16; ++cc) {
    size_t o = ((size_t)(b * 128 + c0 + cc) << 12) + n;
    sc1[o] = fmaf(g, acc[cc], f[o]);
  }
}

// ---------------- K8: BN+ReLU + 1x1 conv 128->512, 16 co per block -----------
__global__ __launch_bounds__(256) void k_branch_out(
    const float* __restrict__ sa1, const float* __restrict__ sc1,
    const float* __restrict__ wa_, const float* __restrict__ ba_,
    const float* __restrict__ ma_, const float* __restrict__ va_,
    const float* __restrict__ wc_, const float* __restrict__ bc_,
    const float* __restrict__ mc_, const float* __restrict__ vc_,
    const float* __restrict__ Wa, const float* __restrict__ Ba,
    const float* __restrict__ Wc, const float* __restrict__ Bc,
    u16* __restrict__ sa2, u16* __restrict__ sc2) {
  int z = blockIdx.z;
  int b = z & 1, br = z >> 1;
  const float* src = br ? sc1 : sa1;
  const float* bw = br ? wc_ : wa_;
  const float* bb = br ? bc_ : ba_;
  const float* bm = br ? mc_ : ma_;
  const float* bvv = br ? vc_ : va_;
  const float* W = br ? Wc : Wa;
  const float* Bs = br ? Bc : Ba;
  u16* dst = br ? sc2 : sa2;
  __shared__ float wl[128 * 16];
  __shared__ float scl[128], shf[128];
  int t = threadIdx.x;
  int co0 = blockIdx.y * 16;
  int n = blockIdx.x * 256 + t;
  if (t < 128) {
    float s = bw[t] * rsqrtf(bvv[t] + 1e-5f);
    scl[t] = s;
    shf[t] = bb[t] - bm[t] * s;
  }
  for (int idx = t; idx < 2048; idx += 256) {
    int ci = idx >> 4, cc = idx & 15;
    wl[idx] = W[(co0 + cc) * 128 + ci];
  }
  __syncthreads();
  float acc[16] = {};
  const float* sp = src + ((size_t)b * 128 << 12) + n;
  for (int ci = 0; ci < 128; ++ci) {
    float xv = fmaxf(fmaf(sp[ci << 12], scl[ci], shf[ci]), 0.f);
    const float* wp = wl + ci * 16;
    float4 w0 = *(const float4*)wp;
    float4 w1 = *(const float4*)(wp + 4);
    float4 w2 = *(const float4*)(wp + 8);
    float4 w3 = *(const float4*)(wp + 12);
    acc[0] = fmaf(w0.x, xv, acc[0]);  acc[1] = fmaf(w0.y, xv, acc[1]);
    acc[2] = fmaf(w0.z, xv, acc[2]);  acc[3] = fmaf(w0.w, xv, acc[3]);
    acc[4] = fmaf(w1.x, xv, acc[4]);  acc[5] = fmaf(w1.y, xv, acc[5]);
    acc[6] = fmaf(w1.z, xv, acc[6]);  acc[7] = fmaf(w1.w, xv, acc[7]);
    acc[8] = fmaf(w2.x, xv, acc[8]);  acc[9] = fmaf(w2.y, xv, acc[9]);
    acc[10] = fmaf(w2.z, xv, acc[10]); acc[11] = fmaf(w2.w, xv, acc[11]);
    acc[12] = fmaf(w3.x, xv, acc[12]); acc[13] = fmaf(w3.y, xv, acc[13]);
    acc[14] = fmaf(w3.z, xv, acc[14]); acc[15] = fmaf(w3.w, xv, acc[15]);
  }
#pragma unroll
  for (int cc = 0; cc < 16; ++cc) {
    dst[((size_t)(b * 512 + co0 + cc) << 12) + n] = f2bf(acc[cc] + Bs[co0 + cc]);
  }
}

// ---------------- K9a: fusion + partial class-head sums (8-way c split) ------
__global__ __launch_bounds__(256) void k_heads(const u16* __restrict__ sa2,
    const u16* __restrict__ sc2,
    const float* __restrict__ wf, const float* __restrict__ wa, const float* __restrict__ wc,
    float* __restrict__ outFusion, float* __restrict__ clsacc) {
  __shared__ float lw[3 * 5 * 64];
  int t = threadIdx.x;
  int b = blockIdx.y, co0 = blockIdx.z * 64;
  int n = blockIdx.x * 256 + t;
  for (int idx = t; idx < 960; idx += 256) {
    int arr = idx / 320, rest = idx - arr * 320;
    int cls = rest >> 6, cc = rest & 63;
    const float* w = arr == 0 ? wf : (arr == 1 ? wa : wc);
    lw[idx] = w[cls * 512 + co0 + cc];
  }
  __syncthreads();
  float af[5] = {}, aa[5] = {}, ac[5] = {};
  for (int cc = 0; cc < 64; ++cc) {
    size_t o = ((size_t)(b * 512 + co0 + cc) << 12) + n;
    float a = bf2f(sa2[o]), c = bf2f(sc2[o]);
    float s = a + c;
    outFusion[o] = s;
#pragma unroll
    for (int cls = 0; cls < 5; ++cls) {
      af[cls] = fmaf(lw[0 * 320 + cls * 64 + cc], s, af[cls]);
      aa[cls] = fmaf(lw[1 * 320 + cls * 64 + cc], a, aa[cls]);
      ac[cls] = fmaf(lw[2 * 320 + cls * 64 + cc], c, ac[cls]);
    }
  }
#pragma unroll
  for (int cls = 0; cls < 5; ++cls) {
    int o = ((b * 5 + cls) << 12) + n;
    atomicAdd(&clsacc[o], af[cls]);
    atomicAdd(&clsacc[40960 + o], aa[cls]);
    atomicAdd(&clsacc[81920 + o], ac[cls]);
  }
}

// ---------------- K9b: add bias, f32 out -------------------------------------
__global__ void k_heads_final(const float* __restrict__ clsacc,
    const float* __restrict__ bf_, const float* __restrict__ ba_,
    const float* __restrict__ bc_, float* __restrict__ outCls) {
  int idx = blockIdx.x * 256 + threadIdx.x;   // 122880
  int arr = idx / 40960;
  int rest = idx - arr * 40960;
  int cls = (rest >> 12) % 5;
  const float* bp = arr == 0 ? bf_ : (arr == 1 ? ba_ : bc_);
  outCls[idx] = clsacc[idx] + bp[cls];
}

extern "C" void kernel_launch(void* const* d_in, const int* in_sizes, int n_in,
                              void* d_out, int out_size, void* d_ws, size_t ws_size,
                              hipStream_t stream) {
  (void)in_sizes; (void)n_in; (void)out_size; (void)ws_size;
  const float* x      = (const float*)d_in[0];
  const float* bnaw   = (const float*)d_in[1];
  const float* bnab   = (const float*)d_in[2];
  const float* bnam   = (const float*)d_in[3];
  const float* bnav   = (const float*)d_in[4];
  const float* convaw = (const float*)d_in[5];
  const float* bncw   = (const float*)d_in[6];
  const float* bncb   = (const float*)d_in[7];
  const float* bncm   = (const float*)d_in[8];
  const float* bncv   = (const float*)d_in[9];
  const float* convcw = (const float*)d_in[10];
  const float* pqw    = (const float*)d_in[11];
  const float* pqb    = (const float*)d_in[12];
  const float* pkw    = (const float*)d_in[13];
  const float* pkb    = (const float*)d_in[14];
  const float* pvw    = (const float*)d_in[15];
  const float* pvb    = (const float*)d_in[16];
  const float* pgam   = (const float*)d_in[17];
  const float* cgam   = (const float*)d_in[18];
  const float* bna1w  = (const float*)d_in[19];
  const float* bna1b  = (const float*)d_in[20];
  const float* bna1m  = (const float*)d_in[21];
  const float* bna1v  = (const float*)d_in[22];
  const float* conva1w = (const float*)d_in[23];
  const float* conva1b = (const float*)d_in[24];
  const float* bnc1w  = (const float*)d_in[25];
  const float* bnc1b  = (const float*)d_in[26];
  const float* bnc1m  = (const float*)d_in[27];
  const float* bnc1v  = (const float*)d_in[28];
  const float* convc1w = (const float*)d_in[29];
  const float* convc1b = (const float*)d_in[30];
  const float* outaw  = (const float*)d_in[31];
  const float* outab  = (const float*)d_in[32];
  const float* outcw  = (const float*)d_in[33];
  const float* outcb  = (const float*)d_in[34];
  const float* outfw  = (const float*)d_in[35];
  const float* outfb  = (const float*)d_in[36];

  char* wsb = (char*)d_ws;
  size_t off = 0;
  auto take = [&](size_t bytes) -> void* {
    void* p = wsb + off;
    off += (bytes + 255) & ~(size_t)255;
    return p;
  };
  float* wvT   = (float*)take((size_t)128 * 128 * 4);
  u16*   Wb    = (u16*)take((size_t)2 * 128 * 9 * 512 * 2);
  u16*   xa16  = (u16*)take((size_t)2 * 512 * 4096 * 2);
  u16*   xcb16 = (u16*)take((size_t)2 * 512 * 4096 * 2);
  float* sa0   = (float*)take((size_t)2 * 128 * 4096 * 4);
  float* sc0   = (float*)take((size_t)2 * 128 * 4096 * 4);
  float* qb    = (float*)take((size_t)2 * 16 * 4096 * 4);
  float* kbuf  = (float*)take((size_t)2 * 16 * 4096 * 4);
  u16*   vt16  = (u16*)take((size_t)2 * 128 * 4096 * 2);
  float* rmax  = (float*)take((size_t)2 * 4096 * 4);
  float* rinv  = (float*)take((size_t)2 * 4096 * 4);
  float* sa1   = (float*)take((size_t)2 * 128 * 4096 * 4);
  float* sc1   = (float*)take((size_t)2 * 128 * 4096 * 4);
  float* energy = (float*)take((size_t)2 * 128 * 128 * 4);
  float* attn  = (float*)take((size_t)2 * 128 * 128 * 4);
  u16*   sa2   = (u16*)take((size_t)2 * 512 * 4096 * 2);
  u16*   sc2   = (u16*)take((size_t)2 * 512 * 4096 * 2);
  float* clsacc = (float*)take((size_t)3 * 2 * 5 * 4096 * 4);

  float* outF = (float*)d_out;
  float* outCls = outF + (size_t)2 * 512 * 4096;

  hipMemsetAsync(clsacc, 0, (size_t)3 * 2 * 5 * 4096 * 4, stream);

  k_prep_wv<<<64, 256, 0, stream>>>(pvw, wvT);
  k_prep_w<<<4608, 256, 0, stream>>>(convaw, convcw, Wb);
  k_bnrelu2t<<<dim3(64, 2), 256, 0, stream>>>(x, bnaw, bnab, bnam, bnav,
                                              bncw, bncb, bncm, bncv, xa16, xcb16);
  k_conv3n<<<dim3(64, 4), 256, 0, stream>>>(xa16, xcb16, Wb, sa0, sc0);
  k_qk<<<dim3(16, 32, 2), 256, 0, stream>>>(sa0, pqw, pqb, pkw, pkb, qb, kbuf);
  k_vt<<<dim3(16, 16, 2), 256, 0, stream>>>(sa0, wvT, pvb, vt16);
  k_pam_stats<<<dim3(1024, 2), 256, 0, stream>>>(qb, kbuf, rmax, rinv);
  hipMemcpyAsync(sa1, sa0, (size_t)2 * 128 * 4096 * 4, hipMemcpyDeviceToDevice, stream);
  k_pam_pv<<<dim3(256, 2, 2), 256, 0, stream>>>(qb, kbuf, vt16, rmax, rinv, pgam, sa1);
  k_cam_energy<<<dim3(128, 2), 256, 0, stream>>>(sc0, energy);
  k_cam_softmax<<<dim3(128, 2), 64, 0, stream>>>(energy, attn);
  k_cam_out<<<dim3(16, 8, 2), 256, 0, stream>>>(sc0, attn, cgam, sc1);
  k_branch_out<<<dim3(16, 32, 4), 256, 0, stream>>>(sa1, sc1,
      bna1w, bna1b, bna1m, bna1v, bnc1w, bnc1b, bnc1m, bnc1v,
      conva1w, conva1b, convc1w, convc1b, sa2, sc2);
  k_heads<<<dim3(16, 2, 8), 256, 0, stream>>>(sa2, sc2, outfw, outaw, outcw, outF, clsacc);
  k_heads_final<<<480, 256, 0, stream>>>(clsacc, outfb, outab, outcb, outCls);
}

// Round 3
// 449.344 us; speedup vs baseline: 1.2803x; 1.1166x over previous
//
#include <hip/hip_runtime.h>

using u16 = unsigned short;
using short8 = __attribute__((ext_vector_type(8))) short;
using f32x4 = __attribute__((ext_vector_type(4))) float;

struct alignas(8) U16x4 { u16 x, y, z, w; };

__device__ __forceinline__ float bf2f(u16 u) {
  return __uint_as_float(((unsigned int)u) << 16);
}
__device__ __forceinline__ u16 f2bf(float f) {
  unsigned int u = __float_as_uint(f);
  unsigned int r = u + 0x7FFFu + ((u >> 16) & 1u);
  return (u16)(r >> 16);
}

// ---------------- K0a: transpose pam_v_w [c][ci] -> wvT [ci][c] --------------
__global__ void k_prep_wv(const float* __restrict__ wv, float* __restrict__ wvT) {
  int idx = blockIdx.x * 256 + threadIdx.x;   // 16384
  int ci = idx >> 7, c = idx & 127;
  wvT[ci * 128 + c] = wv[c * 128 + ci];
}

// ---------------- K0b: conv weights -> bf16, MFMA-fragment order -------------
// Layout: [br][mt(8)][chunk(4)][tap(9)][ks(4)][lane(64)][j(8)]
__global__ void k_prep_w(const float* __restrict__ wa, const float* __restrict__ wc,
                         u16* __restrict__ Wb) {
  int idx = blockIdx.x * 256 + threadIdx.x;   // 1179648
  int j = idx & 7;
  int l = (idx >> 3) & 63;
  int ks = (idx >> 9) & 3;
  int rest = idx >> 11;
  int tap = rest % 9;
  int rest2 = rest / 9;
  int chunk = rest2 & 3;
  int mt = (rest2 >> 2) & 7;
  int br = rest2 >> 5;
  int co = mt * 16 + (l & 15);
  int ci = chunk * 128 + ks * 32 + (l >> 4) * 8 + j;
  const float* w = br ? wc : wa;
  Wb[idx] = f2bf(w[co * 4608 + ci * 9 + tap]);
}

// ---------------- K1: BN+ReLU both branches, NHWC bf16 out -------------------
__global__ __launch_bounds__(256) void k_bnrelu2t(const float* __restrict__ x,
    const float* __restrict__ wa, const float* __restrict__ ba,
    const float* __restrict__ ma, const float* __restrict__ va,
    const float* __restrict__ wc, const float* __restrict__ bc,
    const float* __restrict__ mc, const float* __restrict__ vc,
    u16* __restrict__ xa16, u16* __restrict__ xcb16) {
  __shared__ float sA[512], bA[512], sC[512], bC[512];
  __shared__ u16 ta[64 * 136], tc[64 * 136];
  int t = threadIdx.x;
  int h = blockIdx.x, b = blockIdx.y;
  for (int c = t; c < 512; c += 256) {
    float s1 = wa[c] * rsqrtf(va[c] + 1e-5f);
    sA[c] = s1; bA[c] = ba[c] - ma[c] * s1;
    float s2 = wc[c] * rsqrtf(vc[c] + 1e-5f);
    sC[c] = s2; bC[c] = bc[c] - mc[c] * s2;
  }
  __syncthreads();
  const float* xb = x + ((size_t)b << 21) + (h << 6);
  u16* oa = xa16 + ((size_t)b << 21) + ((size_t)h << 15);
  u16* oc = xcb16 + ((size_t)b << 21) + ((size_t)h << 15);
  int w = t & 63, cg = t >> 6;
  for (int c0 = 0; c0 < 512; c0 += 128) {
#pragma unroll
    for (int i = 0; i < 8; ++i) {
      int cl = cg * 4 + i * 16;
      int c = c0 + cl;
      const float* xp = xb + (size_t)c * 4096 + w;
      float v0 = xp[0], v1 = xp[4096], v2 = xp[8192], v3 = xp[12288];
      U16x4 pa, pc;
      pa.x = f2bf(fmaxf(fmaf(v0, sA[c], bA[c]), 0.f));
      pa.y = f2bf(fmaxf(fmaf(v1, sA[c + 1], bA[c + 1]), 0.f));
      pa.z = f2bf(fmaxf(fmaf(v2, sA[c + 2], bA[c + 2]), 0.f));
      pa.w = f2bf(fmaxf(fmaf(v3, sA[c + 3], bA[c + 3]), 0.f));
      pc.x = f2bf(fmaxf(fmaf(v0, sC[c], bC[c]), 0.f));
      pc.y = f2bf(fmaxf(fmaf(v1, sC[c + 1], bC[c + 1]), 0.f));
      pc.z = f2bf(fmaxf(fmaf(v2, sC[c + 2], bC[c + 2]), 0.f));
      pc.w = f2bf(fmaxf(fmaf(v3, sC[c + 3], bC[c + 3]), 0.f));
      *(U16x4*)(ta + w * 136 + cl) = pa;
      *(U16x4*)(tc + w * 136 + cl) = pc;
    }
    __syncthreads();
#pragma unroll
    for (int i = 0; i < 4; ++i) {
      int idx = t + i * 256;
      int ww = idx >> 4, c8 = (idx & 15) << 3;
      *(short8*)(oa + (size_t)ww * 512 + c0 + c8) = *(const short8*)(ta + ww * 136 + c8);
      *(short8*)(oc + (size_t)ww * 512 + c0 + c8) = *(const short8*)(tc + ww * 136 + c8);
    }
    __syncthreads();
  }
}

// ---------------- K2: 3x3 conv, implicit GEMM, NHWC input --------------------
__global__ __launch_bounds__(256) void k_conv3n(
    const u16* __restrict__ xa16, const u16* __restrict__ xcb16,
    const u16* __restrict__ Wb,
    float* __restrict__ sa0, float* __restrict__ sc0) {
  __shared__ u16 xs[3 * 66 * 136];
  int t = threadIdx.x;
  int h = blockIdx.x;
  int z = blockIdx.y; int b = z & 1, br = z >> 1;
  const u16* xb = (br ? xcb16 : xa16) + ((size_t)b << 21);
  const u16* wb = Wb + (size_t)br * 589824;
  float* out = (br ? sc0 : sa0) + (((size_t)b * 128) << 12) + (h << 6);

  int lane = t & 63, wave = t >> 6;
  int mi = lane & 15, quad = lane >> 4;

  if (t < 96) {
    int dh = t >> 5, side = (t >> 4) & 1, c8 = t & 15;
    short8 z8 = {0, 0, 0, 0, 0, 0, 0, 0};
    *(short8*)(xs + (dh * 66 + side * 65) * 136 + c8 * 8) = z8;
  }

  f32x4 acc[2][4] = {};

  const u16* wlane = wb + lane * 8;
  const u16* bbase0 = xs + mi * 136 + quad * 8;

  for (int chunk = 0; chunk < 4; ++chunk) {
    int ci0 = chunk << 7;
    __syncthreads();
#pragma unroll
    for (int dh = 0; dh < 3; ++dh) {
      int hh = h + dh - 1;
      bool val = (hh >= 0) && (hh < 64);
      const u16* src = xb + (((size_t)hh << 6) << 9) + ci0;
#pragma unroll
      for (int i = 0; i < 4; ++i) {
        int idx = t + i * 256;
        int w = idx >> 4, c8 = (idx & 15) << 3;
        short8 v = {0, 0, 0, 0, 0, 0, 0, 0};
        if (val) v = *(const short8*)(src + ((size_t)w << 9) + c8);
        *(short8*)(xs + (dh * 66 + 1 + w) * 136 + c8) = v;
      }
    }
    __syncthreads();
    const u16* wchunk = wlane + (size_t)(wave * 2 * 4 + chunk) * 36 * 512;
#pragma unroll
    for (int tap = 0; tap < 9; ++tap) {
      const int dh = tap / 3, dw = tap % 3;
      const u16* bp = bbase0 + (dh * 66 + dw) * 136;
      const u16* wt0 = wchunk + tap * 2048;
      const u16* wt1 = wt0 + 73728;
#pragma unroll
      for (int ks = 0; ks < 4; ++ks) {
        short8 a0 = *(const short8*)(wt0 + ks * 512);
        short8 a1 = *(const short8*)(wt1 + ks * 512);
#pragma unroll
        for (int nt = 0; nt < 4; ++nt) {
          short8 bf = *(const short8*)(bp + nt * 2176 + ks * 32);
          acc[0][nt] = __builtin_amdgcn_mfma_f32_16x16x32_bf16(a0, bf, acc[0][nt], 0, 0, 0);
          acc[1][nt] = __builtin_amdgcn_mfma_f32_16x16x32_bf16(a1, bf, acc[1][nt], 0, 0, 0);
        }
      }
    }
  }
#pragma unroll
  for (int m = 0; m < 2; ++m)
#pragma unroll
    for (int nt = 0; nt < 4; ++nt)
#pragma unroll
      for (int r = 0; r < 4; ++r) {
        int co = wave * 32 + m * 16 + quad * 4 + r;
        out[((size_t)co << 12) + nt * 16 + mi] = acc[m][nt][r];
      }
}

// ---------------- K3a: 1x1 conv -> q,k ([b][16][4096] f32) -------------------
__global__ void k_qk(const float* __restrict__ sa0,
    const float* __restrict__ wq, const float* __restrict__ bq,
    const float* __restrict__ wk, const float* __restrict__ bk,
    float* __restrict__ qb, float* __restrict__ kb) {
  int n = blockIdx.x * 256 + threadIdx.x;
  int co = blockIdx.y, b = blockIdx.z;
  const float* w; float* dst; float bias;
  if (co < 16) { w = wq + co * 128; bias = bq[co]; dst = qb + ((b * 16 + co) << 12); }
  else { int c2 = co - 16; w = wk + c2 * 128; bias = bk[c2]; dst = kb + ((b * 16 + c2) << 12); }
  const float* s = sa0 + ((size_t)b * 128 << 12) + n;
  float acc = bias;
  for (int ci = 0; ci < 128; ++ci) acc = fmaf(w[ci], s[ci << 12], acc);
  dst[n] = acc;
}

// ---------------- K3b: 1x1 conv -> v, bf16, layout vt16[b][c][n] -------------
__global__ __launch_bounds__(256) void k_vt(const float* __restrict__ sa0,
    const float* __restrict__ wvT, const float* __restrict__ bv,
    u16* __restrict__ vt16) {
  int t = threadIdx.x;
  int n = blockIdx.x * 256 + t;
  int c0 = blockIdx.y * 8;
  int b = blockIdx.z;
  const float* s = sa0 + ((size_t)b * 128 << 12) + n;
  float acc[8];
#pragma unroll
  for (int c = 0; c < 8; ++c) acc[c] = bv[c0 + c];
  for (int ci = 0; ci < 128; ++ci) {
    float xv = s[ci << 12];
    const float* wp = wvT + ci * 128 + c0;
#pragma unroll
    for (int c = 0; c < 8; ++c) acc[c] = fmaf(wp[c], xv, acc[c]);
  }
#pragma unroll
  for (int c = 0; c < 8; ++c)
    vt16[((size_t)(b * 128 + c0 + c) << 12) + n] = f2bf(acc[c]);
}

// ---------------- K4: PAM softmax row stats; 4 n per lane, 16 n per block ----
__global__ __launch_bounds__(256) void k_pam_stats(const float* __restrict__ qb,
    const float* __restrict__ kb, float* __restrict__ rmax, float* __restrict__ rinv) {
  int t = threadIdx.x, lane = t & 63, wid = t >> 6;
  int b = blockIdx.y;
  int n0 = blockIdx.x * 16 + wid * 4;
  float qreg[4][16];
  const float* qp = qb + ((size_t)b * 16 << 12) + n0;
#pragma unroll
  for (int ch = 0; ch < 16; ++ch)
#pragma unroll
    for (int j = 0; j < 4; ++j) qreg[j][ch] = qp[(ch << 12) + j];
  const float* kp = kb + ((size_t)b * 16 << 12);
  float mx[4], se[4];
#pragma unroll
  for (int j = 0; j < 4; ++j) { mx[j] = -1e30f; se[j] = 0.f; }
  for (int m4 = lane * 4; m4 < 4096; m4 += 256) {
    float e[4][4] = {};
#pragma unroll
    for (int ch = 0; ch < 16; ++ch) {
      float4 kv = *(const float4*)(kp + (ch << 12) + m4);
#pragma unroll
      for (int j = 0; j < 4; ++j) {
        float qv = qreg[j][ch];
        e[j][0] = fmaf(qv, kv.x, e[j][0]);
        e[j][1] = fmaf(qv, kv.y, e[j][1]);
        e[j][2] = fmaf(qv, kv.z, e[j][2]);
        e[j][3] = fmaf(qv, kv.w, e[j][3]);
      }
    }
#pragma unroll
    for (int j = 0; j < 4; ++j) {
      float lm = fmaxf(fmaxf(e[j][0], e[j][1]), fmaxf(e[j][2], e[j][3]));
      float nm = fmaxf(mx[j], lm);
      se[j] = se[j] * __expf(mx[j] - nm)
            + __expf(e[j][0] - nm) + __expf(e[j][1] - nm)
            + __expf(e[j][2] - nm) + __expf(e[j][3] - nm);
      mx[j] = nm;
    }
  }
#pragma unroll
  for (int off = 32; off >= 1; off >>= 1) {
#pragma unroll
    for (int j = 0; j < 4; ++j) {
      float om = __shfl_xor(mx[j], off);
      float os = __shfl_xor(se[j], off);
      float nm = fmaxf(mx[j], om);
      se[j] = se[j] * __expf(mx[j] - nm) + os * __expf(om - nm);
      mx[j] = nm;
    }
  }
  if (lane == 0) {
#pragma unroll
    for (int j = 0; j < 4; ++j) {
      rmax[(b << 12) + n0 + j] = mx[j];
      rinv[(b << 12) + n0 + j] = 1.f / se[j];
    }
  }
}

// ---------------- K5: PAM PV, 512 thr, 32-n x full-m per block ---------------
// grid (128, 2): block owns n0..n0+31, all 4096 m, all 128 c. 8 waves:
// wave w -> c tile [16w, 16w+16). Per 256-m chunk: p-compute (VALU, fp32) ->
// P[32][256] bf16 in LDS -> 16 MFMA/wave. K double-buffered (4096 floats per
// buffer = 8 elems/thread), reg-staged. Epilogue: sa1 = sa0 + gamma*acc.
__global__ __launch_bounds__(512) void k_pam_pv(const float* __restrict__ qb,
    const float* __restrict__ kb, const u16* __restrict__ vt16,
    const float* __restrict__ rmax, const float* __restrict__ rinv,
    const float* __restrict__ gamma,
    const float* __restrict__ sa0, float* __restrict__ sa1) {
  constexpr int PSTR = 264;          // u16; odd 16B stride
  __shared__ float ks[2][16 * 256];  // [buf][ch][m]
  __shared__ u16 pL[32 * PSTR];      // [n][m] bf16
  int t = threadIdx.x;
  int b = blockIdx.y, n0 = blockIdx.x * 32;
  int lane = t & 63, wave = t >> 6;
  int nl = t & 31, mg = t >> 5;      // p-compute: n local, m-group (16 m each)
  int mi = lane & 15, quad = lane >> 4;
  int c0 = wave * 16;
  // hoist q, stats to registers
  float qreg[16];
  const float* qp = qb + ((size_t)b * 16 << 12) + n0 + nl;
#pragma unroll
  for (int ch = 0; ch < 16; ++ch) qreg[ch] = qp[ch << 12];
  float mv = rmax[(b << 12) + n0 + nl];
  float iv = rinv[(b << 12) + n0 + nl];
  const float* kpb = kb + ((size_t)b * 16 << 12);
  const u16* vb = vt16 + ((size_t)b * 128 << 12);
  f32x4 acc[2] = {};
  // prologue: stage K chunk 0 (16 ch x 256 m = 4096 floats, 8/thread)
#pragma unroll
  for (int k = 0; k < 8; ++k) {
    int idx = t + k * 512;
    ks[0][idx] = kpb[((idx >> 8) << 12) + (idx & 255)];
  }
  __syncthreads();
  int cur = 0;
  for (int it = 0; it < 16; ++it) {
    int m0 = it << 8;
    // issue next-chunk K loads early (latency hides under p-compute)
    float kreg[8];
    if (it < 15) {
#pragma unroll
      for (int k = 0; k < 8; ++k) {
        int idx = t + k * 512;
        kreg[k] = kpb[((idx >> 8) << 12) + m0 + 256 + (idx & 255)];
      }
    }
    // p-compute: energies for (n=nl, m=mg*16..+15); K reads broadcast per half-wave
    float e[16] = {};
    const float* kbase = &ks[cur][mg << 4];
#pragma unroll
    for (int ch = 0; ch < 16; ++ch) {
      float qv = qreg[ch];
      const float* kp2 = kbase + (ch << 8);
      float4 kv0 = *(const float4*)(kp2);
      float4 kv1 = *(const float4*)(kp2 + 4);
      float4 kv2 = *(const float4*)(kp2 + 8);
      float4 kv3 = *(const float4*)(kp2 + 12);
      e[0] = fmaf(qv, kv0.x, e[0]);  e[1] = fmaf(qv, kv0.y, e[1]);
      e[2] = fmaf(qv, kv0.z, e[2]);  e[3] = fmaf(qv, kv0.w, e[3]);
      e[4] = fmaf(qv, kv1.x, e[4]);  e[5] = fmaf(qv, kv1.y, e[5]);
      e[6] = fmaf(qv, kv1.z, e[6]);  e[7] = fmaf(qv, kv1.w, e[7]);
      e[8] = fmaf(qv, kv2.x, e[8]);  e[9] = fmaf(qv, kv2.y, e[9]);
      e[10] = fmaf(qv, kv2.z, e[10]); e[11] = fmaf(qv, kv2.w, e[11]);
      e[12] = fmaf(qv, kv3.x, e[12]); e[13] = fmaf(qv, kv3.y, e[13]);
      e[14] = fmaf(qv, kv3.z, e[14]); e[15] = fmaf(qv, kv3.w, e[15]);
    }
    short8 p0, p1;
#pragma unroll
    for (int j = 0; j < 8; ++j) {
      p0[j] = (short)f2bf(__expf(fminf(e[j] - mv, 0.f)) * iv);
      p1[j] = (short)f2bf(__expf(fminf(e[j + 8] - mv, 0.f)) * iv);
    }
    {
      u16* pw = pL + nl * PSTR + (mg << 4);
      *(short8*)(pw) = p0;
      *(short8*)(pw + 8) = p1;
    }
    __syncthreads();   // P ready; ks[cur] reads done
    // stage next K into alternate buffer (overlaps MFMA phase)
    if (it < 15) {
#pragma unroll
      for (int k = 0; k < 8; ++k) {
        int idx = t + k * 512;
        ks[cur ^ 1][idx] = kreg[k];
      }
    }
    // MFMA: acc[c][n] += V[c][m] * P[n][m], 8 k-slices of 32 m
#pragma unroll
    for (int ksl = 0; ksl < 8; ++ksl) {
      const u16* ap = vb + ((size_t)(c0 + mi) << 12) + m0 + ksl * 32 + quad * 8;
      short8 a = *(const short8*)ap;
      const u16* pb0 = pL + mi * PSTR + ksl * 32 + quad * 8;
      short8 b0 = *(const short8*)(pb0);
      short8 b1 = *(const short8*)(pb0 + 16 * PSTR);
      acc[0] = __builtin_amdgcn_mfma_f32_16x16x32_bf16(a, b0, acc[0], 0, 0, 0);
      acc[1] = __builtin_amdgcn_mfma_f32_16x16x32_bf16(a, b1, acc[1], 0, 0, 0);
    }
    __syncthreads();   // pL free, ks[cur^1] writes done
    cur ^= 1;
  }
  // epilogue: direct write with residual; D: col(n)=mi, row(c)=quad*4+r
  float g = gamma[0];
#pragma unroll
  for (int nh = 0; nh < 2; ++nh)
#pragma unroll
    for (int r = 0; r < 4; ++r) {
      int c = c0 + quad * 4 + r;
      size_t o = ((size_t)(b * 128 + c) << 12) + n0 + nh * 16 + mi;
      sa1[o] = fmaf(g, acc[nh][r], sa0[o]);
    }
}

// ---------------- K6a: CAM Gram energy, block per row c, all threads ---------
__global__ __launch_bounds__(256) void k_cam_energy(const float* __restrict__ f,
                                                    float* __restrict__ energy) {
  __shared__ float fc[4096];
  __shared__ float part[256];
  int t = threadIdx.x;
  int c = blockIdx.x, b = blockIdx.y;
  const float* fr = f + ((size_t)(b * 128 + c) << 12);
  for (int i = t; i < 4096; i += 256) fc[i] = fr[i];
  __syncthreads();
  int d = t & 127, seg = t >> 7;
  const float* fd = f + ((size_t)(b * 128 + d) << 12) + seg * 2048;
  const float* fcs = fc + seg * 2048;
  float acc = 0.f;
  for (int nn = 0; nn < 2048; ++nn) acc = fmaf(fcs[nn], fd[nn], acc);
  part[t] = acc;
  __syncthreads();
  if (t < 128)
    energy[((b * 128 + c) << 7) + t] = part[t] + part[t + 128];
}

// ---------------- K6b: CAM softmax row (attn = softmax(rowmax - e)) ----------
__global__ void k_cam_softmax(const float* __restrict__ energy, float* __restrict__ attn) {
  int lane = threadIdx.x;
  int c = blockIdx.x, b = blockIdx.y;
  const float* e = energy + ((b * 128 + c) << 7);
  float e0 = e[lane], e1 = e[lane + 64];
  float mn = fminf(e0, e1);
#pragma unroll
  for (int off = 32; off >= 1; off >>= 1) mn = fminf(mn, __shfl_xor(mn, off));
  float p0 = __expf(fminf(mn - e0, 0.f)), p1 = __expf(fminf(mn - e1, 0.f));
  float s = p0 + p1;
#pragma unroll
  for (int off = 32; off >= 1; off >>= 1) s += __shfl_xor(s, off);
  float inv = 1.f / s;
  float* a = attn + ((b * 128 + c) << 7);
  a[lane] = p0 * inv;
  a[lane + 64] = p1 * inv;
}

// ---------------- K7: CAM out + residual -------------------------------------
__global__ __launch_bounds__(256) void k_cam_out(const float* __restrict__ f,
    const float* __restrict__ attn, const float* __restrict__ gamma,
    float* __restrict__ sc1) {
  __shared__ float at2[128 * 16];
  int t = threadIdx.x;
  int b = blockIdx.z, c0 = blockIdx.y * 16;
  int n = blockIdx.x * 256 + t;
  for (int idx = t; idx < 2048; idx += 256) {
    int d = idx >> 4, cc = idx & 15;
    at2[idx] = attn[((b * 128 + c0 + cc) << 7) + d];
  }
  __syncthreads();
  float acc[16] = {};
  const float* fb = f + ((size_t)b * 128 << 12) + n;
  for (int d = 0; d < 128; ++d) {
    float fv = fb[d << 12];
    const float* ap = at2 + d * 16;
#pragma unroll
    for (int cc = 0; cc < 16; ++cc) acc[cc] = fmaf(ap[cc], fv, acc[cc]);
  }
  float g = gamma[0];
#pragma unroll
  for (int cc = 0; cc < 16; ++cc) {
    size_t o = ((size_t)(b * 128 + c0 + cc) << 12) + n;
    sc1[o] = fmaf(g, acc[cc], f[o]);
  }
}

// ---------------- K8: BN+ReLU + 1x1 conv 128->512, 16 co per block -----------
__global__ __launch_bounds__(256) void k_branch_out(
    const float* __restrict__ sa1, const float* __restrict__ sc1,
    const float* __restrict__ wa_, const float* __restrict__ ba_,
    const float* __restrict__ ma_, const float* __restrict__ va_,
    const float* __restrict__ wc_, const float* __restrict__ bc_,
    const float* __restrict__ mc_, const float* __restrict__ vc_,
    const float* __restrict__ Wa, const float* __restrict__ Ba,
    const float* __restrict__ Wc, const float* __restrict__ Bc,
    u16* __restrict__ sa2, u16* __restrict__ sc2) {
  int z = blockIdx.z;
  int b = z & 1, br = z >> 1;
  const float* src = br ? sc1 : sa1;
  const float* bw = br ? wc_ : wa_;
  const float* bb = br ? bc_ : ba_;
  const float* bm = br ? mc_ : ma_;
  const float* bvv = br ? vc_ : va_;
  const float* W = br ? Wc : Wa;
  const float* Bs = br ? Bc : Ba;
  u16* dst = br ? sc2 : sa2;
  __shared__ float wl[128 * 16];
  __shared__ float scl[128], shf[128];
  int t = threadIdx.x;
  int co0 = blockIdx.y * 16;
  int n = blockIdx.x * 256 + t;
  if (t < 128) {
    float s = bw[t] * rsqrtf(bvv[t] + 1e-5f);
    scl[t] = s;
    shf[t] = bb[t] - bm[t] * s;
  }
  for (int idx = t; idx < 2048; idx += 256) {
    int ci = idx >> 4, cc = idx & 15;
    wl[idx] = W[(co0 + cc) * 128 + ci];
  }
  __syncthreads();
  float acc[16] = {};
  const float* sp = src + ((size_t)b * 128 << 12) + n;
  for (int ci = 0; ci < 128; ++ci) {
    float xv = fmaxf(fmaf(sp[ci << 12], scl[ci], shf[ci]), 0.f);
    const float* wp = wl + ci * 16;
    float4 w0 = *(const float4*)wp;
    float4 w1 = *(const float4*)(wp + 4);
    float4 w2 = *(const float4*)(wp + 8);
    float4 w3 = *(const float4*)(wp + 12);
    acc[0] = fmaf(w0.x, xv, acc[0]);  acc[1] = fmaf(w0.y, xv, acc[1]);
    acc[2] = fmaf(w0.z, xv, acc[2]);  acc[3] = fmaf(w0.w, xv, acc[3]);
    acc[4] = fmaf(w1.x, xv, acc[4]);  acc[5] = fmaf(w1.y, xv, acc[5]);
    acc[6] = fmaf(w1.z, xv, acc[6]);  acc[7] = fmaf(w1.w, xv, acc[7]);
    acc[8] = fmaf(w2.x, xv, acc[8]);  acc[9] = fmaf(w2.y, xv, acc[9]);
    acc[10] = fmaf(w2.z, xv, acc[10]); acc[11] = fmaf(w2.w, xv, acc[11]);
    acc[12] = fmaf(w3.x, xv, acc[12]); acc[13] = fmaf(w3.y, xv, acc[13]);
    acc[14] = fmaf(w3.z, xv, acc[14]); acc[15] = fmaf(w3.w, xv, acc[15]);
  }
#pragma unroll
  for (int cc = 0; cc < 16; ++cc) {
    dst[((size_t)(b * 512 + co0 + cc) << 12) + n] = f2bf(acc[cc] + Bs[co0 + cc]);
  }
}

// ---------------- K9a: fusion + partial class-head sums (8-way c split) ------
__global__ __launch_bounds__(256) void k_heads(const u16* __restrict__ sa2,
    const u16* __restrict__ sc2,
    const float* __restrict__ wf, const float* __restrict__ wa, const float* __restrict__ wc,
    float* __restrict__ outFusion, float* __restrict__ clsacc) {
  __shared__ float lw[3 * 5 * 64];
  int t = threadIdx.x;
  int b = blockIdx.y, co0 = blockIdx.z * 64;
  int n = blockIdx.x * 256 + t;
  for (int idx = t; idx < 960; idx += 256) {
    int arr = idx / 320, rest = idx - arr * 320;
    int cls = rest >> 6, cc = rest & 63;
    const float* w = arr == 0 ? wf : (arr == 1 ? wa : wc);
    lw[idx] = w[cls * 512 + co0 + cc];
  }
  __syncthreads();
  float af[5] = {}, aa[5] = {}, ac[5] = {};
  for (int cc = 0; cc < 64; ++cc) {
    size_t o = ((size_t)(b * 512 + co0 + cc) << 12) + n;
    float a = bf2f(sa2[o]), c = bf2f(sc2[o]);
    float s = a + c;
    outFusion[o] = s;
#pragma unroll
    for (int cls = 0; cls < 5; ++cls) {
      af[cls] = fmaf(lw[0 * 320 + cls * 64 + cc], s, af[cls]);
      aa[cls] = fmaf(lw[1 * 320 + cls * 64 + cc], a, aa[cls]);
      ac[cls] = fmaf(lw[2 * 320 + cls * 64 + cc], c, ac[cls]);
    }
  }
#pragma unroll
  for (int cls = 0; cls < 5; ++cls) {
    int o = ((b * 5 + cls) << 12) + n;
    atomicAdd(&clsacc[o], af[cls]);
    atomicAdd(&clsacc[40960 + o], aa[cls]);
    atomicAdd(&clsacc[81920 + o], ac[cls]);
  }
}

// ---------------- K9b: add bias, f32 out -------------------------------------
__global__ void k_heads_final(const float* __restrict__ clsacc,
    const float* __restrict__ bf_, const float* __restrict__ ba_,
    const float* __restrict__ bc_, float* __restrict__ outCls) {
  int idx = blockIdx.x * 256 + threadIdx.x;   // 122880
  int arr = idx / 40960;
  int rest = idx - arr * 40960;
  int cls = (rest >> 12) % 5;
  const float* bp = arr == 0 ? bf_ : (arr == 1 ? ba_ : bc_);
  outCls[idx] = clsacc[idx] + bp[cls];
}

extern "C" void kernel_launch(void* const* d_in, const int* in_sizes, int n_in,
                              void* d_out, int out_size, void* d_ws, size_t ws_size,
                              hipStream_t stream) {
  (void)in_sizes; (void)n_in; (void)out_size; (void)ws_size;
  const float* x      = (const float*)d_in[0];
  const float* bnaw   = (const float*)d_in[1];
  const float* bnab   = (const float*)d_in[2];
  const float* bnam   = (const float*)d_in[3];
  const float* bnav   = (const float*)d_in[4];
  const float* convaw = (const float*)d_in[5];
  const float* bncw   = (const float*)d_in[6];
  const float* bncb   = (const float*)d_in[7];
  const float* bncm   = (const float*)d_in[8];
  const float* bncv   = (const float*)d_in[9];
  const float* convcw = (const float*)d_in[10];
  const float* pqw    = (const float*)d_in[11];
  const float* pqb    = (const float*)d_in[12];
  const float* pkw    = (const float*)d_in[13];
  const float* pkb    = (const float*)d_in[14];
  const float* pvw    = (const float*)d_in[15];
  const float* pvb    = (const float*)d_in[16];
  const float* pgam   = (const float*)d_in[17];
  const float* cgam   = (const float*)d_in[18];
  const float* bna1w  = (const float*)d_in[19];
  const float* bna1b  = (const float*)d_in[20];
  const float* bna1m  = (const float*)d_in[21];
  const float* bna1v  = (const float*)d_in[22];
  const float* conva1w = (const float*)d_in[23];
  const float* conva1b = (const float*)d_in[24];
  const float* bnc1w  = (const float*)d_in[25];
  const float* bnc1b  = (const float*)d_in[26];
  const float* bnc1m  = (const float*)d_in[27];
  const float* bnc1v  = (const float*)d_in[28];
  const float* convc1w = (const float*)d_in[29];
  const float* convc1b = (const float*)d_in[30];
  const float* outaw  = (const float*)d_in[31];
  const float* outab  = (const float*)d_in[32];
  const float* outcw  = (const float*)d_in[33];
  const float* outcb  = (const float*)d_in[34];
  const float* outfw  = (const float*)d_in[35];
  const float* outfb  = (const float*)d_in[36];

  char* wsb = (char*)d_ws;
  size_t off = 0;
  auto take = [&](size_t bytes) -> void* {
    void* p = wsb + off;
    off += (bytes + 255) & ~(size_t)255;
    return p;
  };
  float* wvT   = (float*)take((size_t)128 * 128 * 4);
  u16*   Wb    = (u16*)take((size_t)2 * 128 * 9 * 512 * 2);
  u16*   xa16  = (u16*)take((size_t)2 * 512 * 4096 * 2);
  u16*   xcb16 = (u16*)take((size_t)2 * 512 * 4096 * 2);
  float* sa0   = (float*)take((size_t)2 * 128 * 4096 * 4);
  float* sc0   = (float*)take((size_t)2 * 128 * 4096 * 4);
  float* qb    = (float*)take((size_t)2 * 16 * 4096 * 4);
  float* kbuf  = (float*)take((size_t)2 * 16 * 4096 * 4);
  u16*   vt16  = (u16*)take((size_t)2 * 128 * 4096 * 2);
  float* rmax  = (float*)take((size_t)2 * 4096 * 4);
  float* rinv  = (float*)take((size_t)2 * 4096 * 4);
  float* sa1   = (float*)take((size_t)2 * 128 * 4096 * 4);
  float* sc1   = (float*)take((size_t)2 * 128 * 4096 * 4);
  float* energy = (float*)take((size_t)2 * 128 * 128 * 4);
  float* attn  = (float*)take((size_t)2 * 128 * 128 * 4);
  u16*   sa2   = (u16*)take((size_t)2 * 512 * 4096 * 2);
  u16*   sc2   = (u16*)take((size_t)2 * 512 * 4096 * 2);
  float* clsacc = (float*)take((size_t)3 * 2 * 5 * 4096 * 4);

  float* outF = (float*)d_out;
  float* outCls = outF + (size_t)2 * 512 * 4096;

  hipMemsetAsync(clsacc, 0, (size_t)3 * 2 * 5 * 4096 * 4, stream);

  k_prep_wv<<<64, 256, 0, stream>>>(pvw, wvT);
  k_prep_w<<<4608, 256, 0, stream>>>(convaw, convcw, Wb);
  k_bnrelu2t<<<dim3(64, 2), 256, 0, stream>>>(x, bnaw, bnab, bnam, bnav,
                                              bncw, bncb, bncm, bncv, xa16, xcb16);
  k_conv3n<<<dim3(64, 4), 256, 0, stream>>>(xa16, xcb16, Wb, sa0, sc0);
  k_qk<<<dim3(16, 32, 2), 256, 0, stream>>>(sa0, pqw, pqb, pkw, pkb, qb, kbuf);
  k_vt<<<dim3(16, 16, 2), 256, 0, stream>>>(sa0, wvT, pvb, vt16);
  k_pam_stats<<<dim3(256, 2), 256, 0, stream>>>(qb, kbuf, rmax, rinv);
  k_pam_pv<<<dim3(128, 2), 512, 0, stream>>>(qb, kbuf, vt16, rmax, rinv, pgam, sa0, sa1);
  k_cam_energy<<<dim3(128, 2), 256, 0, stream>>>(sc0, energy);
  k_cam_softmax<<<dim3(128, 2), 64, 0, stream>>>(energy, attn);
  k_cam_out<<<dim3(16, 8, 2), 256, 0, stream>>>(sc0, attn, cgam, sc1);
  k_branch_out<<<dim3(16, 32, 4), 256, 0, stream>>>(sa1, sc1,
      bna1w, bna1b, bna1m, bna1v, bnc1w, bnc1b, bnc1m, bnc1v,
      conva1w, conva1b, convc1w, convc1b, sa2, sc2);
  k_heads<<<dim3(16, 2, 8), 256, 0, stream>>>(sa2, sc2, outfw, outaw, outcw, outF, clsacc);
  k_heads_final<<<480, 256, 0, stream>>>(clsacc, outfb, outab, outcb, outCls);
}

// Round 4
// 399.031 us; speedup vs baseline: 1.4417x; 1.1261x over previous
//
#include <hip/hip_runtime.h>

using u16 = unsigned short;
using short8 = __attribute__((ext_vector_type(8))) short;
using f32x4 = __attribute__((ext_vector_type(4))) float;

struct alignas(8) U16x4 { u16 x, y, z, w; };

__device__ __forceinline__ float bf2f(u16 u) {
  return __uint_as_float(((unsigned int)u) << 16);
}
__device__ __forceinline__ u16 f2bf(float f) {
  unsigned int u = __float_as_uint(f);
  unsigned int r = u + 0x7FFFu + ((u >> 16) & 1u);
  return (u16)(r >> 16);
}

// ---------------- K0a: transpose pam_v_w [c][ci] -> wvT [ci][c] --------------
__global__ void k_prep_wv(const float* __restrict__ wv, float* __restrict__ wvT) {
  int idx = blockIdx.x * 256 + threadIdx.x;   // 16384
  int ci = idx >> 7, c = idx & 127;
  wvT[ci * 128 + c] = wv[c * 128 + ci];
}

// ---------------- K0b: conv weights -> bf16, MFMA-fragment order -------------
// Layout: [br][mt(8)][chunk(4)][tap(9)][ks(4)][lane(64)][j(8)]
__global__ void k_prep_w(const float* __restrict__ wa, const float* __restrict__ wc,
                         u16* __restrict__ Wb) {
  int idx = blockIdx.x * 256 + threadIdx.x;   // 1179648
  int j = idx & 7;
  int l = (idx >> 3) & 63;
  int ks = (idx >> 9) & 3;
  int rest = idx >> 11;
  int tap = rest % 9;
  int rest2 = rest / 9;
  int chunk = rest2 & 3;
  int mt = (rest2 >> 2) & 7;
  int br = rest2 >> 5;
  int co = mt * 16 + (l & 15);
  int ci = chunk * 128 + ks * 32 + (l >> 4) * 8 + j;
  const float* w = br ? wc : wa;
  Wb[idx] = f2bf(w[co * 4608 + ci * 9 + tap]);
}

// ---------------- K0c: 1x1 out-conv weights (128->512) -> bf16 A-frag order --
// Layout: [br][cot(32)][ks(4)][lane(64)][j(8)]; co=cot*16+(l&15), ci=ks*32+(l>>4)*8+j
__global__ void k_prep_w1(const float* __restrict__ wa, const float* __restrict__ wc,
                          u16* __restrict__ W1b) {
  int idx = blockIdx.x * 256 + threadIdx.x;   // 2*32*4*64*8 = 131072
  int j = idx & 7;
  int l = (idx >> 3) & 63;
  int ks = (idx >> 9) & 3;
  int cot = (idx >> 11) & 31;
  int br = idx >> 16;
  int co = cot * 16 + (l & 15);
  int ci = ks * 32 + (l >> 4) * 8 + j;
  const float* w = br ? wc : wa;
  W1b[idx] = f2bf(w[co * 128 + ci]);
}

// ---------------- K1: BN+ReLU both branches, NHWC bf16 out -------------------
__global__ __launch_bounds__(256) void k_bnrelu2t(const float* __restrict__ x,
    const float* __restrict__ wa, const float* __restrict__ ba,
    const float* __restrict__ ma, const float* __restrict__ va,
    const float* __restrict__ wc, const float* __restrict__ bc,
    const float* __restrict__ mc, const float* __restrict__ vc,
    u16* __restrict__ xa16, u16* __restrict__ xcb16) {
  __shared__ float sA[512], bA[512], sC[512], bC[512];
  __shared__ u16 ta[64 * 136], tc[64 * 136];
  int t = threadIdx.x;
  int h = blockIdx.x, b = blockIdx.y;
  for (int c = t; c < 512; c += 256) {
    float s1 = wa[c] * rsqrtf(va[c] + 1e-5f);
    sA[c] = s1; bA[c] = ba[c] - ma[c] * s1;
    float s2 = wc[c] * rsqrtf(vc[c] + 1e-5f);
    sC[c] = s2; bC[c] = bc[c] - mc[c] * s2;
  }
  __syncthreads();
  const float* xb = x + ((size_t)b << 21) + (h << 6);
  u16* oa = xa16 + ((size_t)b << 21) + ((size_t)h << 15);
  u16* oc = xcb16 + ((size_t)b << 21) + ((size_t)h << 15);
  int w = t & 63, cg = t >> 6;
  for (int c0 = 0; c0 < 512; c0 += 128) {
#pragma unroll
    for (int i = 0; i < 8; ++i) {
      int cl = cg * 4 + i * 16;
      int c = c0 + cl;
      const float* xp = xb + (size_t)c * 4096 + w;
      float v0 = xp[0], v1 = xp[4096], v2 = xp[8192], v3 = xp[12288];
      U16x4 pa, pc;
      pa.x = f2bf(fmaxf(fmaf(v0, sA[c], bA[c]), 0.f));
      pa.y = f2bf(fmaxf(fmaf(v1, sA[c + 1], bA[c + 1]), 0.f));
      pa.z = f2bf(fmaxf(fmaf(v2, sA[c + 2], bA[c + 2]), 0.f));
      pa.w = f2bf(fmaxf(fmaf(v3, sA[c + 3], bA[c + 3]), 0.f));
      pc.x = f2bf(fmaxf(fmaf(v0, sC[c], bC[c]), 0.f));
      pc.y = f2bf(fmaxf(fmaf(v1, sC[c + 1], bC[c + 1]), 0.f));
      pc.z = f2bf(fmaxf(fmaf(v2, sC[c + 2], bC[c + 2]), 0.f));
      pc.w = f2bf(fmaxf(fmaf(v3, sC[c + 3], bC[c + 3]), 0.f));
      *(U16x4*)(ta + w * 136 + cl) = pa;
      *(U16x4*)(tc + w * 136 + cl) = pc;
    }
    __syncthreads();
#pragma unroll
    for (int i = 0; i < 4; ++i) {
      int idx = t + i * 256;
      int ww = idx >> 4, c8 = (idx & 15) << 3;
      *(short8*)(oa + (size_t)ww * 512 + c0 + c8) = *(const short8*)(ta + ww * 136 + c8);
      *(short8*)(oc + (size_t)ww * 512 + c0 + c8) = *(const short8*)(tc + ww * 136 + c8);
    }
    __syncthreads();
  }
}

// ---------------- K2: 3x3 conv, implicit GEMM, NHWC input --------------------
__global__ __launch_bounds__(256) void k_conv3n(
    const u16* __restrict__ xa16, const u16* __restrict__ xcb16,
    const u16* __restrict__ Wb,
    float* __restrict__ sa0, float* __restrict__ sc0) {
  __shared__ u16 xs[3 * 66 * 136];
  int t = threadIdx.x;
  int h = blockIdx.x;
  int z = blockIdx.y; int b = z & 1, br = z >> 1;
  const u16* xb = (br ? xcb16 : xa16) + ((size_t)b << 21);
  const u16* wb = Wb + (size_t)br * 589824;
  float* out = (br ? sc0 : sa0) + (((size_t)b * 128) << 12) + (h << 6);

  int lane = t & 63, wave = t >> 6;
  int mi = lane & 15, quad = lane >> 4;

  if (t < 96) {
    int dh = t >> 5, side = (t >> 4) & 1, c8 = t & 15;
    short8 z8 = {0, 0, 0, 0, 0, 0, 0, 0};
    *(short8*)(xs + (dh * 66 + side * 65) * 136 + c8 * 8) = z8;
  }

  f32x4 acc[2][4] = {};

  const u16* wlane = wb + lane * 8;
  const u16* bbase0 = xs + mi * 136 + quad * 8;

  for (int chunk = 0; chunk < 4; ++chunk) {
    int ci0 = chunk << 7;
    __syncthreads();
#pragma unroll
    for (int dh = 0; dh < 3; ++dh) {
      int hh = h + dh - 1;
      bool val = (hh >= 0) && (hh < 64);
      const u16* src = xb + (((size_t)hh << 6) << 9) + ci0;
#pragma unroll
      for (int i = 0; i < 4; ++i) {
        int idx = t + i * 256;
        int w = idx >> 4, c8 = (idx & 15) << 3;
        short8 v = {0, 0, 0, 0, 0, 0, 0, 0};
        if (val) v = *(const short8*)(src + ((size_t)w << 9) + c8);
        *(short8*)(xs + (dh * 66 + 1 + w) * 136 + c8) = v;
      }
    }
    __syncthreads();
    const u16* wchunk = wlane + (size_t)(wave * 2 * 4 + chunk) * 36 * 512;
#pragma unroll
    for (int tap = 0; tap < 9; ++tap) {
      const int dh = tap / 3, dw = tap % 3;
      const u16* bp = bbase0 + (dh * 66 + dw) * 136;
      const u16* wt0 = wchunk + tap * 2048;
      const u16* wt1 = wt0 + 73728;
#pragma unroll
      for (int ks = 0; ks < 4; ++ks) {
        short8 a0 = *(const short8*)(wt0 + ks * 512);
        short8 a1 = *(const short8*)(wt1 + ks * 512);
#pragma unroll
        for (int nt = 0; nt < 4; ++nt) {
          short8 bf = *(const short8*)(bp + nt * 2176 + ks * 32);
          acc[0][nt] = __builtin_amdgcn_mfma_f32_16x16x32_bf16(a0, bf, acc[0][nt], 0, 0, 0);
          acc[1][nt] = __builtin_amdgcn_mfma_f32_16x16x32_bf16(a1, bf, acc[1][nt], 0, 0, 0);
        }
      }
    }
  }
#pragma unroll
  for (int m = 0; m < 2; ++m)
#pragma unroll
    for (int nt = 0; nt < 4; ++nt)
#pragma unroll
      for (int r = 0; r < 4; ++r) {
        int co = wave * 32 + m * 16 + quad * 4 + r;
        out[((size_t)co << 12) + nt * 16 + mi] = acc[m][nt][r];
      }
}

// ---------------- K3a: 1x1 conv -> q,k ([b][16][4096] f32) -------------------
__global__ void k_qk(const float* __restrict__ sa0,
    const float* __restrict__ wq, const float* __restrict__ bq,
    const float* __restrict__ wk, const float* __restrict__ bk,
    float* __restrict__ qb, float* __restrict__ kb) {
  int n = blockIdx.x * 256 + threadIdx.x;
  int co = blockIdx.y, b = blockIdx.z;
  const float* w; float* dst; float bias;
  if (co < 16) { w = wq + co * 128; bias = bq[co]; dst = qb + ((b * 16 + co) << 12); }
  else { int c2 = co - 16; w = wk + c2 * 128; bias = bk[c2]; dst = kb + ((b * 16 + c2) << 12); }
  const float* s = sa0 + ((size_t)b * 128 << 12) + n;
  float acc = bias;
  for (int ci = 0; ci < 128; ++ci) acc = fmaf(w[ci], s[ci << 12], acc);
  dst[n] = acc;
}

// ---------------- K3b: 1x1 conv -> v, bf16, layout vt16[b][c][n] -------------
__global__ __launch_bounds__(256) void k_vt(const float* __restrict__ sa0,
    const float* __restrict__ wvT, const float* __restrict__ bv,
    u16* __restrict__ vt16) {
  int t = threadIdx.x;
  int n = blockIdx.x * 256 + t;
  int c0 = blockIdx.y * 8;
  int b = blockIdx.z;
  const float* s = sa0 + ((size_t)b * 128 << 12) + n;
  float acc[8];
#pragma unroll
  for (int c = 0; c < 8; ++c) acc[c] = bv[c0 + c];
  for (int ci = 0; ci < 128; ++ci) {
    float xv = s[ci << 12];
    const float* wp = wvT + ci * 128 + c0;
#pragma unroll
    for (int c = 0; c < 8; ++c) acc[c] = fmaf(wp[c], xv, acc[c]);
  }
#pragma unroll
  for (int c = 0; c < 8; ++c)
    vt16[((size_t)(b * 128 + c0 + c) << 12) + n] = f2bf(acc[c]);
}

// ---------------- K4: PAM softmax row stats; 4 n per lane, 16 n per block ----
__global__ __launch_bounds__(256) void k_pam_stats(const float* __restrict__ qb,
    const float* __restrict__ kb, float* __restrict__ rmax, float* __restrict__ rinv) {
  int t = threadIdx.x, lane = t & 63, wid = t >> 6;
  int b = blockIdx.y;
  int n0 = blockIdx.x * 16 + wid * 4;
  float qreg[4][16];
  const float* qp = qb + ((size_t)b * 16 << 12) + n0;
#pragma unroll
  for (int ch = 0; ch < 16; ++ch)
#pragma unroll
    for (int j = 0; j < 4; ++j) qreg[j][ch] = qp[(ch << 12) + j];
  const float* kp = kb + ((size_t)b * 16 << 12);
  float mx[4], se[4];
#pragma unroll
  for (int j = 0; j < 4; ++j) { mx[j] = -1e30f; se[j] = 0.f; }
  for (int m4 = lane * 4; m4 < 4096; m4 += 256) {
    float e[4][4] = {};
#pragma unroll
    for (int ch = 0; ch < 16; ++ch) {
      float4 kv = *(const float4*)(kp + (ch << 12) + m4);
#pragma unroll
      for (int j = 0; j < 4; ++j) {
        float qv = qreg[j][ch];
        e[j][0] = fmaf(qv, kv.x, e[j][0]);
        e[j][1] = fmaf(qv, kv.y, e[j][1]);
        e[j][2] = fmaf(qv, kv.z, e[j][2]);
        e[j][3] = fmaf(qv, kv.w, e[j][3]);
      }
    }
#pragma unroll
    for (int j = 0; j < 4; ++j) {
      float lm = fmaxf(fmaxf(e[j][0], e[j][1]), fmaxf(e[j][2], e[j][3]));
      float nm = fmaxf(mx[j], lm);
      se[j] = se[j] * __expf(mx[j] - nm)
            + __expf(e[j][0] - nm) + __expf(e[j][1] - nm)
            + __expf(e[j][2] - nm) + __expf(e[j][3] - nm);
      mx[j] = nm;
    }
  }
#pragma unroll
  for (int off = 32; off >= 1; off >>= 1) {
#pragma unroll
    for (int j = 0; j < 4; ++j) {
      float om = __shfl_xor(mx[j], off);
      float os = __shfl_xor(se[j], off);
      float nm = fmaxf(mx[j], om);
      se[j] = se[j] * __expf(mx[j] - nm) + os * __expf(om - nm);
      mx[j] = nm;
    }
  }
  if (lane == 0) {
#pragma unroll
    for (int j = 0; j < 4; ++j) {
      rmax[(b << 12) + n0 + j] = mx[j];
      rinv[(b << 12) + n0 + j] = 1.f / se[j];
    }
  }
}

// ---------------- K5: PAM PV, 512 thr, 32-n x 2048-m per block ---------------
// grid (128, 2, 2): block owns n0..n0+31, m-half mh (2048 m), all 128 c.
// 2 blocks/CU. 8 waves: wave w -> c tile [16w, 16w+16). Per 256-m chunk:
// V prefetched to regs at phase start; p-compute (fp32 VALU) -> P bf16 in LDS
// -> 16 MFMA/wave. K double-buffered reg-staged. Partial out: pvp = gamma*acc.
__global__ __launch_bounds__(512, 4) void k_pam_pv(const float* __restrict__ qb,
    const float* __restrict__ kb, const u16* __restrict__ vt16,
    const float* __restrict__ rmax, const float* __restrict__ rinv,
    const float* __restrict__ gamma, float* __restrict__ pvpart) {
  constexpr int PSTR = 264;          // u16; odd 16B stride
  __shared__ float ks[2][16 * 256];  // [buf][ch][m]
  __shared__ u16 pL[32 * PSTR];      // [n][m] bf16
  int t = threadIdx.x;
  int b = blockIdx.y, n0 = blockIdx.x * 32;
  int mbeg = blockIdx.z << 11;       // 0 or 2048
  int lane = t & 63, wave = t >> 6;
  int nl = t & 31, mg = t >> 5;      // p-compute: n local, m-group (16 m each)
  int mi = lane & 15, quad = lane >> 4;
  int c0 = wave * 16;
  // hoist q, stats to registers
  float qreg[16];
  const float* qp = qb + ((size_t)b * 16 << 12) + n0 + nl;
#pragma unroll
  for (int ch = 0; ch < 16; ++ch) qreg[ch] = qp[ch << 12];
  float mv = rmax[(b << 12) + n0 + nl];
  float iv = rinv[(b << 12) + n0 + nl];
  const float* kpb = kb + ((size_t)b * 16 << 12) + mbeg;
  const u16* vb = vt16 + ((size_t)b * 128 << 12);
  f32x4 acc[2] = {};
  // prologue: stage K chunk 0 (16 ch x 256 m = 4096 floats, 8/thread)
#pragma unroll
  for (int k = 0; k < 8; ++k) {
    int idx = t + k * 512;
    ks[0][idx] = kpb[((idx >> 8) << 12) + (idx & 255)];
  }
  __syncthreads();
  int cur = 0;
  for (int it = 0; it < 8; ++it) {
    int m0 = mbeg + (it << 8);
    // prefetch this chunk's V fragments (used after barrier; hides under p-compute)
    short8 vreg[8];
#pragma unroll
    for (int ksl = 0; ksl < 8; ++ksl)
      vreg[ksl] = *(const short8*)(vb + ((size_t)(c0 + mi) << 12) + m0 + ksl * 32 + quad * 8);
    // issue next-chunk K loads early
    float kreg[8];
    if (it < 7) {
#pragma unroll
      for (int k = 0; k < 8; ++k) {
        int idx = t + k * 512;
        kreg[k] = kpb[((idx >> 8) << 12) + ((it + 1) << 8) + (idx & 255)];
      }
    }
    // p-compute: energies for (n=nl, m=mg*16..+15); K reads broadcast
    float e[16] = {};
    const float* kbase = &ks[cur][mg << 4];
#pragma unroll
    for (int ch = 0; ch < 16; ++ch) {
      float qv = qreg[ch];
      const float* kp2 = kbase + (ch << 8);
      float4 kv0 = *(const float4*)(kp2);
      float4 kv1 = *(const float4*)(kp2 + 4);
      float4 kv2 = *(const float4*)(kp2 + 8);
      float4 kv3 = *(const float4*)(kp2 + 12);
      e[0] = fmaf(qv, kv0.x, e[0]);  e[1] = fmaf(qv, kv0.y, e[1]);
      e[2] = fmaf(qv, kv0.z, e[2]);  e[3] = fmaf(qv, kv0.w, e[3]);
      e[4] = fmaf(qv, kv1.x, e[4]);  e[5] = fmaf(qv, kv1.y, e[5]);
      e[6] = fmaf(qv, kv1.z, e[6]);  e[7] = fmaf(qv, kv1.w, e[7]);
      e[8] = fmaf(qv, kv2.x, e[8]);  e[9] = fmaf(qv, kv2.y, e[9]);
      e[10] = fmaf(qv, kv2.z, e[10]); e[11] = fmaf(qv, kv2.w, e[11]);
      e[12] = fmaf(qv, kv3.x, e[12]); e[13] = fmaf(qv, kv3.y, e[13]);
      e[14] = fmaf(qv, kv3.z, e[14]); e[15] = fmaf(qv, kv3.w, e[15]);
    }
    short8 p0, p1;
#pragma unroll
    for (int j = 0; j < 8; ++j) {
      p0[j] = (short)f2bf(__expf(fminf(e[j] - mv, 0.f)) * iv);
      p1[j] = (short)f2bf(__expf(fminf(e[j + 8] - mv, 0.f)) * iv);
    }
    {
      u16* pw = pL + nl * PSTR + (mg << 4);
      *(short8*)(pw) = p0;
      *(short8*)(pw + 8) = p1;
    }
    __syncthreads();   // P ready; ks[cur] reads done
    // stage next K into alternate buffer (overlaps MFMA phase)
    if (it < 7) {
#pragma unroll
      for (int k = 0; k < 8; ++k) {
        int idx = t + k * 512;
        ks[cur ^ 1][idx] = kreg[k];
      }
    }
    // MFMA: acc[c][n] += V[c][m] * P[n][m], 8 k-slices of 32 m
#pragma unroll
    for (int ksl = 0; ksl < 8; ++ksl) {
      const u16* pb0 = pL + mi * PSTR + ksl * 32 + quad * 8;
      short8 b0 = *(const short8*)(pb0);
      short8 b1 = *(const short8*)(pb0 + 16 * PSTR);
      acc[0] = __builtin_amdgcn_mfma_f32_16x16x32_bf16(vreg[ksl], b0, acc[0], 0, 0, 0);
      acc[1] = __builtin_amdgcn_mfma_f32_16x16x32_bf16(vreg[ksl], b1, acc[1], 0, 0, 0);
    }
    __syncthreads();   // pL free, ks[cur^1] writes done
    cur ^= 1;
  }
  // epilogue: partial write; D: col(n)=mi, row(c)=quad*4+r
  float g = gamma[0];
  float* dst = pvpart + (((size_t)(blockIdx.z * 2 + b) * 128) << 12);
#pragma unroll
  for (int nh = 0; nh < 2; ++nh)
#pragma unroll
    for (int r = 0; r < 4; ++r) {
      int c = c0 + quad * 4 + r;
      dst[((size_t)c << 12) + n0 + nh * 16 + mi] = g * acc[nh][r];
    }
}

// ---------------- K6a: CAM Gram energy, block per row c, all threads ---------
__global__ __launch_bounds__(256) void k_cam_energy(const float* __restrict__ f,
                                                    float* __restrict__ energy) {
  __shared__ float fc[4096];
  __shared__ float part[256];
  int t = threadIdx.x;
  int c = blockIdx.x, b = blockIdx.y;
  const float* fr = f + ((size_t)(b * 128 + c) << 12);
  for (int i = t; i < 4096; i += 256) fc[i] = fr[i];
  __syncthreads();
  int d = t & 127, seg = t >> 7;
  const float* fd = f + ((size_t)(b * 128 + d) << 12) + seg * 2048;
  const float* fcs = fc + seg * 2048;
  float acc = 0.f;
  for (int nn = 0; nn < 2048; ++nn) acc = fmaf(fcs[nn], fd[nn], acc);
  part[t] = acc;
  __syncthreads();
  if (t < 128)
    energy[((b * 128 + c) << 7) + t] = part[t] + part[t + 128];
}

// ---------------- K6b: CAM softmax row (attn = softmax(rowmax - e)) ----------
__global__ void k_cam_softmax(const float* __restrict__ energy, float* __restrict__ attn) {
  int lane = threadIdx.x;
  int c = blockIdx.x, b = blockIdx.y;
  const float* e = energy + ((b * 128 + c) << 7);
  float e0 = e[lane], e1 = e[lane + 64];
  float mn = fminf(e0, e1);
#pragma unroll
  for (int off = 32; off >= 1; off >>= 1) mn = fminf(mn, __shfl_xor(mn, off));
  float p0 = __expf(fminf(mn - e0, 0.f)), p1 = __expf(fminf(mn - e1, 0.f));
  float s = p0 + p1;
#pragma unroll
  for (int off = 32; off >= 1; off >>= 1) s += __shfl_xor(s, off);
  float inv = 1.f / s;
  float* a = attn + ((b * 128 + c) << 7);
  a[lane] = p0 * inv;
  a[lane + 64] = p1 * inv;
}

// ---------------- K7: CAM out + residual -------------------------------------
__global__ __launch_bounds__(256) void k_cam_out(const float* __restrict__ f,
    const float* __restrict__ attn, const float* __restrict__ gamma,
    float* __restrict__ sc1) {
  __shared__ float at2[128 * 16];
  int t = threadIdx.x;
  int b = blockIdx.z, c0 = blockIdx.y * 16;
  int n = blockIdx.x * 256 + t;
  for (int idx = t; idx < 2048; idx += 256) {
    int d = idx >> 4, cc = idx & 15;
    at2[idx] = attn[((b * 128 + c0 + cc) << 7) + d];
  }
  __syncthreads();
  float acc[16] = {};
  const float* fb = f + ((size_t)b * 128 << 12) + n;
  for (int d = 0; d < 128; ++d) {
    float fv = fb[d << 12];
    const float* ap = at2 + d * 16;
#pragma unroll
    for (int cc = 0; cc < 16; ++cc) acc[cc] = fmaf(ap[cc], fv, acc[cc]);
  }
  float g = gamma[0];
#pragma unroll
  for (int cc = 0; cc < 16; ++cc) {
    size_t o = ((size_t)(b * 128 + c0 + cc) << 12) + n;
    sc1[o] = fmaf(g, acc[cc], f[o]);
  }
}

// ---------------- K8: BN+ReLU + 1x1 conv 128->512 via MFMA -------------------
// grid (128 nt32, 2 b, 2 br), 256 thr, 2 blocks/CU. Stage BN+ReLU bf16
// transposed [32n][128ci] in LDS; sa-branch input = sa0 + pv0 + pv1.
// 4 waves: wave w -> co [128w, 128w+128) (8 co-tiles). 256 MFMA/block.
__global__ __launch_bounds__(256, 2) void k_bout_m(
    const float* __restrict__ sa0, const float* __restrict__ pvpart,
    const float* __restrict__ sc1,
    const float* __restrict__ wa_, const float* __restrict__ ba_,
    const float* __restrict__ ma_, const float* __restrict__ va_,
    const float* __restrict__ wc_, const float* __restrict__ bc_,
    const float* __restrict__ mc_, const float* __restrict__ vc_,
    const u16* __restrict__ W1b, const float* __restrict__ Ba,
    const float* __restrict__ Bc,
    u16* __restrict__ sa2, u16* __restrict__ sc2) {
  __shared__ u16 xl[32 * 136];
  __shared__ float scl[128], shf[128];
  int t = threadIdx.x;
  int n0 = blockIdx.x * 32;
  int b = blockIdx.y, br = blockIdx.z;
  const float* bw = br ? wc_ : wa_;
  const float* bb = br ? bc_ : ba_;
  const float* bm = br ? mc_ : ma_;
  const float* bvv = br ? vc_ : va_;
  if (t < 128) {
    float s = bw[t] * rsqrtf(bvv[t] + 1e-5f);
    scl[t] = s;
    shf[t] = bb[t] - bm[t] * s;
  }
  __syncthreads();
  // stage: BN+ReLU -> bf16, transpose to [n][ci]
  {
    int nl = t & 31, cio = t >> 5;   // cio 0..7 -> ci block of 16
    const float* s0 = (br ? sc1 : sa0) + ((size_t)b * 128 << 12) + n0 + nl;
    const float* p0 = pvpart + ((size_t)b * 128 << 12) + n0 + nl;
    const float* p1 = pvpart + (((size_t)(2 + b) * 128) << 12) + n0 + nl;
#pragma unroll
    for (int half = 0; half < 2; ++half) {
      short8 v;
#pragma unroll
      for (int i = 0; i < 8; ++i) {
        int ci = cio * 16 + half * 8 + i;
        float xv = s0[(size_t)ci << 12];
        if (!br) xv += p0[(size_t)ci << 12] + p1[(size_t)ci << 12];
        v[i] = (short)f2bf(fmaxf(fmaf(xv, scl[ci], shf[ci]), 0.f));
      }
      *(short8*)(xl + nl * 136 + cio * 16 + half * 8) = v;
    }
  }
  __syncthreads();
  int lane = t & 63, wave = t >> 6;
  int mi = lane & 15, quad = lane >> 4;
  const u16* wb = W1b + (size_t)br * 65536 + lane * 8;
  f32x4 acc[8][2] = {};
#pragma unroll
  for (int ks = 0; ks < 4; ++ks) {
    short8 b0 = *(const short8*)(xl + mi * 136 + ks * 32 + quad * 8);
    short8 b1 = *(const short8*)(xl + (16 + mi) * 136 + ks * 32 + quad * 8);
#pragma unroll
    for (int ct = 0; ct < 8; ++ct) {
      int cot = wave * 8 + ct;
      short8 a = *(const short8*)(wb + ((size_t)(cot * 4 + ks) << 9));
      acc[ct][0] = __builtin_amdgcn_mfma_f32_16x16x32_bf16(a, b0, acc[ct][0], 0, 0, 0);
      acc[ct][1] = __builtin_amdgcn_mfma_f32_16x16x32_bf16(a, b1, acc[ct][1], 0, 0, 0);
    }
  }
  const float* Bs = br ? Bc : Ba;
  u16* dst = br ? sc2 : sa2;
#pragma unroll
  for (int ct = 0; ct < 8; ++ct)
#pragma unroll
    for (int nh = 0; nh < 2; ++nh)
#pragma unroll
      for (int r = 0; r < 4; ++r) {
        int co = (wave * 8 + ct) * 16 + quad * 4 + r;
        dst[((size_t)(b * 512 + co) << 12) + n0 + nh * 16 + mi] =
            f2bf(acc[ct][nh][r] + Bs[co]);
      }
}

// ---------------- K9a: fusion + partial class-head sums (8-way c split) ------
__global__ __launch_bounds__(256) void k_heads(const u16* __restrict__ sa2,
    const u16* __restrict__ sc2,
    const float* __restrict__ wf, const float* __restrict__ wa, const float* __restrict__ wc,
    float* __restrict__ outFusion, float* __restrict__ clsacc) {
  __shared__ float lw[3 * 5 * 64];
  int t = threadIdx.x;
  int b = blockIdx.y, co0 = blockIdx.z * 64;
  int n = blockIdx.x * 256 + t;
  for (int idx = t; idx < 960; idx += 256) {
    int arr = idx / 320, rest = idx - arr * 320;
    int cls = rest >> 6, cc = rest & 63;
    const float* w = arr == 0 ? wf : (arr == 1 ? wa : wc);
    lw[idx] = w[cls * 512 + co0 + cc];
  }
  __syncthreads();
  float af[5] = {}, aa[5] = {}, ac[5] = {};
  for (int cc = 0; cc < 64; ++cc) {
    size_t o = ((size_t)(b * 512 + co0 + cc) << 12) + n;
    float a = bf2f(sa2[o]), c = bf2f(sc2[o]);
    float s = a + c;
    outFusion[o] = s;
#pragma unroll
    for (int cls = 0; cls < 5; ++cls) {
      af[cls] = fmaf(lw[0 * 320 + cls * 64 + cc], s, af[cls]);
      aa[cls] = fmaf(lw[1 * 320 + cls * 64 + cc], a, aa[cls]);
      ac[cls] = fmaf(lw[2 * 320 + cls * 64 + cc], c, ac[cls]);
    }
  }
#pragma unroll
  for (int cls = 0; cls < 5; ++cls) {
    int o = ((b * 5 + cls) << 12) + n;
    atomicAdd(&clsacc[o], af[cls]);
    atomicAdd(&clsacc[40960 + o], aa[cls]);
    atomicAdd(&clsacc[81920 + o], ac[cls]);
  }
}

// ---------------- K9b: add bias, f32 out -------------------------------------
__global__ void k_heads_final(const float* __restrict__ clsacc,
    const float* __restrict__ bf_, const float* __restrict__ ba_,
    const float* __restrict__ bc_, float* __restrict__ outCls) {
  int idx = blockIdx.x * 256 + threadIdx.x;   // 122880
  int arr = idx / 40960;
  int rest = idx - arr * 40960;
  int cls = (rest >> 12) % 5;
  const float* bp = arr == 0 ? bf_ : (arr == 1 ? ba_ : bc_);
  outCls[idx] = clsacc[idx] + bp[cls];
}

extern "C" void kernel_launch(void* const* d_in, const int* in_sizes, int n_in,
                              void* d_out, int out_size, void* d_ws, size_t ws_size,
                              hipStream_t stream) {
  (void)in_sizes; (void)n_in; (void)out_size; (void)ws_size;
  const float* x      = (const float*)d_in[0];
  const float* bnaw   = (const float*)d_in[1];
  const float* bnab   = (const float*)d_in[2];
  const float* bnam   = (const float*)d_in[3];
  const float* bnav   = (const float*)d_in[4];
  const float* convaw = (const float*)d_in[5];
  const float* bncw   = (const float*)d_in[6];
  const float* bncb   = (const float*)d_in[7];
  const float* bncm   = (const float*)d_in[8];
  const float* bncv   = (const float*)d_in[9];
  const float* convcw = (const float*)d_in[10];
  const float* pqw    = (const float*)d_in[11];
  const float* pqb    = (const float*)d_in[12];
  const float* pkw    = (const float*)d_in[13];
  const float* pkb    = (const float*)d_in[14];
  const float* pvw    = (const float*)d_in[15];
  const float* pvb    = (const float*)d_in[16];
  const float* pgam   = (const float*)d_in[17];
  const float* cgam   = (const float*)d_in[18];
  const float* bna1w  = (const float*)d_in[19];
  const float* bna1b  = (const float*)d_in[20];
  const float* bna1m  = (const float*)d_in[21];
  const float* bna1v  = (const float*)d_in[22];
  const float* conva1w = (const float*)d_in[23];
  const float* conva1b = (const float*)d_in[24];
  const float* bnc1w  = (const float*)d_in[25];
  const float* bnc1b  = (const float*)d_in[26];
  const float* bnc1m  = (const float*)d_in[27];
  const float* bnc1v  = (const float*)d_in[28];
  const float* convc1w = (const float*)d_in[29];
  const float* convc1b = (const float*)d_in[30];
  const float* outaw  = (const float*)d_in[31];
  const float* outab  = (const float*)d_in[32];
  const float* outcw  = (const float*)d_in[33];
  const float* outcb  = (const float*)d_in[34];
  const float* outfw  = (const float*)d_in[35];
  const float* outfb  = (const float*)d_in[36];

  char* wsb = (char*)d_ws;
  size_t off = 0;
  auto take = [&](size_t bytes) -> void* {
    void* p = wsb + off;
    off += (bytes + 255) & ~(size_t)255;
    return p;
  };
  float* wvT   = (float*)take((size_t)128 * 128 * 4);
  u16*   Wb    = (u16*)take((size_t)2 * 128 * 9 * 512 * 2);
  u16*   W1b   = (u16*)take((size_t)2 * 512 * 128 * 2);
  u16*   xa16  = (u16*)take((size_t)2 * 512 * 4096 * 2);
  u16*   xcb16 = (u16*)take((size_t)2 * 512 * 4096 * 2);
  float* sa0   = (float*)take((size_t)2 * 128 * 4096 * 4);
  float* sc0   = (float*)take((size_t)2 * 128 * 4096 * 4);
  float* qb    = (float*)take((size_t)2 * 16 * 4096 * 4);
  float* kbuf  = (float*)take((size_t)2 * 16 * 4096 * 4);
  u16*   vt16  = (u16*)take((size_t)2 * 128 * 4096 * 2);
  float* rmax  = (float*)take((size_t)2 * 4096 * 4);
  float* rinv  = (float*)take((size_t)2 * 4096 * 4);
  float* pvpart = (float*)take((size_t)2 * 2 * 128 * 4096 * 4);
  float* sc1   = (float*)take((size_t)2 * 128 * 4096 * 4);
  float* energy = (float*)take((size_t)2 * 128 * 128 * 4);
  float* attn  = (float*)take((size_t)2 * 128 * 128 * 4);
  u16*   sa2   = (u16*)take((size_t)2 * 512 * 4096 * 2);
  u16*   sc2   = (u16*)take((size_t)2 * 512 * 4096 * 2);
  float* clsacc = (float*)take((size_t)3 * 2 * 5 * 4096 * 4);

  float* outF = (float*)d_out;
  float* outCls = outF + (size_t)2 * 512 * 4096;

  hipMemsetAsync(clsacc, 0, (size_t)3 * 2 * 5 * 4096 * 4, stream);

  k_prep_wv<<<64, 256, 0, stream>>>(pvw, wvT);
  k_prep_w<<<4608, 256, 0, stream>>>(convaw, convcw, Wb);
  k_prep_w1<<<512, 256, 0, stream>>>(conva1w, convc1w, W1b);
  k_bnrelu2t<<<dim3(64, 2), 256, 0, stream>>>(x, bnaw, bnab, bnam, bnav,
                                              bncw, bncb, bncm, bncv, xa16, xcb16);
  k_conv3n<<<dim3(64, 4), 256, 0, stream>>>(xa16, xcb16, Wb, sa0, sc0);
  k_qk<<<dim3(16, 32, 2), 256, 0, stream>>>(sa0, pqw, pqb, pkw, pkb, qb, kbuf);
  k_vt<<<dim3(16, 16, 2), 256, 0, stream>>>(sa0, wvT, pvb, vt16);
  k_pam_stats<<<dim3(256, 2), 256, 0, stream>>>(qb, kbuf, rmax, rinv);
  k_pam_pv<<<dim3(128, 2, 2), 512, 0, stream>>>(qb, kbuf, vt16, rmax, rinv, pgam, pvpart);
  k_cam_energy<<<dim3(128, 2), 256, 0, stream>>>(sc0, energy);
  k_cam_softmax<<<dim3(128, 2), 64, 0, stream>>>(energy, attn);
  k_cam_out<<<dim3(16, 8, 2), 256, 0, stream>>>(sc0, attn, cgam, sc1);
  k_bout_m<<<dim3(128, 2, 2), 256, 0, stream>>>(sa0, pvpart, sc1,
      bna1w, bna1b, bna1m, bna1v, bnc1w, bnc1b, bnc1m, bnc1v,
      W1b, conva1b, convc1b, sa2, sc2);
  k_heads<<<dim3(16, 2, 8), 256, 0, stream>>>(sa2, sc2, outfw, outaw, outcw, outF, clsacc);
  k_heads_final<<<480, 256, 0, stream>>>(clsacc, outfb, outab, outcb, outCls);
}

// Round 5
// 349.844 us; speedup vs baseline: 1.6444x; 1.1406x over previous
//
#include <hip/hip_runtime.h>

using u16 = unsigned short;
using short8 = __attribute__((ext_vector_type(8))) short;
using f32x4 = __attribute__((ext_vector_type(4))) float;

struct alignas(8) U16x4 { u16 x, y, z, w; };

__device__ __forceinline__ float bf2f(u16 u) {
  return __uint_as_float(((unsigned int)u) << 16);
}
__device__ __forceinline__ u16 f2bf(float f) {
  unsigned int u = __float_as_uint(f);
  unsigned int r = u + 0x7FFFu + ((u >> 16) & 1u);
  return (u16)(r >> 16);
}

// ---------------- K0b: conv weights -> bf16, MFMA-fragment order -------------
// Layout: [br][mt(8)][chunk(4)][tap(9)][ks(4)][lane(64)][j(8)]
__global__ void k_prep_w(const float* __restrict__ wa, const float* __restrict__ wc,
                         u16* __restrict__ Wb) {
  int idx = blockIdx.x * 256 + threadIdx.x;   // 1179648
  int j = idx & 7;
  int l = (idx >> 3) & 63;
  int ks = (idx >> 9) & 3;
  int rest = idx >> 11;
  int tap = rest % 9;
  int rest2 = rest / 9;
  int chunk = rest2 & 3;
  int mt = (rest2 >> 2) & 7;
  int br = rest2 >> 5;
  int co = mt * 16 + (l & 15);
  int ci = chunk * 128 + ks * 32 + (l >> 4) * 8 + j;
  const float* w = br ? wc : wa;
  Wb[idx] = f2bf(w[co * 4608 + ci * 9 + tap]);
}

// ---------------- K0c: 1x1 out-conv weights (128->512) -> bf16 A-frag order --
__global__ void k_prep_w1(const float* __restrict__ wa, const float* __restrict__ wc,
                          u16* __restrict__ W1b) {
  int idx = blockIdx.x * 256 + threadIdx.x;   // 131072
  int j = idx & 7;
  int l = (idx >> 3) & 63;
  int ks = (idx >> 9) & 3;
  int cot = (idx >> 11) & 31;
  int br = idx >> 16;
  int co = cot * 16 + (l & 15);
  int ci = ks * 32 + (l >> 4) * 8 + j;
  const float* w = br ? wc : wa;
  W1b[idx] = f2bf(w[co * 128 + ci]);
}

// ---------------- K0d: qkv weights (160x128) -> bf16 A-frag order ------------
// rows 0-15: wq, 16-31: wk, 32-159: wv. [cot(10)][ks(4)][lane(64)][j(8)]
__global__ void k_prep_wqkv(const float* __restrict__ wq, const float* __restrict__ wk,
                            const float* __restrict__ wv, u16* __restrict__ Wq) {
  int idx = blockIdx.x * 256 + threadIdx.x;   // 20480
  if (idx >= 20480) return;
  int j = idx & 7;
  int l = (idx >> 3) & 63;
  int ks = (idx >> 9) & 3;
  int cot = idx >> 11;
  int co = cot * 16 + (l & 15);
  int ci = ks * 32 + (l >> 4) * 8 + j;
  float w = co < 16 ? wq[co * 128 + ci]
          : (co < 32 ? wk[(co - 16) * 128 + ci] : wv[(co - 32) * 128 + ci]);
  Wq[idx] = f2bf(w);
}

// ---------------- K1: BN+ReLU both branches, NHWC bf16 out -------------------
__global__ __launch_bounds__(256) void k_bnrelu2t(const float* __restrict__ x,
    const float* __restrict__ wa, const float* __restrict__ ba,
    const float* __restrict__ ma, const float* __restrict__ va,
    const float* __restrict__ wc, const float* __restrict__ bc,
    const float* __restrict__ mc, const float* __restrict__ vc,
    u16* __restrict__ xa16, u16* __restrict__ xcb16) {
  __shared__ float sA[512], bA[512], sC[512], bC[512];
  __shared__ u16 ta[64 * 136], tc[64 * 136];
  int t = threadIdx.x;
  int h = blockIdx.x, b = blockIdx.y;
  for (int c = t; c < 512; c += 256) {
    float s1 = wa[c] * rsqrtf(va[c] + 1e-5f);
    sA[c] = s1; bA[c] = ba[c] - ma[c] * s1;
    float s2 = wc[c] * rsqrtf(vc[c] + 1e-5f);
    sC[c] = s2; bC[c] = bc[c] - mc[c] * s2;
  }
  __syncthreads();
  const float* xb = x + ((size_t)b << 21) + (h << 6);
  u16* oa = xa16 + ((size_t)b << 21) + ((size_t)h << 15);
  u16* oc = xcb16 + ((size_t)b << 21) + ((size_t)h << 15);
  int w = t & 63, cg = t >> 6;
  for (int c0 = 0; c0 < 512; c0 += 128) {
#pragma unroll
    for (int i = 0; i < 8; ++i) {
      int cl = cg * 4 + i * 16;
      int c = c0 + cl;
      const float* xp = xb + (size_t)c * 4096 + w;
      float v0 = xp[0], v1 = xp[4096], v2 = xp[8192], v3 = xp[12288];
      U16x4 pa, pc;
      pa.x = f2bf(fmaxf(fmaf(v0, sA[c], bA[c]), 0.f));
      pa.y = f2bf(fmaxf(fmaf(v1, sA[c + 1], bA[c + 1]), 0.f));
      pa.z = f2bf(fmaxf(fmaf(v2, sA[c + 2], bA[c + 2]), 0.f));
      pa.w = f2bf(fmaxf(fmaf(v3, sA[c + 3], bA[c + 3]), 0.f));
      pc.x = f2bf(fmaxf(fmaf(v0, sC[c], bC[c]), 0.f));
      pc.y = f2bf(fmaxf(fmaf(v1, sC[c + 1], bC[c + 1]), 0.f));
      pc.z = f2bf(fmaxf(fmaf(v2, sC[c + 2], bC[c + 2]), 0.f));
      pc.w = f2bf(fmaxf(fmaf(v3, sC[c + 3], bC[c + 3]), 0.f));
      *(U16x4*)(ta + w * 136 + cl) = pa;
      *(U16x4*)(tc + w * 136 + cl) = pc;
    }
    __syncthreads();
#pragma unroll
    for (int i = 0; i < 4; ++i) {
      int idx = t + i * 256;
      int ww = idx >> 4, c8 = (idx & 15) << 3;
      *(short8*)(oa + (size_t)ww * 512 + c0 + c8) = *(const short8*)(ta + ww * 136 + c8);
      *(short8*)(oc + (size_t)ww * 512 + c0 + c8) = *(const short8*)(tc + ww * 136 + c8);
    }
    __syncthreads();
  }
}

// ---------------- K2: 3x3 conv, implicit GEMM, NHWC input --------------------
// Extra outputs: br==0 -> sa_nhwc [b][n][128] bf16 (QKV GEMM operand);
//                br==1 -> sc16h/sc16l [b][c][n] split-bf16 (CAM Gram operand).
__global__ __launch_bounds__(256) void k_conv3n(
    const u16* __restrict__ xa16, const u16* __restrict__ xcb16,
    const u16* __restrict__ Wb,
    float* __restrict__ sa0, float* __restrict__ sc0,
    u16* __restrict__ sa_nhwc, u16* __restrict__ sc16h, u16* __restrict__ sc16l) {
  __shared__ u16 xs[3 * 66 * 136];
  int t = threadIdx.x;
  int h = blockIdx.x;
  int z = blockIdx.y; int b = z & 1, br = z >> 1;
  const u16* xb = (br ? xcb16 : xa16) + ((size_t)b << 21);
  const u16* wb = Wb + (size_t)br * 589824;
  float* out = (br ? sc0 : sa0) + (((size_t)b * 128) << 12) + (h << 6);

  int lane = t & 63, wave = t >> 6;
  int mi = lane & 15, quad = lane >> 4;

  if (t < 96) {
    int dh = t >> 5, side = (t >> 4) & 1, c8 = t & 15;
    short8 z8 = {0, 0, 0, 0, 0, 0, 0, 0};
    *(short8*)(xs + (dh * 66 + side * 65) * 136 + c8 * 8) = z8;
  }

  f32x4 acc[2][4] = {};

  const u16* wlane = wb + lane * 8;
  const u16* bbase0 = xs + mi * 136 + quad * 8;

  for (int chunk = 0; chunk < 4; ++chunk) {
    int ci0 = chunk << 7;
    __syncthreads();
#pragma unroll
    for (int dh = 0; dh < 3; ++dh) {
      int hh = h + dh - 1;
      bool val = (hh >= 0) && (hh < 64);
      const u16* src = xb + (((size_t)hh << 6) << 9) + ci0;
#pragma unroll
      for (int i = 0; i < 4; ++i) {
        int idx = t + i * 256;
        int w = idx >> 4, c8 = (idx & 15) << 3;
        short8 v = {0, 0, 0, 0, 0, 0, 0, 0};
        if (val) v = *(const short8*)(src + ((size_t)w << 9) + c8);
        *(short8*)(xs + (dh * 66 + 1 + w) * 136 + c8) = v;
      }
    }
    __syncthreads();
    const u16* wchunk = wlane + (size_t)(wave * 2 * 4 + chunk) * 36 * 512;
#pragma unroll
    for (int tap = 0; tap < 9; ++tap) {
      const int dh = tap / 3, dw = tap % 3;
      const u16* bp = bbase0 + (dh * 66 + dw) * 136;
      const u16* wt0 = wchunk + tap * 2048;
      const u16* wt1 = wt0 + 73728;
#pragma unroll
      for (int ks = 0; ks < 4; ++ks) {
        short8 a0 = *(const short8*)(wt0 + ks * 512);
        short8 a1 = *(const short8*)(wt1 + ks * 512);
#pragma unroll
        for (int nt = 0; nt < 4; ++nt) {
          short8 bf = *(const short8*)(bp + nt * 2176 + ks * 32);
          acc[0][nt] = __builtin_amdgcn_mfma_f32_16x16x32_bf16(a0, bf, acc[0][nt], 0, 0, 0);
          acc[1][nt] = __builtin_amdgcn_mfma_f32_16x16x32_bf16(a1, bf, acc[1][nt], 0, 0, 0);
        }
      }
    }
  }
#pragma unroll
  for (int m = 0; m < 2; ++m)
#pragma unroll
    for (int nt = 0; nt < 4; ++nt)
#pragma unroll
      for (int r = 0; r < 4; ++r) {
        int co = wave * 32 + m * 16 + quad * 4 + r;
        out[((size_t)co << 12) + nt * 16 + mi] = acc[m][nt][r];
      }
  if (br == 0) {
    // NHWC bf16: sa_nhwc[(b*4096 + h*64 + n)*128 + co]
    u16* dstq = sa_nhwc + ((size_t)b << 19) + ((size_t)h << 6) * 128;
#pragma unroll
    for (int m = 0; m < 2; ++m)
#pragma unroll
      for (int nt = 0; nt < 4; ++nt) {
        U16x4 v4;
        v4.x = f2bf(acc[m][nt][0]); v4.y = f2bf(acc[m][nt][1]);
        v4.z = f2bf(acc[m][nt][2]); v4.w = f2bf(acc[m][nt][3]);
        *(U16x4*)(dstq + (size_t)(nt * 16 + mi) * 128 + wave * 32 + m * 16 + quad * 4) = v4;
      }
  } else {
    // split-bf16 [c][n]
    u16* dh_ = sc16h + ((size_t)b << 19) + (h << 6);
    u16* dl_ = sc16l + ((size_t)b << 19) + (h << 6);
#pragma unroll
    for (int m = 0; m < 2; ++m)
#pragma unroll
      for (int nt = 0; nt < 4; ++nt)
#pragma unroll
        for (int r = 0; r < 4; ++r) {
          int co = wave * 32 + m * 16 + quad * 4 + r;
          float xv = acc[m][nt][r];
          u16 hi = f2bf(xv);
          float lo = xv - bf2f(hi);
          size_t o = ((size_t)co << 12) + nt * 16 + mi;
          dh_[o] = hi;
          dl_[o] = f2bf(lo);
        }
  }
}

// ---------------- K3: fused q,k,v 1x1 convs via MFMA -------------------------
// M=160 (16 q + 16 k + 128 v), K=128, N=4096. grid (32 nb, 2 b), 256 thr.
// wave w -> n [n0+32w, +32). B from sa_nhwc[n][ci]; A pre-packed Wqkvb.
__global__ __launch_bounds__(256) void k_qkv(
    const u16* __restrict__ sa_nhwc, const u16* __restrict__ Wqkvb,
    const float* __restrict__ bq, const float* __restrict__ bk,
    const float* __restrict__ bv,
    float* __restrict__ qb, float* __restrict__ kbuf, u16* __restrict__ vt16) {
  __shared__ float bs[160];
  int t = threadIdx.x;
  int b = blockIdx.y, n0 = blockIdx.x * 128;
  if (t < 160) bs[t] = t < 16 ? bq[t] : (t < 32 ? bk[t - 16] : bv[t - 32]);
  __syncthreads();
  int lane = t & 63, wave = t >> 6;
  int mi = lane & 15, quad = lane >> 4;
  const u16* xb = sa_nhwc + ((size_t)b << 19) + (size_t)n0 * 128;
  const u16* wb = Wqkvb + lane * 8;
  f32x4 acc[2][10] = {};
  short8 bf[2][4];
#pragma unroll
  for (int ns = 0; ns < 2; ++ns) {
    int n = wave * 32 + ns * 16 + mi;
#pragma unroll
    for (int ks = 0; ks < 4; ++ks)
      bf[ns][ks] = *(const short8*)(xb + (size_t)n * 128 + ks * 32 + quad * 8);
  }
#pragma unroll
  for (int cot = 0; cot < 10; ++cot) {
    short8 a0 = *(const short8*)(wb + (size_t)(cot * 4 + 0) * 512);
    short8 a1 = *(const short8*)(wb + (size_t)(cot * 4 + 1) * 512);
    short8 a2 = *(const short8*)(wb + (size_t)(cot * 4 + 2) * 512);
    short8 a3 = *(const short8*)(wb + (size_t)(cot * 4 + 3) * 512);
#pragma unroll
    for (int ns = 0; ns < 2; ++ns) {
      acc[ns][cot] = __builtin_amdgcn_mfma_f32_16x16x32_bf16(a0, bf[ns][0], acc[ns][cot], 0, 0, 0);
      acc[ns][cot] = __builtin_amdgcn_mfma_f32_16x16x32_bf16(a1, bf[ns][1], acc[ns][cot], 0, 0, 0);
      acc[ns][cot] = __builtin_amdgcn_mfma_f32_16x16x32_bf16(a2, bf[ns][2], acc[ns][cot], 0, 0, 0);
      acc[ns][cot] = __builtin_amdgcn_mfma_f32_16x16x32_bf16(a3, bf[ns][3], acc[ns][cot], 0, 0, 0);
    }
  }
#pragma unroll
  for (int cot = 0; cot < 10; ++cot)
#pragma unroll
    for (int ns = 0; ns < 2; ++ns)
#pragma unroll
      for (int r = 0; r < 4; ++r) {
        int co = cot * 16 + quad * 4 + r;
        int n = n0 + wave * 32 + ns * 16 + mi;
        float v = acc[ns][cot][r] + bs[co];
        if (co < 16) qb[((b * 16 + co) << 12) + n] = v;
        else if (co < 32) kbuf[((b * 16 + co - 16) << 12) + n] = v;
        else vt16[((size_t)(b * 128 + co - 32) << 12) + n] = f2bf(v);
      }
}

// ---------------- K4: PAM softmax row stats; 4 n per lane, 16 n per block ----
__global__ __launch_bounds__(256) void k_pam_stats(const float* __restrict__ qb,
    const float* __restrict__ kb, float* __restrict__ rmax, float* __restrict__ rinv) {
  int t = threadIdx.x, lane = t & 63, wid = t >> 6;
  int b = blockIdx.y;
  int n0 = blockIdx.x * 16 + wid * 4;
  float qreg[4][16];
  const float* qp = qb + ((size_t)b * 16 << 12) + n0;
#pragma unroll
  for (int ch = 0; ch < 16; ++ch)
#pragma unroll
    for (int j = 0; j < 4; ++j) qreg[j][ch] = qp[(ch << 12) + j];
  const float* kp = kb + ((size_t)b * 16 << 12);
  float mx[4], se[4];
#pragma unroll
  for (int j = 0; j < 4; ++j) { mx[j] = -1e30f; se[j] = 0.f; }
  for (int m4 = lane * 4; m4 < 4096; m4 += 256) {
    float e[4][4] = {};
#pragma unroll
    for (int ch = 0; ch < 16; ++ch) {
      float4 kv = *(const float4*)(kp + (ch << 12) + m4);
#pragma unroll
      for (int j = 0; j < 4; ++j) {
        float qv = qreg[j][ch];
        e[j][0] = fmaf(qv, kv.x, e[j][0]);
        e[j][1] = fmaf(qv, kv.y, e[j][1]);
        e[j][2] = fmaf(qv, kv.z, e[j][2]);
        e[j][3] = fmaf(qv, kv.w, e[j][3]);
      }
    }
#pragma unroll
    for (int j = 0; j < 4; ++j) {
      float lm = fmaxf(fmaxf(e[j][0], e[j][1]), fmaxf(e[j][2], e[j][3]));
      float nm = fmaxf(mx[j], lm);
      se[j] = se[j] * __expf(mx[j] - nm)
            + __expf(e[j][0] - nm) + __expf(e[j][1] - nm)
            + __expf(e[j][2] - nm) + __expf(e[j][3] - nm);
      mx[j] = nm;
    }
  }
#pragma unroll
  for (int off = 32; off >= 1; off >>= 1) {
#pragma unroll
    for (int j = 0; j < 4; ++j) {
      float om = __shfl_xor(mx[j], off);
      float os = __shfl_xor(se[j], off);
      float nm = fmaxf(mx[j], om);
      se[j] = se[j] * __expf(mx[j] - nm) + os * __expf(om - nm);
      mx[j] = nm;
    }
  }
  if (lane == 0) {
#pragma unroll
    for (int j = 0; j < 4; ++j) {
      rmax[(b << 12) + n0 + j] = mx[j];
      rinv[(b << 12) + n0 + j] = 1.f / se[j];
    }
  }
}

// ---------------- K5: PAM PV, 512 thr, 32-n x 2048-m per block ---------------
__global__ __launch_bounds__(512, 4) void k_pam_pv(const float* __restrict__ qb,
    const float* __restrict__ kb, const u16* __restrict__ vt16,
    const float* __restrict__ rmax, const float* __restrict__ rinv,
    const float* __restrict__ gamma, float* __restrict__ pvpart) {
  constexpr int PSTR = 264;          // u16; odd 16B stride
  __shared__ float ks[2][16 * 256];  // [buf][ch][m]
  __shared__ u16 pL[32 * PSTR];      // [n][m] bf16
  int t = threadIdx.x;
  int b = blockIdx.y, n0 = blockIdx.x * 32;
  int mbeg = blockIdx.z << 11;       // 0 or 2048
  int lane = t & 63, wave = t >> 6;
  int nl = t & 31, mg = t >> 5;
  int mi = lane & 15, quad = lane >> 4;
  int c0 = wave * 16;
  float qreg[16];
  const float* qp = qb + ((size_t)b * 16 << 12) + n0 + nl;
#pragma unroll
  for (int ch = 0; ch < 16; ++ch) qreg[ch] = qp[ch << 12];
  float mv = rmax[(b << 12) + n0 + nl];
  float iv = rinv[(b << 12) + n0 + nl];
  const float* kpb = kb + ((size_t)b * 16 << 12) + mbeg;
  const u16* vb = vt16 + ((size_t)b * 128 << 12);
  f32x4 acc[2] = {};
#pragma unroll
  for (int k = 0; k < 8; ++k) {
    int idx = t + k * 512;
    ks[0][idx] = kpb[((idx >> 8) << 12) + (idx & 255)];
  }
  __syncthreads();
  int cur = 0;
  for (int it = 0; it < 8; ++it) {
    int m0 = mbeg + (it << 8);
    short8 vreg[8];
#pragma unroll
    for (int ksl = 0; ksl < 8; ++ksl)
      vreg[ksl] = *(const short8*)(vb + ((size_t)(c0 + mi) << 12) + m0 + ksl * 32 + quad * 8);
    float kreg[8];
    if (it < 7) {
#pragma unroll
      for (int k = 0; k < 8; ++k) {
        int idx = t + k * 512;
        kreg[k] = kpb[((idx >> 8) << 12) + ((it + 1) << 8) + (idx & 255)];
      }
    }
    float e[16] = {};
    const float* kbase = &ks[cur][mg << 4];
#pragma unroll
    for (int ch = 0; ch < 16; ++ch) {
      float qv = qreg[ch];
      const float* kp2 = kbase + (ch << 8);
      float4 kv0 = *(const float4*)(kp2);
      float4 kv1 = *(const float4*)(kp2 + 4);
      float4 kv2 = *(const float4*)(kp2 + 8);
      float4 kv3 = *(const float4*)(kp2 + 12);
      e[0] = fmaf(qv, kv0.x, e[0]);  e[1] = fmaf(qv, kv0.y, e[1]);
      e[2] = fmaf(qv, kv0.z, e[2]);  e[3] = fmaf(qv, kv0.w, e[3]);
      e[4] = fmaf(qv, kv1.x, e[4]);  e[5] = fmaf(qv, kv1.y, e[5]);
      e[6] = fmaf(qv, kv1.z, e[6]);  e[7] = fmaf(qv, kv1.w, e[7]);
      e[8] = fmaf(qv, kv2.x, e[8]);  e[9] = fmaf(qv, kv2.y, e[9]);
      e[10] = fmaf(qv, kv2.z, e[10]); e[11] = fmaf(qv, kv2.w, e[11]);
      e[12] = fmaf(qv, kv3.x, e[12]); e[13] = fmaf(qv, kv3.y, e[13]);
      e[14] = fmaf(qv, kv3.z, e[14]); e[15] = fmaf(qv, kv3.w, e[15]);
    }
    short8 p0, p1;
#pragma unroll
    for (int j = 0; j < 8; ++j) {
      p0[j] = (short)f2bf(__expf(fminf(e[j] - mv, 0.f)) * iv);
      p1[j] = (short)f2bf(__expf(fminf(e[j + 8] - mv, 0.f)) * iv);
    }
    {
      u16* pw = pL + nl * PSTR + (mg << 4);
      *(short8*)(pw) = p0;
      *(short8*)(pw + 8) = p1;
    }
    __syncthreads();
    if (it < 7) {
#pragma unroll
      for (int k = 0; k < 8; ++k) {
        int idx = t + k * 512;
        ks[cur ^ 1][idx] = kreg[k];
      }
    }
#pragma unroll
    for (int ksl = 0; ksl < 8; ++ksl) {
      const u16* pb0 = pL + mi * PSTR + ksl * 32 + quad * 8;
      short8 b0 = *(const short8*)(pb0);
      short8 b1 = *(const short8*)(pb0 + 16 * PSTR);
      acc[0] = __builtin_amdgcn_mfma_f32_16x16x32_bf16(vreg[ksl], b0, acc[0], 0, 0, 0);
      acc[1] = __builtin_amdgcn_mfma_f32_16x16x32_bf16(vreg[ksl], b1, acc[1], 0, 0, 0);
    }
    __syncthreads();
    cur ^= 1;
  }
  float g = gamma[0];
  float* dst = pvpart + (((size_t)(blockIdx.z * 2 + b) * 128) << 12);
#pragma unroll
  for (int nh = 0; nh < 2; ++nh)
#pragma unroll
    for (int r = 0; r < 4; ++r) {
      int c = c0 + quad * 4 + r;
      dst[((size_t)c << 12) + n0 + nh * 16 + mi] = g * acc[nh][r];
    }
}

// ---------------- K6a: CAM Gram energy via MFMA, split-bf16 ------------------
// grid (8 ti, 8 kc, 2 b), 512 thr; wave = col tile. K-chunk 512.
// acc = hi*hi + hi*lo + lo*hi (lo*lo dropped). Partials -> epart[kc][b][c][d].
__global__ __launch_bounds__(512) void k_cam_energy_m(
    const u16* __restrict__ sc16h, const u16* __restrict__ sc16l,
    float* __restrict__ epart) {
  int t = threadIdx.x;
  int ti = blockIdx.x, kc = blockIdx.y, b = blockIdx.z;
  int lane = t & 63, wave = t >> 6;
  int mi = lane & 15, quad = lane >> 4;
  const u16* fh = sc16h + ((size_t)b << 19);
  const u16* fl = sc16l + ((size_t)b << 19);
  size_t ao = ((size_t)(ti * 16 + mi) << 12) + (kc << 9) + quad * 8;
  size_t bo = ((size_t)(wave * 16 + mi) << 12) + (kc << 9) + quad * 8;
  const u16* ah = fh + ao; const u16* al = fl + ao;
  const u16* bh = fh + bo; const u16* bl = fl + bo;
  f32x4 acc = {};
#pragma unroll
  for (int k = 0; k < 16; ++k) {
    short8 vah = *(const short8*)(ah + k * 32);
    short8 val = *(const short8*)(al + k * 32);
    short8 vbh = *(const short8*)(bh + k * 32);
    short8 vbl = *(const short8*)(bl + k * 32);
    acc = __builtin_amdgcn_mfma_f32_16x16x32_bf16(vah, vbh, acc, 0, 0, 0);
    acc = __builtin_amdgcn_mfma_f32_16x16x32_bf16(vah, vbl, acc, 0, 0, 0);
    acc = __builtin_amdgcn_mfma_f32_16x16x32_bf16(val, vbh, acc, 0, 0, 0);
  }
  float* ep = epart + (((size_t)(kc * 2 + b)) << 14);
#pragma unroll
  for (int r = 0; r < 4; ++r)
    ep[((ti * 16 + quad * 4 + r) << 7) + wave * 16 + mi] = acc[r];
}

// ---------------- K6b: CAM softmax row (reduce 8 partials) -------------------
__global__ void k_cam_softmax(const float* __restrict__ epart, float* __restrict__ attn) {
  int lane = threadIdx.x;
  int c = blockIdx.x, b = blockIdx.y;
  float e0 = 0.f, e1 = 0.f;
#pragma unroll
  for (int kc = 0; kc < 8; ++kc) {
    const float* ep = epart + (((size_t)(kc * 2 + b)) << 14) + (c << 7);
    e0 += ep[lane];
    e1 += ep[lane + 64];
  }
  float mn = fminf(e0, e1);
#pragma unroll
  for (int off = 32; off >= 1; off >>= 1) mn = fminf(mn, __shfl_xor(mn, off));
  float p0 = __expf(fminf(mn - e0, 0.f)), p1 = __expf(fminf(mn - e1, 0.f));
  float s = p0 + p1;
#pragma unroll
  for (int off = 32; off >= 1; off >>= 1) s += __shfl_xor(s, off);
  float inv = 1.f / s;
  float* a = attn + ((b * 128 + c) << 7);
  a[lane] = p0 * inv;
  a[lane + 64] = p1 * inv;
}

// ---------------- K7: CAM out + residual -------------------------------------
__global__ __launch_bounds__(256) void k_cam_out(const float* __restrict__ f,
    const float* __restrict__ attn, const float* __restrict__ gamma,
    float* __restrict__ sc1) {
  __shared__ float at2[128 * 16];
  int t = threadIdx.x;
  int b = blockIdx.z, c0 = blockIdx.y * 16;
  int n = blockIdx.x * 256 + t;
  for (int idx = t; idx < 2048; idx += 256) {
    int d = idx >> 4, cc = idx & 15;
    at2[idx] = attn[((b * 128 + c0 + cc) << 7) + d];
  }
  __syncthreads();
  float acc[16] = {};
  const float* fb = f + ((size_t)b * 128 << 12) + n;
  for (int d = 0; d < 128; ++d) {
    float fv = fb[d << 12];
    const float* ap = at2 + d * 16;
#pragma unroll
    for (int cc = 0; cc < 16; ++cc) acc[cc] = fmaf(ap[cc], fv, acc[cc]);
  }
  float g = gamma[0];
#pragma unroll
  for (int cc = 0; cc < 16; ++cc) {
    size_t o = ((size_t)(b * 128 + c0 + cc) << 12) + n;
    sc1[o] = fmaf(g, acc[cc], f[o]);
  }
}

// ---------------- K8: BN+ReLU + 1x1 conv 128->512 via MFMA -------------------
__global__ __launch_bounds__(256, 2) void k_bout_m(
    const float* __restrict__ sa0, const float* __restrict__ pvpart,
    const float* __restrict__ sc1,
    const float* __restrict__ wa_, const float* __restrict__ ba_,
    const float* __restrict__ ma_, const float* __restrict__ va_,
    const float* __restrict__ wc_, const float* __restrict__ bc_,
    const float* __restrict__ mc_, const float* __restrict__ vc_,
    const u16* __restrict__ W1b, const float* __restrict__ Ba,
    const float* __restrict__ Bc,
    u16* __restrict__ sa2, u16* __restrict__ sc2) {
  __shared__ u16 xl[32 * 136];
  __shared__ float scl[128], shf[128];
  int t = threadIdx.x;
  int n0 = blockIdx.x * 32;
  int b = blockIdx.y, br = blockIdx.z;
  const float* bw = br ? wc_ : wa_;
  const float* bb = br ? bc_ : ba_;
  const float* bm = br ? mc_ : ma_;
  const float* bvv = br ? vc_ : va_;
  if (t < 128) {
    float s = bw[t] * rsqrtf(bvv[t] + 1e-5f);
    scl[t] = s;
    shf[t] = bb[t] - bm[t] * s;
  }
  __syncthreads();
  {
    int nl = t & 31, cio = t >> 5;
    const float* s0 = (br ? sc1 : sa0) + ((size_t)b * 128 << 12) + n0 + nl;
    const float* p0 = pvpart + ((size_t)b * 128 << 12) + n0 + nl;
    const float* p1 = pvpart + (((size_t)(2 + b) * 128) << 12) + n0 + nl;
#pragma unroll
    for (int half = 0; half < 2; ++half) {
      short8 v;
#pragma unroll
      for (int i = 0; i < 8; ++i) {
        int ci = cio * 16 + half * 8 + i;
        float xv = s0[(size_t)ci << 12];
        if (!br) xv += p0[(size_t)ci << 12] + p1[(size_t)ci << 12];
        v[i] = (short)f2bf(fmaxf(fmaf(xv, scl[ci], shf[ci]), 0.f));
      }
      *(short8*)(xl + nl * 136 + cio * 16 + half * 8) = v;
    }
  }
  __syncthreads();
  int lane = t & 63, wave = t >> 6;
  int mi = lane & 15, quad = lane >> 4;
  const u16* wb = W1b + (size_t)br * 65536 + lane * 8;
  f32x4 acc[8][2] = {};
#pragma unroll
  for (int ks = 0; ks < 4; ++ks) {
    short8 b0 = *(const short8*)(xl + mi * 136 + ks * 32 + quad * 8);
    short8 b1 = *(const short8*)(xl + (16 + mi) * 136 + ks * 32 + quad * 8);
#pragma unroll
    for (int ct = 0; ct < 8; ++ct) {
      int cot = wave * 8 + ct;
      short8 a = *(const short8*)(wb + ((size_t)(cot * 4 + ks) << 9));
      acc[ct][0] = __builtin_amdgcn_mfma_f32_16x16x32_bf16(a, b0, acc[ct][0], 0, 0, 0);
      acc[ct][1] = __builtin_amdgcn_mfma_f32_16x16x32_bf16(a, b1, acc[ct][1], 0, 0, 0);
    }
  }
  const float* Bs = br ? Bc : Ba;
  u16* dst = br ? sc2 : sa2;
#pragma unroll
  for (int ct = 0; ct < 8; ++ct)
#pragma unroll
    for (int nh = 0; nh < 2; ++nh)
#pragma unroll
      for (int r = 0; r < 4; ++r) {
        int co = (wave * 8 + ct) * 16 + quad * 4 + r;
        dst[((size_t)(b * 512 + co) << 12) + n0 + nh * 16 + mi] =
            f2bf(acc[ct][nh][r] + Bs[co]);
      }
}

// ---------------- K9a: fusion + partial class-head sums (8-way c split) ------
__global__ __launch_bounds__(256) void k_heads(const u16* __restrict__ sa2,
    const u16* __restrict__ sc2,
    const float* __restrict__ wf, const float* __restrict__ wa, const float* __restrict__ wc,
    float* __restrict__ outFusion, float* __restrict__ clsacc) {
  __shared__ float lw[3 * 5 * 64];
  int t = threadIdx.x;
  int b = blockIdx.y, co0 = blockIdx.z * 64;
  int n = blockIdx.x * 256 + t;
  for (int idx = t; idx < 960; idx += 256) {
    int arr = idx / 320, rest = idx - arr * 320;
    int cls = rest >> 6, cc = rest & 63;
    const float* w = arr == 0 ? wf : (arr == 1 ? wa : wc);
    lw[idx] = w[cls * 512 + co0 + cc];
  }
  __syncthreads();
  float af[5] = {}, aa[5] = {}, ac[5] = {};
  for (int cc = 0; cc < 64; ++cc) {
    size_t o = ((size_t)(b * 512 + co0 + cc) << 12) + n;
    float a = bf2f(sa2[o]), c = bf2f(sc2[o]);
    float s = a + c;
    outFusion[o] = s;
#pragma unroll
    for (int cls = 0; cls < 5; ++cls) {
      af[cls] = fmaf(lw[0 * 320 + cls * 64 + cc], s, af[cls]);
      aa[cls] = fmaf(lw[1 * 320 + cls * 64 + cc], a, aa[cls]);
      ac[cls] = fmaf(lw[2 * 320 + cls * 64 + cc], c, ac[cls]);
    }
  }
#pragma unroll
  for (int cls = 0; cls < 5; ++cls) {
    int o = ((b * 5 + cls) << 12) + n;
    atomicAdd(&clsacc[o], af[cls]);
    atomicAdd(&clsacc[40960 + o], aa[cls]);
    atomicAdd(&clsacc[81920 + o], ac[cls]);
  }
}

// ---------------- K9b: add bias, f32 out -------------------------------------
__global__ void k_heads_final(const float* __restrict__ clsacc,
    const float* __restrict__ bf_, const float* __restrict__ ba_,
    const float* __restrict__ bc_, float* __restrict__ outCls) {
  int idx = blockIdx.x * 256 + threadIdx.x;   // 122880
  int arr = idx / 40960;
  int rest = idx - arr * 40960;
  int cls = (rest >> 12) % 5;
  const float* bp = arr == 0 ? bf_ : (arr == 1 ? ba_ : bc_);
  outCls[idx] = clsacc[idx] + bp[cls];
}

extern "C" void kernel_launch(void* const* d_in, const int* in_sizes, int n_in,
                              void* d_out, int out_size, void* d_ws, size_t ws_size,
                              hipStream_t stream) {
  (void)in_sizes; (void)n_in; (void)out_size; (void)ws_size;
  const float* x      = (const float*)d_in[0];
  const float* bnaw   = (const float*)d_in[1];
  const float* bnab   = (const float*)d_in[2];
  const float* bnam   = (const float*)d_in[3];
  const float* bnav   = (const float*)d_in[4];
  const float* convaw = (const float*)d_in[5];
  const float* bncw   = (const float*)d_in[6];
  const float* bncb   = (const float*)d_in[7];
  const float* bncm   = (const float*)d_in[8];
  const float* bncv   = (const float*)d_in[9];
  const float* convcw = (const float*)d_in[10];
  const float* pqw    = (const float*)d_in[11];
  const float* pqb    = (const float*)d_in[12];
  const float* pkw    = (const float*)d_in[13];
  const float* pkb    = (const float*)d_in[14];
  const float* pvw    = (const float*)d_in[15];
  const float* pvb    = (const float*)d_in[16];
  const float* pgam   = (const float*)d_in[17];
  const float* cgam   = (const float*)d_in[18];
  const float* bna1w  = (const float*)d_in[19];
  const float* bna1b  = (const float*)d_in[20];
  const float* bna1m  = (const float*)d_in[21];
  const float* bna1v  = (const float*)d_in[22];
  const float* conva1w = (const float*)d_in[23];
  const float* conva1b = (const float*)d_in[24];
  const float* bnc1w  = (const float*)d_in[25];
  const float* bnc1b  = (const float*)d_in[26];
  const float* bnc1m  = (const float*)d_in[27];
  const float* bnc1v  = (const float*)d_in[28];
  const float* convc1w = (const float*)d_in[29];
  const float* convc1b = (const float*)d_in[30];
  const float* outaw  = (const float*)d_in[31];
  const float* outab  = (const float*)d_in[32];
  const float* outcw  = (const float*)d_in[33];
  const float* outcb  = (const float*)d_in[34];
  const float* outfw  = (const float*)d_in[35];
  const float* outfb  = (const float*)d_in[36];

  char* wsb = (char*)d_ws;
  size_t off = 0;
  auto take = [&](size_t bytes) -> void* {
    void* p = wsb + off;
    off += (bytes + 255) & ~(size_t)255;
    return p;
  };
  u16*   Wb    = (u16*)take((size_t)2 * 128 * 9 * 512 * 2);
  u16*   W1b   = (u16*)take((size_t)2 * 512 * 128 * 2);
  u16*   Wqkvb = (u16*)take((size_t)160 * 128 * 2);
  u16*   xa16  = (u16*)take((size_t)2 * 512 * 4096 * 2);
  u16*   xcb16 = (u16*)take((size_t)2 * 512 * 4096 * 2);
  float* sa0   = (float*)take((size_t)2 * 128 * 4096 * 4);
  float* sc0   = (float*)take((size_t)2 * 128 * 4096 * 4);
  u16*   sa_nhwc = (u16*)take((size_t)2 * 4096 * 128 * 2);
  u16*   sc16h = (u16*)take((size_t)2 * 128 * 4096 * 2);
  u16*   sc16l = (u16*)take((size_t)2 * 128 * 4096 * 2);
  float* qb    = (float*)take((size_t)2 * 16 * 4096 * 4);
  float* kbuf  = (float*)take((size_t)2 * 16 * 4096 * 4);
  u16*   vt16  = (u16*)take((size_t)2 * 128 * 4096 * 2);
  float* rmax  = (float*)take((size_t)2 * 4096 * 4);
  float* rinv  = (float*)take((size_t)2 * 4096 * 4);
  float* pvpart = (float*)take((size_t)2 * 2 * 128 * 4096 * 4);
  float* sc1   = (float*)take((size_t)2 * 128 * 4096 * 4);
  float* epart = (float*)take((size_t)8 * 2 * 128 * 128 * 4);
  float* attn  = (float*)take((size_t)2 * 128 * 128 * 4);
  u16*   sa2   = (u16*)take((size_t)2 * 512 * 4096 * 2);
  u16*   sc2   = (u16*)take((size_t)2 * 512 * 4096 * 2);
  float* clsacc = (float*)take((size_t)3 * 2 * 5 * 4096 * 4);

  float* outF = (float*)d_out;
  float* outCls = outF + (size_t)2 * 512 * 4096;

  hipMemsetAsync(clsacc, 0, (size_t)3 * 2 * 5 * 4096 * 4, stream);

  k_prep_w<<<4608, 256, 0, stream>>>(convaw, convcw, Wb);
  k_prep_w1<<<512, 256, 0, stream>>>(conva1w, convc1w, W1b);
  k_prep_wqkv<<<80, 256, 0, stream>>>(pqw, pkw, pvw, Wqkvb);
  k_bnrelu2t<<<dim3(64, 2), 256, 0, stream>>>(x, bnaw, bnab, bnam, bnav,
                                              bncw, bncb, bncm, bncv, xa16, xcb16);
  k_conv3n<<<dim3(64, 4), 256, 0, stream>>>(xa16, xcb16, Wb, sa0, sc0,
                                            sa_nhwc, sc16h, sc16l);
  k_qkv<<<dim3(32, 2), 256, 0, stream>>>(sa_nhwc, Wqkvb, pqb, pkb, pvb,
                                         qb, kbuf, vt16);
  k_pam_stats<<<dim3(256, 2), 256, 0, stream>>>(qb, kbuf, rmax, rinv);
  k_pam_pv<<<dim3(128, 2, 2), 512, 0, stream>>>(qb, kbuf, vt16, rmax, rinv, pgam, pvpart);
  k_cam_energy_m<<<dim3(8, 8, 2), 512, 0, stream>>>(sc16h, sc16l, epart);
  k_cam_softmax<<<dim3(128, 2), 64, 0, stream>>>(epart, attn);
  k_cam_out<<<dim3(16, 8, 2), 256, 0, stream>>>(sc0, attn, cgam, sc1);
  k_bout_m<<<dim3(128, 2, 2), 256, 0, stream>>>(sa0, pvpart, sc1,
      bna1w, bna1b, bna1m, bna1v, bnc1w, bnc1b, bnc1m, bnc1v,
      W1b, conva1b, convc1b, sa2, sc2);
  k_heads<<<dim3(16, 2, 8), 256, 0, stream>>>(sa2, sc2, outfw, outaw, outcw, outF, clsacc);
  k_heads_final<<<480, 256, 0, stream>>>(clsacc, outfb, outab, outcb, outCls);
}

// Round 6
// 347.137 us; speedup vs baseline: 1.6573x; 1.0078x over previous
//
#include <hip/hip_runtime.h>

using u16 = unsigned short;
using short8 = __attribute__((ext_vector_type(8))) short;
using f32x4 = __attribute__((ext_vector_type(4))) float;

struct alignas(8) U16x4 { u16 x, y, z, w; };

__device__ __forceinline__ float bf2f(u16 u) {
  return __uint_as_float(((unsigned int)u) << 16);
}
__device__ __forceinline__ u16 f2bf(float f) {
  unsigned int u = __float_as_uint(f);
  unsigned int r = u + 0x7FFFu + ((u >> 16) & 1u);
  return (u16)(r >> 16);
}

// ---------------- K0b: conv weights -> bf16, MFMA-fragment order -------------
// Layout: [br][mt(8)][chunk(4)][tap(9)][ks(4)][lane(64)][j(8)]
__global__ void k_prep_w(const float* __restrict__ wa, const float* __restrict__ wc,
                         u16* __restrict__ Wb) {
  int idx = blockIdx.x * 256 + threadIdx.x;   // 1179648
  int j = idx & 7;
  int l = (idx >> 3) & 63;
  int ks = (idx >> 9) & 3;
  int rest = idx >> 11;
  int tap = rest % 9;
  int rest2 = rest / 9;
  int chunk = rest2 & 3;
  int mt = (rest2 >> 2) & 7;
  int br = rest2 >> 5;
  int co = mt * 16 + (l & 15);
  int ci = chunk * 128 + ks * 32 + (l >> 4) * 8 + j;
  const float* w = br ? wc : wa;
  Wb[idx] = f2bf(w[co * 4608 + ci * 9 + tap]);
}

// ---------------- K0c: 1x1 out-conv weights (128->512) -> bf16 A-frag order --
__global__ void k_prep_w1(const float* __restrict__ wa, const float* __restrict__ wc,
                          u16* __restrict__ W1b) {
  int idx = blockIdx.x * 256 + threadIdx.x;   // 131072
  int j = idx & 7;
  int l = (idx >> 3) & 63;
  int ks = (idx >> 9) & 3;
  int cot = (idx >> 11) & 31;
  int br = idx >> 16;
  int co = cot * 16 + (l & 15);
  int ci = ks * 32 + (l >> 4) * 8 + j;
  const float* w = br ? wc : wa;
  W1b[idx] = f2bf(w[co * 128 + ci]);
}

// ---------------- K0d: qkv weights (160x128) -> bf16 A-frag order ------------
// rows 0-15: wq, 16-31: wk, 32-159: wv. [cot(10)][ks(4)][lane(64)][j(8)]
__global__ void k_prep_wqkv(const float* __restrict__ wq, const float* __restrict__ wk,
                            const float* __restrict__ wv, u16* __restrict__ Wq) {
  int idx = blockIdx.x * 256 + threadIdx.x;   // 20480
  if (idx >= 20480) return;
  int j = idx & 7;
  int l = (idx >> 3) & 63;
  int ks = (idx >> 9) & 3;
  int cot = idx >> 11;
  int co = cot * 16 + (l & 15);
  int ci = ks * 32 + (l >> 4) * 8 + j;
  float w = co < 16 ? wq[co * 128 + ci]
          : (co < 32 ? wk[(co - 16) * 128 + ci] : wv[(co - 32) * 128 + ci]);
  Wq[idx] = f2bf(w);
}

// ---------------- K1: BN+ReLU both branches, NHWC bf16 out -------------------
__global__ __launch_bounds__(256) void k_bnrelu2t(const float* __restrict__ x,
    const float* __restrict__ wa, const float* __restrict__ ba,
    const float* __restrict__ ma, const float* __restrict__ va,
    const float* __restrict__ wc, const float* __restrict__ bc,
    const float* __restrict__ mc, const float* __restrict__ vc,
    u16* __restrict__ xa16, u16* __restrict__ xcb16) {
  __shared__ float sA[512], bA[512], sC[512], bC[512];
  __shared__ u16 ta[64 * 136], tc[64 * 136];
  int t = threadIdx.x;
  int h = blockIdx.x, b = blockIdx.y;
  for (int c = t; c < 512; c += 256) {
    float s1 = wa[c] * rsqrtf(va[c] + 1e-5f);
    sA[c] = s1; bA[c] = ba[c] - ma[c] * s1;
    float s2 = wc[c] * rsqrtf(vc[c] + 1e-5f);
    sC[c] = s2; bC[c] = bc[c] - mc[c] * s2;
  }
  __syncthreads();
  const float* xb = x + ((size_t)b << 21) + (h << 6);
  u16* oa = xa16 + ((size_t)b << 21) + ((size_t)h << 15);
  u16* oc = xcb16 + ((size_t)b << 21) + ((size_t)h << 15);
  int w = t & 63, cg = t >> 6;
  for (int c0 = 0; c0 < 512; c0 += 128) {
#pragma unroll
    for (int i = 0; i < 8; ++i) {
      int cl = cg * 4 + i * 16;
      int c = c0 + cl;
      const float* xp = xb + (size_t)c * 4096 + w;
      float v0 = xp[0], v1 = xp[4096], v2 = xp[8192], v3 = xp[12288];
      U16x4 pa, pc;
      pa.x = f2bf(fmaxf(fmaf(v0, sA[c], bA[c]), 0.f));
      pa.y = f2bf(fmaxf(fmaf(v1, sA[c + 1], bA[c + 1]), 0.f));
      pa.z = f2bf(fmaxf(fmaf(v2, sA[c + 2], bA[c + 2]), 0.f));
      pa.w = f2bf(fmaxf(fmaf(v3, sA[c + 3], bA[c + 3]), 0.f));
      pc.x = f2bf(fmaxf(fmaf(v0, sC[c], bC[c]), 0.f));
      pc.y = f2bf(fmaxf(fmaf(v1, sC[c + 1], bC[c + 1]), 0.f));
      pc.z = f2bf(fmaxf(fmaf(v2, sC[c + 2], bC[c + 2]), 0.f));
      pc.w = f2bf(fmaxf(fmaf(v3, sC[c + 3], bC[c + 3]), 0.f));
      *(U16x4*)(ta + w * 136 + cl) = pa;
      *(U16x4*)(tc + w * 136 + cl) = pc;
    }
    __syncthreads();
#pragma unroll
    for (int i = 0; i < 4; ++i) {
      int idx = t + i * 256;
      int ww = idx >> 4, c8 = (idx & 15) << 3;
      *(short8*)(oa + (size_t)ww * 512 + c0 + c8) = *(const short8*)(ta + ww * 136 + c8);
      *(short8*)(oc + (size_t)ww * 512 + c0 + c8) = *(const short8*)(tc + ww * 136 + c8);
    }
    __syncthreads();
  }
}

// ---------------- K2: 3x3 conv, implicit GEMM, NHWC input --------------------
// grid (64 h, 4 bz, 2 cosplit): 512 blocks = 2 blocks/CU (8 waves/CU).
// Wave w -> single 16-co m-tile mt = cosplit*4 + w. Weights software-pipelined
// one tap ahead in registers. Extra outputs as before (per-co-slice).
__global__ __launch_bounds__(256, 2) void k_conv3n(
    const u16* __restrict__ xa16, const u16* __restrict__ xcb16,
    const u16* __restrict__ Wb,
    float* __restrict__ sa0, float* __restrict__ sc0,
    u16* __restrict__ sa_nhwc, u16* __restrict__ sc16h, u16* __restrict__ sc16l) {
  __shared__ u16 xs[3 * 66 * 136];
  int t = threadIdx.x;
  int h = blockIdx.x;
  int z = blockIdx.y; int b = z & 1, br = z >> 1;
  int cosplit = blockIdx.z;
  const u16* xb = (br ? xcb16 : xa16) + ((size_t)b << 21);
  const u16* wb = Wb + (size_t)br * 589824;
  float* out = (br ? sc0 : sa0) + (((size_t)b * 128) << 12) + (h << 6);

  int lane = t & 63, wave = t >> 6;
  int mi = lane & 15, quad = lane >> 4;
  int mt = cosplit * 4 + wave;     // this wave's 16-co tile

  if (t < 96) {
    int dh = t >> 5, side = (t >> 4) & 1, c8 = t & 15;
    short8 z8 = {0, 0, 0, 0, 0, 0, 0, 0};
    *(short8*)(xs + (dh * 66 + side * 65) * 136 + c8 * 8) = z8;
  }

  f32x4 acc[4] = {};

  const u16* wlane = wb + lane * 8;
  const u16* bbase0 = xs + mi * 136 + quad * 8;

  for (int chunk = 0; chunk < 4; ++chunk) {
    int ci0 = chunk << 7;
    __syncthreads();
#pragma unroll
    for (int dh = 0; dh < 3; ++dh) {
      int hh = h + dh - 1;
      bool val = (hh >= 0) && (hh < 64);
      const u16* src = xb + (((size_t)hh << 6) << 9) + ci0;
#pragma unroll
      for (int i = 0; i < 4; ++i) {
        int idx = t + i * 256;
        int w = idx >> 4, c8 = (idx & 15) << 3;
        short8 v = {0, 0, 0, 0, 0, 0, 0, 0};
        if (val) v = *(const short8*)(src + ((size_t)w << 9) + c8);
        *(short8*)(xs + (dh * 66 + 1 + w) * 136 + c8) = v;
      }
    }
    __syncthreads();
    // [mt][chunk][tap][ks] element offset = (((mt*4+chunk)*9+tap)*4+ks)*512
    const u16* wchunk = wlane + (size_t)(mt * 4 + chunk) * 18432;
    short8 wreg[2][4];
#pragma unroll
    for (int ks = 0; ks < 4; ++ks)
      wreg[0][ks] = *(const short8*)(wchunk + ks * 512);
#pragma unroll
    for (int tap = 0; tap < 9; ++tap) {
      const int cb = tap & 1;
      if (tap < 8) {
        const u16* wn = wchunk + (tap + 1) * 2048;
#pragma unroll
        for (int ks = 0; ks < 4; ++ks)
          wreg[cb ^ 1][ks] = *(const short8*)(wn + ks * 512);
      }
      const int dh = tap / 3, dw = tap % 3;
      const u16* bp = bbase0 + (dh * 66 + dw) * 136;
#pragma unroll
      for (int ks = 0; ks < 4; ++ks) {
        short8 a = wreg[cb][ks];
#pragma unroll
        for (int nt = 0; nt < 4; ++nt) {
          short8 bf = *(const short8*)(bp + nt * 2176 + ks * 32);
          acc[nt] = __builtin_amdgcn_mfma_f32_16x16x32_bf16(a, bf, acc[nt], 0, 0, 0);
        }
      }
    }
  }
#pragma unroll
  for (int nt = 0; nt < 4; ++nt)
#pragma unroll
    for (int r = 0; r < 4; ++r) {
      int co = mt * 16 + quad * 4 + r;
      out[((size_t)co << 12) + nt * 16 + mi] = acc[nt][r];
    }
  if (br == 0) {
    // NHWC bf16: sa_nhwc[(b*4096 + h*64 + n)*128 + co]
    u16* dstq = sa_nhwc + ((size_t)b << 19) + ((size_t)h << 6) * 128;
#pragma unroll
    for (int nt = 0; nt < 4; ++nt) {
      U16x4 v4;
      v4.x = f2bf(acc[nt][0]); v4.y = f2bf(acc[nt][1]);
      v4.z = f2bf(acc[nt][2]); v4.w = f2bf(acc[nt][3]);
      *(U16x4*)(dstq + (size_t)(nt * 16 + mi) * 128 + mt * 16 + quad * 4) = v4;
    }
  } else {
    // split-bf16 [c][n]
    u16* dh_ = sc16h + ((size_t)b << 19) + (h << 6);
    u16* dl_ = sc16l + ((size_t)b << 19) + (h << 6);
#pragma unroll
    for (int nt = 0; nt < 4; ++nt)
#pragma unroll
      for (int r = 0; r < 4; ++r) {
        int co = mt * 16 + quad * 4 + r;
        float xv = acc[nt][r];
        u16 hi = f2bf(xv);
        float lo = xv - bf2f(hi);
        size_t o = ((size_t)co << 12) + nt * 16 + mi;
        dh_[o] = hi;
        dl_[o] = f2bf(lo);
      }
  }
}

// ---------------- K3: fused q,k,v 1x1 convs via MFMA -------------------------
__global__ __launch_bounds__(256) void k_qkv(
    const u16* __restrict__ sa_nhwc, const u16* __restrict__ Wqkvb,
    const float* __restrict__ bq, const float* __restrict__ bk,
    const float* __restrict__ bv,
    float* __restrict__ qb, float* __restrict__ kbuf, u16* __restrict__ vt16) {
  __shared__ float bs[160];
  int t = threadIdx.x;
  int b = blockIdx.y, n0 = blockIdx.x * 128;
  if (t < 160) bs[t] = t < 16 ? bq[t] : (t < 32 ? bk[t - 16] : bv[t - 32]);
  __syncthreads();
  int lane = t & 63, wave = t >> 6;
  int mi = lane & 15, quad = lane >> 4;
  const u16* xb = sa_nhwc + ((size_t)b << 19) + (size_t)n0 * 128;
  const u16* wb = Wqkvb + lane * 8;
  f32x4 acc[2][10] = {};
  short8 bf[2][4];
#pragma unroll
  for (int ns = 0; ns < 2; ++ns) {
    int n = wave * 32 + ns * 16 + mi;
#pragma unroll
    for (int ks = 0; ks < 4; ++ks)
      bf[ns][ks] = *(const short8*)(xb + (size_t)n * 128 + ks * 32 + quad * 8);
  }
#pragma unroll
  for (int cot = 0; cot < 10; ++cot) {
    short8 a0 = *(const short8*)(wb + (size_t)(cot * 4 + 0) * 512);
    short8 a1 = *(const short8*)(wb + (size_t)(cot * 4 + 1) * 512);
    short8 a2 = *(const short8*)(wb + (size_t)(cot * 4 + 2) * 512);
    short8 a3 = *(const short8*)(wb + (size_t)(cot * 4 + 3) * 512);
#pragma unroll
    for (int ns = 0; ns < 2; ++ns) {
      acc[ns][cot] = __builtin_amdgcn_mfma_f32_16x16x32_bf16(a0, bf[ns][0], acc[ns][cot], 0, 0, 0);
      acc[ns][cot] = __builtin_amdgcn_mfma_f32_16x16x32_bf16(a1, bf[ns][1], acc[ns][cot], 0, 0, 0);
      acc[ns][cot] = __builtin_amdgcn_mfma_f32_16x16x32_bf16(a2, bf[ns][2], acc[ns][cot], 0, 0, 0);
      acc[ns][cot] = __builtin_amdgcn_mfma_f32_16x16x32_bf16(a3, bf[ns][3], acc[ns][cot], 0, 0, 0);
    }
  }
#pragma unroll
  for (int cot = 0; cot < 10; ++cot)
#pragma unroll
    for (int ns = 0; ns < 2; ++ns)
#pragma unroll
      for (int r = 0; r < 4; ++r) {
        int co = cot * 16 + quad * 4 + r;
        int n = n0 + wave * 32 + ns * 16 + mi;
        float v = acc[ns][cot][r] + bs[co];
        if (co < 16) qb[((b * 16 + co) << 12) + n] = v;
        else if (co < 32) kbuf[((b * 16 + co - 16) << 12) + n] = v;
        else vt16[((size_t)(b * 128 + co - 32) << 12) + n] = f2bf(v);
      }
}

// ---------------- K4: PAM softmax row stats; 4 n per lane, 16 n per block ----
__global__ __launch_bounds__(256) void k_pam_stats(const float* __restrict__ qb,
    const float* __restrict__ kb, float* __restrict__ rmax, float* __restrict__ rinv) {
  int t = threadIdx.x, lane = t & 63, wid = t >> 6;
  int b = blockIdx.y;
  int n0 = blockIdx.x * 16 + wid * 4;
  float qreg[4][16];
  const float* qp = qb + ((size_t)b * 16 << 12) + n0;
#pragma unroll
  for (int ch = 0; ch < 16; ++ch)
#pragma unroll
    for (int j = 0; j < 4; ++j) qreg[j][ch] = qp[(ch << 12) + j];
  const float* kp = kb + ((size_t)b * 16 << 12);
  float mx[4], se[4];
#pragma unroll
  for (int j = 0; j < 4; ++j) { mx[j] = -1e30f; se[j] = 0.f; }
  for (int m4 = lane * 4; m4 < 4096; m4 += 256) {
    float e[4][4] = {};
#pragma unroll
    for (int ch = 0; ch < 16; ++ch) {
      float4 kv = *(const float4*)(kp + (ch << 12) + m4);
#pragma unroll
      for (int j = 0; j < 4; ++j) {
        float qv = qreg[j][ch];
        e[j][0] = fmaf(qv, kv.x, e[j][0]);
        e[j][1] = fmaf(qv, kv.y, e[j][1]);
        e[j][2] = fmaf(qv, kv.z, e[j][2]);
        e[j][3] = fmaf(qv, kv.w, e[j][3]);
      }
    }
#pragma unroll
    for (int j = 0; j < 4; ++j) {
      float lm = fmaxf(fmaxf(e[j][0], e[j][1]), fmaxf(e[j][2], e[j][3]));
      float nm = fmaxf(mx[j], lm);
      se[j] = se[j] * __expf(mx[j] - nm)
            + __expf(e[j][0] - nm) + __expf(e[j][1] - nm)
            + __expf(e[j][2] - nm) + __expf(e[j][3] - nm);
      mx[j] = nm;
    }
  }
#pragma unroll
  for (int off = 32; off >= 1; off >>= 1) {
#pragma unroll
    for (int j = 0; j < 4; ++j) {
      float om = __shfl_xor(mx[j], off);
      float os = __shfl_xor(se[j], off);
      float nm = fmaxf(mx[j], om);
      se[j] = se[j] * __expf(mx[j] - nm) + os * __expf(om - nm);
      mx[j] = nm;
    }
  }
  if (lane == 0) {
#pragma unroll
    for (int j = 0; j < 4; ++j) {
      rmax[(b << 12) + n0 + j] = mx[j];
      rinv[(b << 12) + n0 + j] = 1.f / se[j];
    }
  }
}

// ---------------- K5: PAM PV, 512 thr, 32-n x 2048-m per block ---------------
__global__ __launch_bounds__(512, 4) void k_pam_pv(const float* __restrict__ qb,
    const float* __restrict__ kb, const u16* __restrict__ vt16,
    const float* __restrict__ rmax, const float* __restrict__ rinv,
    const float* __restrict__ gamma, float* __restrict__ pvpart) {
  constexpr int PSTR = 264;          // u16; odd 16B stride
  __shared__ float ks[2][16 * 256];  // [buf][ch][m]
  __shared__ u16 pL[32 * PSTR];      // [n][m] bf16
  int t = threadIdx.x;
  int b = blockIdx.y, n0 = blockIdx.x * 32;
  int mbeg = blockIdx.z << 11;       // 0 or 2048
  int lane = t & 63, wave = t >> 6;
  int nl = t & 31, mg = t >> 5;
  int mi = lane & 15, quad = lane >> 4;
  int c0 = wave * 16;
  float qreg[16];
  const float* qp = qb + ((size_t)b * 16 << 12) + n0 + nl;
#pragma unroll
  for (int ch = 0; ch < 16; ++ch) qreg[ch] = qp[ch << 12];
  float mv = rmax[(b << 12) + n0 + nl];
  float iv = rinv[(b << 12) + n0 + nl];
  const float* kpb = kb + ((size_t)b * 16 << 12) + mbeg;
  const u16* vb = vt16 + ((size_t)b * 128 << 12);
  f32x4 acc[2] = {};
#pragma unroll
  for (int k = 0; k < 8; ++k) {
    int idx = t + k * 512;
    ks[0][idx] = kpb[((idx >> 8) << 12) + (idx & 255)];
  }
  __syncthreads();
  int cur = 0;
  for (int it = 0; it < 8; ++it) {
    int m0 = mbeg + (it << 8);
    short8 vreg[8];
#pragma unroll
    for (int ksl = 0; ksl < 8; ++ksl)
      vreg[ksl] = *(const short8*)(vb + ((size_t)(c0 + mi) << 12) + m0 + ksl * 32 + quad * 8);
    float kreg[8];
    if (it < 7) {
#pragma unroll
      for (int k = 0; k < 8; ++k) {
        int idx = t + k * 512;
        kreg[k] = kpb[((idx >> 8) << 12) + ((it + 1) << 8) + (idx & 255)];
      }
    }
    float e[16] = {};
    const float* kbase = &ks[cur][mg << 4];
#pragma unroll
    for (int ch = 0; ch < 16; ++ch) {
      float qv = qreg[ch];
      const float* kp2 = kbase + (ch << 8);
      float4 kv0 = *(const float4*)(kp2);
      float4 kv1 = *(const float4*)(kp2 + 4);
      float4 kv2 = *(const float4*)(kp2 + 8);
      float4 kv3 = *(const float4*)(kp2 + 12);
      e[0] = fmaf(qv, kv0.x, e[0]);  e[1] = fmaf(qv, kv0.y, e[1]);
      e[2] = fmaf(qv, kv0.z, e[2]);  e[3] = fmaf(qv, kv0.w, e[3]);
      e[4] = fmaf(qv, kv1.x, e[4]);  e[5] = fmaf(qv, kv1.y, e[5]);
      e[6] = fmaf(qv, kv1.z, e[6]);  e[7] = fmaf(qv, kv1.w, e[7]);
      e[8] = fmaf(qv, kv2.x, e[8]);  e[9] = fmaf(qv, kv2.y, e[9]);
      e[10] = fmaf(qv, kv2.z, e[10]); e[11] = fmaf(qv, kv2.w, e[11]);
      e[12] = fmaf(qv, kv3.x, e[12]); e[13] = fmaf(qv, kv3.y, e[13]);
      e[14] = fmaf(qv, kv3.z, e[14]); e[15] = fmaf(qv, kv3.w, e[15]);
    }
    short8 p0, p1;
#pragma unroll
    for (int j = 0; j < 8; ++j) {
      p0[j] = (short)f2bf(__expf(fminf(e[j] - mv, 0.f)) * iv);
      p1[j] = (short)f2bf(__expf(fminf(e[j + 8] - mv, 0.f)) * iv);
    }
    {
      u16* pw = pL + nl * PSTR + (mg << 4);
      *(short8*)(pw) = p0;
      *(short8*)(pw + 8) = p1;
    }
    __syncthreads();
    if (it < 7) {
#pragma unroll
      for (int k = 0; k < 8; ++k) {
        int idx = t + k * 512;
        ks[cur ^ 1][idx] = kreg[k];
      }
    }
#pragma unroll
    for (int ksl = 0; ksl < 8; ++ksl) {
      const u16* pb0 = pL + mi * PSTR + ksl * 32 + quad * 8;
      short8 b0 = *(const short8*)(pb0);
      short8 b1 = *(const short8*)(pb0 + 16 * PSTR);
      acc[0] = __builtin_amdgcn_mfma_f32_16x16x32_bf16(vreg[ksl], b0, acc[0], 0, 0, 0);
      acc[1] = __builtin_amdgcn_mfma_f32_16x16x32_bf16(vreg[ksl], b1, acc[1], 0, 0, 0);
    }
    __syncthreads();
    cur ^= 1;
  }
  float g = gamma[0];
  float* dst = pvpart + (((size_t)(blockIdx.z * 2 + b) * 128) << 12);
#pragma unroll
  for (int nh = 0; nh < 2; ++nh)
#pragma unroll
    for (int r = 0; r < 4; ++r) {
      int c = c0 + quad * 4 + r;
      dst[((size_t)c << 12) + n0 + nh * 16 + mi] = g * acc[nh][r];
    }
}

// ---------------- K6a: CAM Gram energy via MFMA, split-bf16 ------------------
__global__ __launch_bounds__(512) void k_cam_energy_m(
    const u16* __restrict__ sc16h, const u16* __restrict__ sc16l,
    float* __restrict__ epart) {
  int t = threadIdx.x;
  int ti = blockIdx.x, kc = blockIdx.y, b = blockIdx.z;
  int lane = t & 63, wave = t >> 6;
  int mi = lane & 15, quad = lane >> 4;
  const u16* fh = sc16h + ((size_t)b << 19);
  const u16* fl = sc16l + ((size_t)b << 19);
  size_t ao = ((size_t)(ti * 16 + mi) << 12) + (kc << 9) + quad * 8;
  size_t bo = ((size_t)(wave * 16 + mi) << 12) + (kc << 9) + quad * 8;
  const u16* ah = fh + ao; const u16* al = fl + ao;
  const u16* bh = fh + bo; const u16* bl = fl + bo;
  f32x4 acc = {};
#pragma unroll
  for (int k = 0; k < 16; ++k) {
    short8 vah = *(const short8*)(ah + k * 32);
    short8 val = *(const short8*)(al + k * 32);
    short8 vbh = *(const short8*)(bh + k * 32);
    short8 vbl = *(const short8*)(bl + k * 32);
    acc = __builtin_amdgcn_mfma_f32_16x16x32_bf16(vah, vbh, acc, 0, 0, 0);
    acc = __builtin_amdgcn_mfma_f32_16x16x32_bf16(vah, vbl, acc, 0, 0, 0);
    acc = __builtin_amdgcn_mfma_f32_16x16x32_bf16(val, vbh, acc, 0, 0, 0);
  }
  float* ep = epart + (((size_t)(kc * 2 + b)) << 14);
#pragma unroll
  for (int r = 0; r < 4; ++r)
    ep[((ti * 16 + quad * 4 + r) << 7) + wave * 16 + mi] = acc[r];
}

// ---------------- K6b: CAM softmax row (reduce 8 partials) -------------------
__global__ void k_cam_softmax(const float* __restrict__ epart, float* __restrict__ attn) {
  int lane = threadIdx.x;
  int c = blockIdx.x, b = blockIdx.y;
  float e0 = 0.f, e1 = 0.f;
#pragma unroll
  for (int kc = 0; kc < 8; ++kc) {
    const float* ep = epart + (((size_t)(kc * 2 + b)) << 14) + (c << 7);
    e0 += ep[lane];
    e1 += ep[lane + 64];
  }
  float mn = fminf(e0, e1);
#pragma unroll
  for (int off = 32; off >= 1; off >>= 1) mn = fminf(mn, __shfl_xor(mn, off));
  float p0 = __expf(fminf(mn - e0, 0.f)), p1 = __expf(fminf(mn - e1, 0.f));
  float s = p0 + p1;
#pragma unroll
  for (int off = 32; off >= 1; off >>= 1) s += __shfl_xor(s, off);
  float inv = 1.f / s;
  float* a = attn + ((b * 128 + c) << 7);
  a[lane] = p0 * inv;
  a[lane + 64] = p1 * inv;
}

// ---------------- K7: CAM out + residual -------------------------------------
__global__ __launch_bounds__(256) void k_cam_out(const float* __restrict__ f,
    const float* __restrict__ attn, const float* __restrict__ gamma,
    float* __restrict__ sc1) {
  __shared__ float at2[128 * 16];
  int t = threadIdx.x;
  int b = blockIdx.z, c0 = blockIdx.y * 16;
  int n = blockIdx.x * 256 + t;
  for (int idx = t; idx < 2048; idx += 256) {
    int d = idx >> 4, cc = idx & 15;
    at2[idx] = attn[((b * 128 + c0 + cc) << 7) + d];
  }
  __syncthreads();
  float acc[16] = {};
  const float* fb = f + ((size_t)b * 128 << 12) + n;
  for (int d = 0; d < 128; ++d) {
    float fv = fb[d << 12];
    const float* ap = at2 + d * 16;
#pragma unroll
    for (int cc = 0; cc < 16; ++cc) acc[cc] = fmaf(ap[cc], fv, acc[cc]);
  }
  float g = gamma[0];
#pragma unroll
  for (int cc = 0; cc < 16; ++cc) {
    size_t o = ((size_t)(b * 128 + c0 + cc) << 12) + n;
    sc1[o] = fmaf(g, acc[cc], f[o]);
  }
}

// ---------------- K8: BN+ReLU + 1x1 conv 128->512 via MFMA -------------------
__global__ __launch_bounds__(256, 2) void k_bout_m(
    const float* __restrict__ sa0, const float* __restrict__ pvpart,
    const float* __restrict__ sc1,
    const float* __restrict__ wa_, const float* __restrict__ ba_,
    const float* __restrict__ ma_, const float* __restrict__ va_,
    const float* __restrict__ wc_, const float* __restrict__ bc_,
    const float* __restrict__ mc_, const float* __restrict__ vc_,
    const u16* __restrict__ W1b, const float* __restrict__ Ba,
    const float* __restrict__ Bc,
    u16* __restrict__ sa2, u16* __restrict__ sc2) {
  __shared__ u16 xl[32 * 136];
  __shared__ float scl[128], shf[128];
  int t = threadIdx.x;
  int n0 = blockIdx.x * 32;
  int b = blockIdx.y, br = blockIdx.z;
  const float* bw = br ? wc_ : wa_;
  const float* bb = br ? bc_ : ba_;
  const float* bm = br ? mc_ : ma_;
  const float* bvv = br ? vc_ : va_;
  if (t < 128) {
    float s = bw[t] * rsqrtf(bvv[t] + 1e-5f);
    scl[t] = s;
    shf[t] = bb[t] - bm[t] * s;
  }
  __syncthreads();
  {
    int nl = t & 31, cio = t >> 5;
    const float* s0 = (br ? sc1 : sa0) + ((size_t)b * 128 << 12) + n0 + nl;
    const float* p0 = pvpart + ((size_t)b * 128 << 12) + n0 + nl;
    const float* p1 = pvpart + (((size_t)(2 + b) * 128) << 12) + n0 + nl;
#pragma unroll
    for (int half = 0; half < 2; ++half) {
      short8 v;
#pragma unroll
      for (int i = 0; i < 8; ++i) {
        int ci = cio * 16 + half * 8 + i;
        float xv = s0[(size_t)ci << 12];
        if (!br) xv += p0[(size_t)ci << 12] + p1[(size_t)ci << 12];
        v[i] = (short)f2bf(fmaxf(fmaf(xv, scl[ci], shf[ci]), 0.f));
      }
      *(short8*)(xl + nl * 136 + cio * 16 + half * 8) = v;
    }
  }
  __syncthreads();
  int lane = t & 63, wave = t >> 6;
  int mi = lane & 15, quad = lane >> 4;
  const u16* wb = W1b + (size_t)br * 65536 + lane * 8;
  f32x4 acc[8][2] = {};
#pragma unroll
  for (int ks = 0; ks < 4; ++ks) {
    short8 b0 = *(const short8*)(xl + mi * 136 + ks * 32 + quad * 8);
    short8 b1 = *(const short8*)(xl + (16 + mi) * 136 + ks * 32 + quad * 8);
#pragma unroll
    for (int ct = 0; ct < 8; ++ct) {
      int cot = wave * 8 + ct;
      short8 a = *(const short8*)(wb + ((size_t)(cot * 4 + ks) << 9));
      acc[ct][0] = __builtin_amdgcn_mfma_f32_16x16x32_bf16(a, b0, acc[ct][0], 0, 0, 0);
      acc[ct][1] = __builtin_amdgcn_mfma_f32_16x16x32_bf16(a, b1, acc[ct][1], 0, 0, 0);
    }
  }
  const float* Bs = br ? Bc : Ba;
  u16* dst = br ? sc2 : sa2;
#pragma unroll
  for (int ct = 0; ct < 8; ++ct)
#pragma unroll
    for (int nh = 0; nh < 2; ++nh)
#pragma unroll
      for (int r = 0; r < 4; ++r) {
        int co = (wave * 8 + ct) * 16 + quad * 4 + r;
        dst[((size_t)(b * 512 + co) << 12) + n0 + nh * 16 + mi] =
            f2bf(acc[ct][nh][r] + Bs[co]);
      }
}

// ---------------- K9a: fusion + partial class-head sums (8-way c split) ------
__global__ __launch_bounds__(256) void k_heads(const u16* __restrict__ sa2,
    const u16* __restrict__ sc2,
    const float* __restrict__ wf, const float* __restrict__ wa, const float* __restrict__ wc,
    float* __restrict__ outFusion, float* __restrict__ clsacc) {
  __shared__ float lw[3 * 5 * 64];
  int t = threadIdx.x;
  int b = blockIdx.y, co0 = blockIdx.z * 64;
  int n = blockIdx.x * 256 + t;
  for (int idx = t; idx < 960; idx += 256) {
    int arr = idx / 320, rest = idx - arr * 320;
    int cls = rest >> 6, cc = rest & 63;
    const float* w = arr == 0 ? wf : (arr == 1 ? wa : wc);
    lw[idx] = w[cls * 512 + co0 + cc];
  }
  __syncthreads();
  float af[5] = {}, aa[5] = {}, ac[5] = {};
  for (int cc = 0; cc < 64; ++cc) {
    size_t o = ((size_t)(b * 512 + co0 + cc) << 12) + n;
    float a = bf2f(sa2[o]), c = bf2f(sc2[o]);
    float s = a + c;
    outFusion[o] = s;
#pragma unroll
    for (int cls = 0; cls < 5; ++cls) {
      af[cls] = fmaf(lw[0 * 320 + cls * 64 + cc], s, af[cls]);
      aa[cls] = fmaf(lw[1 * 320 + cls * 64 + cc], a, aa[cls]);
      ac[cls] = fmaf(lw[2 * 320 + cls * 64 + cc], c, ac[cls]);
    }
  }
#pragma unroll
  for (int cls = 0; cls < 5; ++cls) {
    int o = ((b * 5 + cls) << 12) + n;
    atomicAdd(&clsacc[o], af[cls]);
    atomicAdd(&clsacc[40960 + o], aa[cls]);
    atomicAdd(&clsacc[81920 + o], ac[cls]);
  }
}

// ---------------- K9b: add bias, f32 out -------------------------------------
__global__ void k_heads_final(const float* __restrict__ clsacc,
    const float* __restrict__ bf_, const float* __restrict__ ba_,
    const float* __restrict__ bc_, float* __restrict__ outCls) {
  int idx = blockIdx.x * 256 + threadIdx.x;   // 122880
  int arr = idx / 40960;
  int rest = idx - arr * 40960;
  int cls = (rest >> 12) % 5;
  const float* bp = arr == 0 ? bf_ : (arr == 1 ? ba_ : bc_);
  outCls[idx] = clsacc[idx] + bp[cls];
}

extern "C" void kernel_launch(void* const* d_in, const int* in_sizes, int n_in,
                              void* d_out, int out_size, void* d_ws, size_t ws_size,
                              hipStream_t stream) {
  (void)in_sizes; (void)n_in; (void)out_size; (void)ws_size;
  const float* x      = (const float*)d_in[0];
  const float* bnaw   = (const float*)d_in[1];
  const float* bnab   = (const float*)d_in[2];
  const float* bnam   = (const float*)d_in[3];
  const float* bnav   = (const float*)d_in[4];
  const float* convaw = (const float*)d_in[5];
  const float* bncw   = (const float*)d_in[6];
  const float* bncb   = (const float*)d_in[7];
  const float* bncm   = (const float*)d_in[8];
  const float* bncv   = (const float*)d_in[9];
  const float* convcw = (const float*)d_in[10];
  const float* pqw    = (const float*)d_in[11];
  const float* pqb    = (const float*)d_in[12];
  const float* pkw    = (const float*)d_in[13];
  const float* pkb    = (const float*)d_in[14];
  const float* pvw    = (const float*)d_in[15];
  const float* pvb    = (const float*)d_in[16];
  const float* pgam   = (const float*)d_in[17];
  const float* cgam   = (const float*)d_in[18];
  const float* bna1w  = (const float*)d_in[19];
  const float* bna1b  = (const float*)d_in[20];
  const float* bna1m  = (const float*)d_in[21];
  const float* bna1v  = (const float*)d_in[22];
  const float* conva1w = (const float*)d_in[23];
  const float* conva1b = (const float*)d_in[24];
  const float* bnc1w  = (const float*)d_in[25];
  const float* bnc1b  = (const float*)d_in[26];
  const float* bnc1m  = (const float*)d_in[27];
  const float* bnc1v  = (const float*)d_in[28];
  const float* convc1w = (const float*)d_in[29];
  const float* convc1b = (const float*)d_in[30];
  const float* outaw  = (const float*)d_in[31];
  const float* outab  = (const float*)d_in[32];
  const float* outcw  = (const float*)d_in[33];
  const float* outcb  = (const float*)d_in[34];
  const float* outfw  = (const float*)d_in[35];
  const float* outfb  = (const float*)d_in[36];

  char* wsb = (char*)d_ws;
  size_t off = 0;
  auto take = [&](size_t bytes) -> void* {
    void* p = wsb + off;
    off += (bytes + 255) & ~(size_t)255;
    return p;
  };
  u16*   Wb    = (u16*)take((size_t)2 * 128 * 9 * 512 * 2);
  u16*   W1b   = (u16*)take((size_t)2 * 512 * 128 * 2);
  u16*   Wqkvb = (u16*)take((size_t)160 * 128 * 2);
  u16*   xa16  = (u16*)take((size_t)2 * 512 * 4096 * 2);
  u16*   xcb16 = (u16*)take((size_t)2 * 512 * 4096 * 2);
  float* sa0   = (float*)take((size_t)2 * 128 * 4096 * 4);
  float* sc0   = (float*)take((size_t)2 * 128 * 4096 * 4);
  u16*   sa_nhwc = (u16*)take((size_t)2 * 4096 * 128 * 2);
  u16*   sc16h = (u16*)take((size_t)2 * 128 * 4096 * 2);
  u16*   sc16l = (u16*)take((size_t)2 * 128 * 4096 * 2);
  float* qb    = (float*)take((size_t)2 * 16 * 4096 * 4);
  float* kbuf  = (float*)take((size_t)2 * 16 * 4096 * 4);
  u16*   vt16  = (u16*)take((size_t)2 * 128 * 4096 * 2);
  float* rmax  = (float*)take((size_t)2 * 4096 * 4);
  float* rinv  = (float*)take((size_t)2 * 4096 * 4);
  float* pvpart = (float*)take((size_t)2 * 2 * 128 * 4096 * 4);
  float* sc1   = (float*)take((size_t)2 * 128 * 4096 * 4);
  float* epart = (float*)take((size_t)8 * 2 * 128 * 128 * 4);
  float* attn  = (float*)take((size_t)2 * 128 * 128 * 4);
  u16*   sa2   = (u16*)take((size_t)2 * 512 * 4096 * 2);
  u16*   sc2   = (u16*)take((size_t)2 * 512 * 4096 * 2);
  float* clsacc = (float*)take((size_t)3 * 2 * 5 * 4096 * 4);

  float* outF = (float*)d_out;
  float* outCls = outF + (size_t)2 * 512 * 4096;

  hipMemsetAsync(clsacc, 0, (size_t)3 * 2 * 5 * 4096 * 4, stream);

  k_prep_w<<<4608, 256, 0, stream>>>(convaw, convcw, Wb);
  k_prep_w1<<<512, 256, 0, stream>>>(conva1w, convc1w, W1b);
  k_prep_wqkv<<<80, 256, 0, stream>>>(pqw, pkw, pvw, Wqkvb);
  k_bnrelu2t<<<dim3(64, 2), 256, 0, stream>>>(x, bnaw, bnab, bnam, bnav,
                                              bncw, bncb, bncm, bncv, xa16, xcb16);
  k_conv3n<<<dim3(64, 4, 2), 256, 0, stream>>>(xa16, xcb16, Wb, sa0, sc0,
                                               sa_nhwc, sc16h, sc16l);
  k_qkv<<<dim3(32, 2), 256, 0, stream>>>(sa_nhwc, Wqkvb, pqb, pkb, pvb,
                                         qb, kbuf, vt16);
  k_pam_stats<<<dim3(256, 2), 256, 0, stream>>>(qb, kbuf, rmax, rinv);
  k_pam_pv<<<dim3(128, 2, 2), 512, 0, stream>>>(qb, kbuf, vt16, rmax, rinv, pgam, pvpart);
  k_cam_energy_m<<<dim3(8, 8, 2), 512, 0, stream>>>(sc16h, sc16l, epart);
  k_cam_softmax<<<dim3(128, 2), 64, 0, stream>>>(epart, attn);
  k_cam_out<<<dim3(16, 8, 2), 256, 0, stream>>>(sc0, attn, cgam, sc1);
  k_bout_m<<<dim3(128, 2, 2), 256, 0, stream>>>(sa0, pvpart, sc1,
      bna1w, bna1b, bna1m, bna1v, bnc1w, bnc1b, bnc1m, bnc1v,
      W1b, conva1b, convc1b, sa2, sc2);
  k_heads<<<dim3(16, 2, 8), 256, 0, stream>>>(sa2, sc2, outfw, outaw, outcw, outF, clsacc);
  k_heads_final<<<480, 256, 0, stream>>>(clsacc, outfb, outab, outcb, outCls);
}

// Round 7
// 341.606 us; speedup vs baseline: 1.6841x; 1.0162x over previous
//
#include <hip/hip_runtime.h>

using u16 = unsigned short;
using short8 = __attribute__((ext_vector_type(8))) short;
using f32x4 = __attribute__((ext_vector_type(4))) float;

struct alignas(8) U16x4 { u16 x, y, z, w; };

__device__ __forceinline__ float bf2f(u16 u) {
  return __uint_as_float(((unsigned int)u) << 16);
}
__device__ __forceinline__ u16 f2bf(float f) {
  unsigned int u = __float_as_uint(f);
  unsigned int r = u + 0x7FFFu + ((u >> 16) & 1u);
  return (u16)(r >> 16);
}

// ---------------- K0b: conv weights -> bf16, MFMA-fragment order -------------
// Layout: [br][mt(8)][chunk(4)][tap(9)][ks(4)][lane(64)][j(8)]
__global__ void k_prep_w(const float* __restrict__ wa, const float* __restrict__ wc,
                         u16* __restrict__ Wb) {
  int idx = blockIdx.x * 256 + threadIdx.x;   // 1179648
  int j = idx & 7;
  int l = (idx >> 3) & 63;
  int ks = (idx >> 9) & 3;
  int rest = idx >> 11;
  int tap = rest % 9;
  int rest2 = rest / 9;
  int chunk = rest2 & 3;
  int mt = (rest2 >> 2) & 7;
  int br = rest2 >> 5;
  int co = mt * 16 + (l & 15);
  int ci = chunk * 128 + ks * 32 + (l >> 4) * 8 + j;
  const float* w = br ? wc : wa;
  Wb[idx] = f2bf(w[co * 4608 + ci * 9 + tap]);
}

// ---------------- K0c: 1x1 out-conv weights (128->512) -> bf16 A-frag order --
__global__ void k_prep_w1(const float* __restrict__ wa, const float* __restrict__ wc,
                          u16* __restrict__ W1b) {
  int idx = blockIdx.x * 256 + threadIdx.x;   // 131072
  int j = idx & 7;
  int l = (idx >> 3) & 63;
  int ks = (idx >> 9) & 3;
  int cot = (idx >> 11) & 31;
  int br = idx >> 16;
  int co = cot * 16 + (l & 15);
  int ci = ks * 32 + (l >> 4) * 8 + j;
  const float* w = br ? wc : wa;
  W1b[idx] = f2bf(w[co * 128 + ci]);
}

// ---------------- K0d: qkv weights (160x128) -> bf16 A-frag order ------------
// rows 0-15: wq, 16-31: wk, 32-159: wv. [cot(10)][ks(4)][lane(64)][j(8)]
__global__ void k_prep_wqkv(const float* __restrict__ wq, const float* __restrict__ wk,
                            const float* __restrict__ wv, u16* __restrict__ Wq) {
  int idx = blockIdx.x * 256 + threadIdx.x;   // 20480
  if (idx >= 20480) return;
  int j = idx & 7;
  int l = (idx >> 3) & 63;
  int ks = (idx >> 9) & 3;
  int cot = idx >> 11;
  int co = cot * 16 + (l & 15);
  int ci = ks * 32 + (l >> 4) * 8 + j;
  float w = co < 16 ? wq[co * 128 + ci]
          : (co < 32 ? wk[(co - 16) * 128 + ci] : wv[(co - 32) * 128 + ci]);
  Wq[idx] = f2bf(w);
}

// ---------------- K1: BN+ReLU both branches, NHWC bf16 out -------------------
__global__ __launch_bounds__(256) void k_bnrelu2t(const float* __restrict__ x,
    const float* __restrict__ wa, const float* __restrict__ ba,
    const float* __restrict__ ma, const float* __restrict__ va,
    const float* __restrict__ wc, const float* __restrict__ bc,
    const float* __restrict__ mc, const float* __restrict__ vc,
    u16* __restrict__ xa16, u16* __restrict__ xcb16) {
  __shared__ float sA[512], bA[512], sC[512], bC[512];
  __shared__ u16 ta[64 * 136], tc[64 * 136];
  int t = threadIdx.x;
  int h = blockIdx.x, b = blockIdx.y;
  for (int c = t; c < 512; c += 256) {
    float s1 = wa[c] * rsqrtf(va[c] + 1e-5f);
    sA[c] = s1; bA[c] = ba[c] - ma[c] * s1;
    float s2 = wc[c] * rsqrtf(vc[c] + 1e-5f);
    sC[c] = s2; bC[c] = bc[c] - mc[c] * s2;
  }
  __syncthreads();
  const float* xb = x + ((size_t)b << 21) + (h << 6);
  u16* oa = xa16 + ((size_t)b << 21) + ((size_t)h << 15);
  u16* oc = xcb16 + ((size_t)b << 21) + ((size_t)h << 15);
  int w = t & 63, cg = t >> 6;
  for (int c0 = 0; c0 < 512; c0 += 128) {
#pragma unroll
    for (int i = 0; i < 8; ++i) {
      int cl = cg * 4 + i * 16;
      int c = c0 + cl;
      const float* xp = xb + (size_t)c * 4096 + w;
      float v0 = xp[0], v1 = xp[4096], v2 = xp[8192], v3 = xp[12288];
      U16x4 pa, pc;
      pa.x = f2bf(fmaxf(fmaf(v0, sA[c], bA[c]), 0.f));
      pa.y = f2bf(fmaxf(fmaf(v1, sA[c + 1], bA[c + 1]), 0.f));
      pa.z = f2bf(fmaxf(fmaf(v2, sA[c + 2], bA[c + 2]), 0.f));
      pa.w = f2bf(fmaxf(fmaf(v3, sA[c + 3], bA[c + 3]), 0.f));
      pc.x = f2bf(fmaxf(fmaf(v0, sC[c], bC[c]), 0.f));
      pc.y = f2bf(fmaxf(fmaf(v1, sC[c + 1], bC[c + 1]), 0.f));
      pc.z = f2bf(fmaxf(fmaf(v2, sC[c + 2], bC[c + 2]), 0.f));
      pc.w = f2bf(fmaxf(fmaf(v3, sC[c + 3], bC[c + 3]), 0.f));
      *(U16x4*)(ta + w * 136 + cl) = pa;
      *(U16x4*)(tc + w * 136 + cl) = pc;
    }
    __syncthreads();
#pragma unroll
    for (int i = 0; i < 4; ++i) {
      int idx = t + i * 256;
      int ww = idx >> 4, c8 = (idx & 15) << 3;
      *(short8*)(oa + (size_t)ww * 512 + c0 + c8) = *(const short8*)(ta + ww * 136 + c8);
      *(short8*)(oc + (size_t)ww * 512 + c0 + c8) = *(const short8*)(tc + ww * 136 + c8);
    }
    __syncthreads();
  }
}

// ---------------- K2: 3x3 conv, implicit GEMM, NHWC input --------------------
__global__ __launch_bounds__(256, 2) void k_conv3n(
    const u16* __restrict__ xa16, const u16* __restrict__ xcb16,
    const u16* __restrict__ Wb,
    float* __restrict__ sa0, float* __restrict__ sc0,
    u16* __restrict__ sa_nhwc, u16* __restrict__ sc16h, u16* __restrict__ sc16l) {
  __shared__ u16 xs[3 * 66 * 136];
  int t = threadIdx.x;
  int h = blockIdx.x;
  int z = blockIdx.y; int b = z & 1, br = z >> 1;
  int cosplit = blockIdx.z;
  const u16* xb = (br ? xcb16 : xa16) + ((size_t)b << 21);
  const u16* wb = Wb + (size_t)br * 589824;
  float* out = (br ? sc0 : sa0) + (((size_t)b * 128) << 12) + (h << 6);

  int lane = t & 63, wave = t >> 6;
  int mi = lane & 15, quad = lane >> 4;
  int mt = cosplit * 4 + wave;

  if (t < 96) {
    int dh = t >> 5, side = (t >> 4) & 1, c8 = t & 15;
    short8 z8 = {0, 0, 0, 0, 0, 0, 0, 0};
    *(short8*)(xs + (dh * 66 + side * 65) * 136 + c8 * 8) = z8;
  }

  f32x4 acc[4] = {};

  const u16* wlane = wb + lane * 8;
  const u16* bbase0 = xs + mi * 136 + quad * 8;

  for (int chunk = 0; chunk < 4; ++chunk) {
    int ci0 = chunk << 7;
    __syncthreads();
#pragma unroll
    for (int dh = 0; dh < 3; ++dh) {
      int hh = h + dh - 1;
      bool val = (hh >= 0) && (hh < 64);
      const u16* src = xb + (((size_t)hh << 6) << 9) + ci0;
#pragma unroll
      for (int i = 0; i < 4; ++i) {
        int idx = t + i * 256;
        int w = idx >> 4, c8 = (idx & 15) << 3;
        short8 v = {0, 0, 0, 0, 0, 0, 0, 0};
        if (val) v = *(const short8*)(src + ((size_t)w << 9) + c8);
        *(short8*)(xs + (dh * 66 + 1 + w) * 136 + c8) = v;
      }
    }
    __syncthreads();
    const u16* wchunk = wlane + (size_t)(mt * 4 + chunk) * 18432;
    short8 wreg[2][4];
#pragma unroll
    for (int ks = 0; ks < 4; ++ks)
      wreg[0][ks] = *(const short8*)(wchunk + ks * 512);
#pragma unroll
    for (int tap = 0; tap < 9; ++tap) {
      const int cb = tap & 1;
      if (tap < 8) {
        const u16* wn = wchunk + (tap + 1) * 2048;
#pragma unroll
        for (int ks = 0; ks < 4; ++ks)
          wreg[cb ^ 1][ks] = *(const short8*)(wn + ks * 512);
      }
      const int dh = tap / 3, dw = tap % 3;
      const u16* bp = bbase0 + (dh * 66 + dw) * 136;
#pragma unroll
      for (int ks = 0; ks < 4; ++ks) {
        short8 a = wreg[cb][ks];
#pragma unroll
        for (int nt = 0; nt < 4; ++nt) {
          short8 bf = *(const short8*)(bp + nt * 2176 + ks * 32);
          acc[nt] = __builtin_amdgcn_mfma_f32_16x16x32_bf16(a, bf, acc[nt], 0, 0, 0);
        }
      }
    }
  }
#pragma unroll
  for (int nt = 0; nt < 4; ++nt)
#pragma unroll
    for (int r = 0; r < 4; ++r) {
      int co = mt * 16 + quad * 4 + r;
      out[((size_t)co << 12) + nt * 16 + mi] = acc[nt][r];
    }
  if (br == 0) {
    u16* dstq = sa_nhwc + ((size_t)b << 19) + ((size_t)h << 6) * 128;
#pragma unroll
    for (int nt = 0; nt < 4; ++nt) {
      U16x4 v4;
      v4.x = f2bf(acc[nt][0]); v4.y = f2bf(acc[nt][1]);
      v4.z = f2bf(acc[nt][2]); v4.w = f2bf(acc[nt][3]);
      *(U16x4*)(dstq + (size_t)(nt * 16 + mi) * 128 + mt * 16 + quad * 4) = v4;
    }
  } else {
    u16* dh_ = sc16h + ((size_t)b << 19) + (h << 6);
    u16* dl_ = sc16l + ((size_t)b << 19) + (h << 6);
#pragma unroll
    for (int nt = 0; nt < 4; ++nt)
#pragma unroll
      for (int r = 0; r < 4; ++r) {
        int co = mt * 16 + quad * 4 + r;
        float xv = acc[nt][r];
        u16 hi = f2bf(xv);
        float lo = xv - bf2f(hi);
        size_t o = ((size_t)co << 12) + nt * 16 + mi;
        dh_[o] = hi;
        dl_[o] = f2bf(lo);
      }
  }
}

// ---------------- K3: fused q,k,v 1x1 convs via MFMA -------------------------
__global__ __launch_bounds__(256) void k_qkv(
    const u16* __restrict__ sa_nhwc, const u16* __restrict__ Wqkvb,
    const float* __restrict__ bq, const float* __restrict__ bk,
    const float* __restrict__ bv,
    float* __restrict__ qb, float* __restrict__ kbuf, u16* __restrict__ vt16) {
  __shared__ float bs[160];
  int t = threadIdx.x;
  int b = blockIdx.y, n0 = blockIdx.x * 128;
  if (t < 160) bs[t] = t < 16 ? bq[t] : (t < 32 ? bk[t - 16] : bv[t - 32]);
  __syncthreads();
  int lane = t & 63, wave = t >> 6;
  int mi = lane & 15, quad = lane >> 4;
  const u16* xb = sa_nhwc + ((size_t)b << 19) + (size_t)n0 * 128;
  const u16* wb = Wqkvb + lane * 8;
  f32x4 acc[2][10] = {};
  short8 bf[2][4];
#pragma unroll
  for (int ns = 0; ns < 2; ++ns) {
    int n = wave * 32 + ns * 16 + mi;
#pragma unroll
    for (int ks = 0; ks < 4; ++ks)
      bf[ns][ks] = *(const short8*)(xb + (size_t)n * 128 + ks * 32 + quad * 8);
  }
#pragma unroll
  for (int cot = 0; cot < 10; ++cot) {
    short8 a0 = *(const short8*)(wb + (size_t)(cot * 4 + 0) * 512);
    short8 a1 = *(const short8*)(wb + (size_t)(cot * 4 + 1) * 512);
    short8 a2 = *(const short8*)(wb + (size_t)(cot * 4 + 2) * 512);
    short8 a3 = *(const short8*)(wb + (size_t)(cot * 4 + 3) * 512);
#pragma unroll
    for (int ns = 0; ns < 2; ++ns) {
      acc[ns][cot] = __builtin_amdgcn_mfma_f32_16x16x32_bf16(a0, bf[ns][0], acc[ns][cot], 0, 0, 0);
      acc[ns][cot] = __builtin_amdgcn_mfma_f32_16x16x32_bf16(a1, bf[ns][1], acc[ns][cot], 0, 0, 0);
      acc[ns][cot] = __builtin_amdgcn_mfma_f32_16x16x32_bf16(a2, bf[ns][2], acc[ns][cot], 0, 0, 0);
      acc[ns][cot] = __builtin_amdgcn_mfma_f32_16x16x32_bf16(a3, bf[ns][3], acc[ns][cot], 0, 0, 0);
    }
  }
#pragma unroll
  for (int cot = 0; cot < 10; ++cot)
#pragma unroll
    for (int ns = 0; ns < 2; ++ns)
#pragma unroll
      for (int r = 0; r < 4; ++r) {
        int co = cot * 16 + quad * 4 + r;
        int n = n0 + wave * 32 + ns * 16 + mi;
        float v = acc[ns][cot][r] + bs[co];
        if (co < 16) qb[((b * 16 + co) << 12) + n] = v;
        else if (co < 32) kbuf[((b * 16 + co - 16) << 12) + n] = v;
        else vt16[((size_t)(b * 128 + co - 32) << 12) + n] = f2bf(v);
      }
}

// ---------------- K4: PAM softmax row stats; 4 n per lane, 16 n per block ----
__global__ __launch_bounds__(256) void k_pam_stats(const float* __restrict__ qb,
    const float* __restrict__ kb, float* __restrict__ rmax, float* __restrict__ rinv) {
  int t = threadIdx.x, lane = t & 63, wid = t >> 6;
  int b = blockIdx.y;
  int n0 = blockIdx.x * 16 + wid * 4;
  float qreg[4][16];
  const float* qp = qb + ((size_t)b * 16 << 12) + n0;
#pragma unroll
  for (int ch = 0; ch < 16; ++ch)
#pragma unroll
    for (int j = 0; j < 4; ++j) qreg[j][ch] = qp[(ch << 12) + j];
  const float* kp = kb + ((size_t)b * 16 << 12);
  float mx[4], se[4];
#pragma unroll
  for (int j = 0; j < 4; ++j) { mx[j] = -1e30f; se[j] = 0.f; }
  for (int m4 = lane * 4; m4 < 4096; m4 += 256) {
    float e[4][4] = {};
#pragma unroll
    for (int ch = 0; ch < 16; ++ch) {
      float4 kv = *(const float4*)(kp + (ch << 12) + m4);
#pragma unroll
      for (int j = 0; j < 4; ++j) {
        float qv = qreg[j][ch];
        e[j][0] = fmaf(qv, kv.x, e[j][0]);
        e[j][1] = fmaf(qv, kv.y, e[j][1]);
        e[j][2] = fmaf(qv, kv.z, e[j][2]);
        e[j][3] = fmaf(qv, kv.w, e[j][3]);
      }
    }
#pragma unroll
    for (int j = 0; j < 4; ++j) {
      float lm = fmaxf(fmaxf(e[j][0], e[j][1]), fmaxf(e[j][2], e[j][3]));
      float nm = fmaxf(mx[j], lm);
      se[j] = se[j] * __expf(mx[j] - nm)
            + __expf(e[j][0] - nm) + __expf(e[j][1] - nm)
            + __expf(e[j][2] - nm) + __expf(e[j][3] - nm);
      mx[j] = nm;
    }
  }
#pragma unroll
  for (int off = 32; off >= 1; off >>= 1) {
#pragma unroll
    for (int j = 0; j < 4; ++j) {
      float om = __shfl_xor(mx[j], off);
      float os = __shfl_xor(se[j], off);
      float nm = fmaxf(mx[j], om);
      se[j] = se[j] * __expf(mx[j] - nm) + os * __expf(om - nm);
      mx[j] = nm;
    }
  }
  if (lane == 0) {
#pragma unroll
    for (int j = 0; j < 4; ++j) {
      rmax[(b << 12) + n0 + j] = mx[j];
      rinv[(b << 12) + n0 + j] = 1.f / se[j];
    }
  }
}

// ---------------- K5: PAM PV, MFMA energy (split-bf16) + MFMA PV -------------
// grid (128, 2, 2): block = 32 n x 2048 m x 128 c. 8 waves; per 256-m chunk:
// wave w owns m slice [32w,32w+32). Energy e = K^T Q via 2 split-MFMAs/tile
// (exact k*(qh+ql)); exp -> pL[n][m]; PV MFMA as before. K staged as split
// bf16 A-frags in LDS (double-buffered), V prefetched to regs.
__global__ __launch_bounds__(512, 4) void k_pam_pv(const float* __restrict__ qb,
    const float* __restrict__ kb, const u16* __restrict__ vt16,
    const float* __restrict__ rmax, const float* __restrict__ rinv,
    const float* __restrict__ gamma, float* __restrict__ pvpart) {
  constexpr int KSTR = 40;           // u16 per m-row (80B, 16B-aligned)
  constexpr int PSTR = 264;          // u16; odd 16B stride
  __shared__ u16 kst[2][256 * KSTR]; // [buf][m][kh(16)|kl(16)]
  __shared__ u16 pL[32 * PSTR];      // [n][m] bf16
  __shared__ u16 qfh[32 * 16], qfl[32 * 16];   // [n][ch]
  int t = threadIdx.x;
  int b = blockIdx.y, n0 = blockIdx.x * 32;
  int mbeg = blockIdx.z << 11;       // 0 or 2048
  int lane = t & 63, wave = t >> 6;
  int mi = lane & 15, quad = lane >> 4;
  int c0 = wave * 16;
  // build q hi/lo fragments (once)
  {
    int ch = t & 15, nl = t >> 4;    // 512 = 32 n x 16 ch
    float qv = qb[((size_t)(b * 16 + ch) << 12) + n0 + nl];
    u16 hi = f2bf(qv);
    qfh[nl * 16 + ch] = hi;
    qfl[nl * 16 + ch] = f2bf(qv - bf2f(hi));
  }
  float mv0 = rmax[(b << 12) + n0 + mi],      iv0 = rinv[(b << 12) + n0 + mi];
  float mv1 = rmax[(b << 12) + n0 + 16 + mi], iv1 = rinv[(b << 12) + n0 + 16 + mi];
  const float* kpb = kb + ((size_t)b * 16 << 12) + mbeg;
  const u16* vb = vt16 + ((size_t)b * 128 << 12);
  f32x4 acc[2] = {};
  // prologue: stage K chunk 0 as split bf16 (thread: m=t&255, ch=sc+2k)
  int sm = t & 255, sc = t >> 8;
  {
    u16* kw = kst[0] + sm * KSTR + sc;
#pragma unroll
    for (int k = 0; k < 8; ++k) {
      float v = kpb[((size_t)(sc + 2 * k) << 12) + sm];
      u16 hi = f2bf(v);
      kw[2 * k] = hi;
      kw[16 + 2 * k] = f2bf(v - bf2f(hi));
    }
  }
  __syncthreads();   // kst[0] + qfh/qfl ready
  // hoist Q B-frags: B1=[qh|qh], B2=[ql|ql]; col=n=mi, k=quad*8+j -> ch=(k&15)
  int qoff = (quad & 1) * 8;
  short8 bq1[2], bq2[2];
  bq1[0] = *(const short8*)(qfh + mi * 16 + qoff);
  bq1[1] = *(const short8*)(qfh + (16 + mi) * 16 + qoff);
  bq2[0] = *(const short8*)(qfl + mi * 16 + qoff);
  bq2[1] = *(const short8*)(qfl + (16 + mi) * 16 + qoff);
  int cur = 0;
  for (int it = 0; it < 8; ++it) {
    int m0 = mbeg + (it << 8);
    // prefetch this chunk's V fragments
    short8 vreg[8];
#pragma unroll
    for (int ksl = 0; ksl < 8; ++ksl)
      vreg[ksl] = *(const short8*)(vb + ((size_t)(c0 + mi) << 12) + m0 + ksl * 32 + quad * 8);
    // issue next-chunk K loads early
    float kreg[8];
    if (it < 7) {
#pragma unroll
      for (int k = 0; k < 8; ++k)
        kreg[k] = kpb[((size_t)(sc + 2 * k) << 12) + ((it + 1) << 8) + sm];
    }
    // energy via MFMA: wave's m slice [wave*32, +32), all 32 n
    {
      const u16* ka = kst[cur] + (wave * 32) * KSTR;
      short8 a0 = *(const short8*)(ka + mi * KSTR + quad * 8);
      short8 a1 = *(const short8*)(ka + (16 + mi) * KSTR + quad * 8);
      f32x4 e00 = {}, e01 = {}, e10 = {}, e11 = {};
      e00 = __builtin_amdgcn_mfma_f32_16x16x32_bf16(a0, bq1[0], e00, 0, 0, 0);
      e00 = __builtin_amdgcn_mfma_f32_16x16x32_bf16(a0, bq2[0], e00, 0, 0, 0);
      e01 = __builtin_amdgcn_mfma_f32_16x16x32_bf16(a0, bq1[1], e01, 0, 0, 0);
      e01 = __builtin_amdgcn_mfma_f32_16x16x32_bf16(a0, bq2[1], e01, 0, 0, 0);
      e10 = __builtin_amdgcn_mfma_f32_16x16x32_bf16(a1, bq1[0], e10, 0, 0, 0);
      e10 = __builtin_amdgcn_mfma_f32_16x16x32_bf16(a1, bq2[0], e10, 0, 0, 0);
      e11 = __builtin_amdgcn_mfma_f32_16x16x32_bf16(a1, bq1[1], e11, 0, 0, 0);
      e11 = __builtin_amdgcn_mfma_f32_16x16x32_bf16(a1, bq2[1], e11, 0, 0, 0);
      // D: m = wave*32 + mt*16 + quad*4 + r, n = nt*16 + mi
      u16* prow0 = pL + mi * PSTR + wave * 32 + quad * 4;          // nt=0
      u16* prow1 = pL + (16 + mi) * PSTR + wave * 32 + quad * 4;   // nt=1
      U16x4 p;
      p.x = f2bf(__expf(fminf(e00[0] - mv0, 0.f)) * iv0);
      p.y = f2bf(__expf(fminf(e00[1] - mv0, 0.f)) * iv0);
      p.z = f2bf(__expf(fminf(e00[2] - mv0, 0.f)) * iv0);
      p.w = f2bf(__expf(fminf(e00[3] - mv0, 0.f)) * iv0);
      *(U16x4*)(prow0) = p;
      p.x = f2bf(__expf(fminf(e10[0] - mv0, 0.f)) * iv0);
      p.y = f2bf(__expf(fminf(e10[1] - mv0, 0.f)) * iv0);
      p.z = f2bf(__expf(fminf(e10[2] - mv0, 0.f)) * iv0);
      p.w = f2bf(__expf(fminf(e10[3] - mv0, 0.f)) * iv0);
      *(U16x4*)(prow0 + 16) = p;
      p.x = f2bf(__expf(fminf(e01[0] - mv1, 0.f)) * iv1);
      p.y = f2bf(__expf(fminf(e01[1] - mv1, 0.f)) * iv1);
      p.z = f2bf(__expf(fminf(e01[2] - mv1, 0.f)) * iv1);
      p.w = f2bf(__expf(fminf(e01[3] - mv1, 0.f)) * iv1);
      *(U16x4*)(prow1) = p;
      p.x = f2bf(__expf(fminf(e11[0] - mv1, 0.f)) * iv1);
      p.y = f2bf(__expf(fminf(e11[1] - mv1, 0.f)) * iv1);
      p.z = f2bf(__expf(fminf(e11[2] - mv1, 0.f)) * iv1);
      p.w = f2bf(__expf(fminf(e11[3] - mv1, 0.f)) * iv1);
      *(U16x4*)(prow1 + 16) = p;
    }
    __syncthreads();   // P ready; kst[cur] energy reads done
    // stage next K into alternate buffer (overlaps PV MFMA phase)
    if (it < 7) {
      u16* kw = kst[cur ^ 1] + sm * KSTR + sc;
#pragma unroll
      for (int k = 0; k < 8; ++k) {
        u16 hi = f2bf(kreg[k]);
        kw[2 * k] = hi;
        kw[16 + 2 * k] = f2bf(kreg[k] - bf2f(hi));
      }
    }
    // PV MFMA: acc[c][n] += V[c][m] * P[n][m]
#pragma unroll
    for (int ksl = 0; ksl < 8; ++ksl) {
      const u16* pb0 = pL + mi * PSTR + ksl * 32 + quad * 8;
      short8 b0 = *(const short8*)(pb0);
      short8 b1 = *(const short8*)(pb0 + 16 * PSTR);
      acc[0] = __builtin_amdgcn_mfma_f32_16x16x32_bf16(vreg[ksl], b0, acc[0], 0, 0, 0);
      acc[1] = __builtin_amdgcn_mfma_f32_16x16x32_bf16(vreg[ksl], b1, acc[1], 0, 0, 0);
    }
    __syncthreads();   // pL free; kst[cur^1] writes done
    cur ^= 1;
  }
  float g = gamma[0];
  float* dst = pvpart + (((size_t)(blockIdx.z * 2 + b) * 128) << 12);
#pragma unroll
  for (int nh = 0; nh < 2; ++nh)
#pragma unroll
    for (int r = 0; r < 4; ++r) {
      int c = c0 + quad * 4 + r;
      dst[((size_t)c << 12) + n0 + nh * 16 + mi] = g * acc[nh][r];
    }
}

// ---------------- K6a: CAM Gram energy via MFMA, split-bf16 ------------------
__global__ __launch_bounds__(512) void k_cam_energy_m(
    const u16* __restrict__ sc16h, const u16* __restrict__ sc16l,
    float* __restrict__ epart) {
  int t = threadIdx.x;
  int ti = blockIdx.x, kc = blockIdx.y, b = blockIdx.z;
  int lane = t & 63, wave = t >> 6;
  int mi = lane & 15, quad = lane >> 4;
  const u16* fh = sc16h + ((size_t)b << 19);
  const u16* fl = sc16l + ((size_t)b << 19);
  size_t ao = ((size_t)(ti * 16 + mi) << 12) + (kc << 9) + quad * 8;
  size_t bo = ((size_t)(wave * 16 + mi) << 12) + (kc << 9) + quad * 8;
  const u16* ah = fh + ao; const u16* al = fl + ao;
  const u16* bh = fh + bo; const u16* bl = fl + bo;
  f32x4 acc = {};
#pragma unroll
  for (int k = 0; k < 16; ++k) {
    short8 vah = *(const short8*)(ah + k * 32);
    short8 val = *(const short8*)(al + k * 32);
    short8 vbh = *(const short8*)(bh + k * 32);
    short8 vbl = *(const short8*)(bl + k * 32);
    acc = __builtin_amdgcn_mfma_f32_16x16x32_bf16(vah, vbh, acc, 0, 0, 0);
    acc = __builtin_amdgcn_mfma_f32_16x16x32_bf16(vah, vbl, acc, 0, 0, 0);
    acc = __builtin_amdgcn_mfma_f32_16x16x32_bf16(val, vbh, acc, 0, 0, 0);
  }
  float* ep = epart + (((size_t)(kc * 2 + b)) << 14);
#pragma unroll
  for (int r = 0; r < 4; ++r)
    ep[((ti * 16 + quad * 4 + r) << 7) + wave * 16 + mi] = acc[r];
}

// ---------------- K6b: CAM softmax row (reduce 8 partials) -------------------
__global__ void k_cam_softmax(const float* __restrict__ epart, float* __restrict__ attn) {
  int lane = threadIdx.x;
  int c = blockIdx.x, b = blockIdx.y;
  float e0 = 0.f, e1 = 0.f;
#pragma unroll
  for (int kc = 0; kc < 8; ++kc) {
    const float* ep = epart + (((size_t)(kc * 2 + b)) << 14) + (c << 7);
    e0 += ep[lane];
    e1 += ep[lane + 64];
  }
  float mn = fminf(e0, e1);
#pragma unroll
  for (int off = 32; off >= 1; off >>= 1) mn = fminf(mn, __shfl_xor(mn, off));
  float p0 = __expf(fminf(mn - e0, 0.f)), p1 = __expf(fminf(mn - e1, 0.f));
  float s = p0 + p1;
#pragma unroll
  for (int off = 32; off >= 1; off >>= 1) s += __shfl_xor(s, off);
  float inv = 1.f / s;
  float* a = attn + ((b * 128 + c) << 7);
  a[lane] = p0 * inv;
  a[lane + 64] = p1 * inv;
}

// ---------------- K7: CAM out + residual -------------------------------------
__global__ __launch_bounds__(256) void k_cam_out(const float* __restrict__ f,
    const float* __restrict__ attn, const float* __restrict__ gamma,
    float* __restrict__ sc1) {
  __shared__ float at2[128 * 16];
  int t = threadIdx.x;
  int b = blockIdx.z, c0 = blockIdx.y * 16;
  int n = blockIdx.x * 256 + t;
  for (int idx = t; idx < 2048; idx += 256) {
    int d = idx >> 4, cc = idx & 15;
    at2[idx] = attn[((b * 128 + c0 + cc) << 7) + d];
  }
  __syncthreads();
  float acc[16] = {};
  const float* fb = f + ((size_t)b * 128 << 12) + n;
  for (int d = 0; d < 128; ++d) {
    float fv = fb[d << 12];
    const float* ap = at2 + d * 16;
#pragma unroll
    for (int cc = 0; cc < 16; ++cc) acc[cc] = fmaf(ap[cc], fv, acc[cc]);
  }
  float g = gamma[0];
#pragma unroll
  for (int cc = 0; cc < 16; ++cc) {
    size_t o = ((size_t)(b * 128 + c0 + cc) << 12) + n;
    sc1[o] = fmaf(g, acc[cc], f[o]);
  }
}

// ---------------- K8: BN+ReLU + 1x1 conv 128->512 via MFMA -------------------
__global__ __launch_bounds__(256, 2) void k_bout_m(
    const float* __restrict__ sa0, const float* __restrict__ pvpart,
    const float* __restrict__ sc1,
    const float* __restrict__ wa_, const float* __restrict__ ba_,
    const float* __restrict__ ma_, const float* __restrict__ va_,
    const float* __restrict__ wc_, const float* __restrict__ bc_,
    const float* __restrict__ mc_, const float* __restrict__ vc_,
    const u16* __restrict__ W1b, const float* __restrict__ Ba,
    const float* __restrict__ Bc,
    u16* __restrict__ sa2, u16* __restrict__ sc2) {
  __shared__ u16 xl[32 * 136];
  __shared__ float scl[128], shf[128];
  int t = threadIdx.x;
  int n0 = blockIdx.x * 32;
  int b = blockIdx.y, br = blockIdx.z;
  const float* bw = br ? wc_ : wa_;
  const float* bb = br ? bc_ : ba_;
  const float* bm = br ? mc_ : ma_;
  const float* bvv = br ? vc_ : va_;
  if (t < 128) {
    float s = bw[t] * rsqrtf(bvv[t] + 1e-5f);
    scl[t] = s;
    shf[t] = bb[t] - bm[t] * s;
  }
  __syncthreads();
  {
    int nl = t & 31, cio = t >> 5;
    const float* s0 = (br ? sc1 : sa0) + ((size_t)b * 128 << 12) + n0 + nl;
    const float* p0 = pvpart + ((size_t)b * 128 << 12) + n0 + nl;
    const float* p1 = pvpart + (((size_t)(2 + b) * 128) << 12) + n0 + nl;
#pragma unroll
    for (int half = 0; half < 2; ++half) {
      short8 v;
#pragma unroll
      for (int i = 0; i < 8; ++i) {
        int ci = cio * 16 + half * 8 + i;
        float xv = s0[(size_t)ci << 12];
        if (!br) xv += p0[(size_t)ci << 12] + p1[(size_t)ci << 12];
        v[i] = (short)f2bf(fmaxf(fmaf(xv, scl[ci], shf[ci]), 0.f));
      }
      *(short8*)(xl + nl * 136 + cio * 16 + half * 8) = v;
    }
  }
  __syncthreads();
  int lane = t & 63, wave = t >> 6;
  int mi = lane & 15, quad = lane >> 4;
  const u16* wb = W1b + (size_t)br * 65536 + lane * 8;
  f32x4 acc[8][2] = {};
#pragma unroll
  for (int ks = 0; ks < 4; ++ks) {
    short8 b0 = *(const short8*)(xl + mi * 136 + ks * 32 + quad * 8);
    short8 b1 = *(const short8*)(xl + (16 + mi) * 136 + ks * 32 + quad * 8);
#pragma unroll
    for (int ct = 0; ct < 8; ++ct) {
      int cot = wave * 8 + ct;
      short8 a = *(const short8*)(wb + ((size_t)(cot * 4 + ks) << 9));
      acc[ct][0] = __builtin_amdgcn_mfma_f32_16x16x32_bf16(a, b0, acc[ct][0], 0, 0, 0);
      acc[ct][1] = __builtin_amdgcn_mfma_f32_16x16x32_bf16(a, b1, acc[ct][1], 0, 0, 0);
    }
  }
  const float* Bs = br ? Bc : Ba;
  u16* dst = br ? sc2 : sa2;
#pragma unroll
  for (int ct = 0; ct < 8; ++ct)
#pragma unroll
    for (int nh = 0; nh < 2; ++nh)
#pragma unroll
      for (int r = 0; r < 4; ++r) {
        int co = (wave * 8 + ct) * 16 + quad * 4 + r;
        dst[((size_t)(b * 512 + co) << 12) + n0 + nh * 16 + mi] =
            f2bf(acc[ct][nh][r] + Bs[co]);
      }
}

// ---------------- K9a: fusion + partial class-head sums (8-way c split) ------
__global__ __launch_bounds__(256) void k_heads(const u16* __restrict__ sa2,
    const u16* __restrict__ sc2,
    const float* __restrict__ wf, const float* __restrict__ wa, const float* __restrict__ wc,
    float* __restrict__ outFusion, float* __restrict__ clsacc) {
  __shared__ float lw[3 * 5 * 64];
  int t = threadIdx.x;
  int b = blockIdx.y, co0 = blockIdx.z * 64;
  int n = blockIdx.x * 256 + t;
  for (int idx = t; idx < 960; idx += 256) {
    int arr = idx / 320, rest = idx - arr * 320;
    int cls = rest >> 6, cc = rest & 63;
    const float* w = arr == 0 ? wf : (arr == 1 ? wa : wc);
    lw[idx] = w[cls * 512 + co0 + cc];
  }
  __syncthreads();
  float af[5] = {}, aa[5] = {}, ac[5] = {};
  for (int cc = 0; cc < 64; ++cc) {
    size_t o = ((size_t)(b * 512 + co0 + cc) << 12) + n;
    float a = bf2f(sa2[o]), c = bf2f(sc2[o]);
    float s = a + c;
    outFusion[o] = s;
#pragma unroll
    for (int cls = 0; cls < 5; ++cls) {
      af[cls] = fmaf(lw[0 * 320 + cls * 64 + cc], s, af[cls]);
      aa[cls] = fmaf(lw[1 * 320 + cls * 64 + cc], a, aa[cls]);
      ac[cls] = fmaf(lw[2 * 320 + cls * 64 + cc], c, ac[cls]);
    }
  }
#pragma unroll
  for (int cls = 0; cls < 5; ++cls) {
    int o = ((b * 5 + cls) << 12) + n;
    atomicAdd(&clsacc[o], af[cls]);
    atomicAdd(&clsacc[40960 + o], aa[cls]);
    atomicAdd(&clsacc[81920 + o], ac[cls]);
  }
}

// ---------------- K9b: add bias, f32 out -------------------------------------
__global__ void k_heads_final(const float* __restrict__ clsacc,
    const float* __restrict__ bf_, const float* __restrict__ ba_,
    const float* __restrict__ bc_, float* __restrict__ outCls) {
  int idx = blockIdx.x * 256 + threadIdx.x;   // 122880
  int arr = idx / 40960;
  int rest = idx - arr * 40960;
  int cls = (rest >> 12) % 5;
  const float* bp = arr == 0 ? bf_ : (arr == 1 ? ba_ : bc_);
  outCls[idx] = clsacc[idx] + bp[cls];
}

extern "C" void kernel_launch(void* const* d_in, const int* in_sizes, int n_in,
                              void* d_out, int out_size, void* d_ws, size_t ws_size,
                              hipStream_t stream) {
  (void)in_sizes; (void)n_in; (void)out_size; (void)ws_size;
  const float* x      = (const float*)d_in[0];
  const float* bnaw   = (const float*)d_in[1];
  const float* bnab   = (const float*)d_in[2];
  const float* bnam   = (const float*)d_in[3];
  const float* bnav   = (const float*)d_in[4];
  const float* convaw = (const float*)d_in[5];
  const float* bncw   = (const float*)d_in[6];
  const float* bncb   = (const float*)d_in[7];
  const float* bncm   = (const float*)d_in[8];
  const float* bncv   = (const float*)d_in[9];
  const float* convcw = (const float*)d_in[10];
  const float* pqw    = (const float*)d_in[11];
  const float* pqb    = (const float*)d_in[12];
  const float* pkw    = (const float*)d_in[13];
  const float* pkb    = (const float*)d_in[14];
  const float* pvw    = (const float*)d_in[15];
  const float* pvb    = (const float*)d_in[16];
  const float* pgam   = (const float*)d_in[17];
  const float* cgam   = (const float*)d_in[18];
  const float* bna1w  = (const float*)d_in[19];
  const float* bna1b  = (const float*)d_in[20];
  const float* bna1m  = (const float*)d_in[21];
  const float* bna1v  = (const float*)d_in[22];
  const float* conva1w = (const float*)d_in[23];
  const float* conva1b = (const float*)d_in[24];
  const float* bnc1w  = (const float*)d_in[25];
  const float* bnc1b  = (const float*)d_in[26];
  const float* bnc1m  = (const float*)d_in[27];
  const float* bnc1v  = (const float*)d_in[28];
  const float* convc1w = (const float*)d_in[29];
  const float* convc1b = (const float*)d_in[30];
  const float* outaw  = (const float*)d_in[31];
  const float* outab  = (const float*)d_in[32];
  const float* outcw  = (const float*)d_in[33];
  const float* outcb  = (const float*)d_in[34];
  const float* outfw  = (const float*)d_in[35];
  const float* outfb  = (const float*)d_in[36];

  char* wsb = (char*)d_ws;
  size_t off = 0;
  auto take = [&](size_t bytes) -> void* {
    void* p = wsb + off;
    off += (bytes + 255) & ~(size_t)255;
    return p;
  };
  u16*   Wb    = (u16*)take((size_t)2 * 128 * 9 * 512 * 2);
  u16*   W1b   = (u16*)take((size_t)2 * 512 * 128 * 2);
  u16*   Wqkvb = (u16*)take((size_t)160 * 128 * 2);
  u16*   xa16  = (u16*)take((size_t)2 * 512 * 4096 * 2);
  u16*   xcb16 = (u16*)take((size_t)2 * 512 * 4096 * 2);
  float* sa0   = (float*)take((size_t)2 * 128 * 4096 * 4);
  float* sc0   = (float*)take((size_t)2 * 128 * 4096 * 4);
  u16*   sa_nhwc = (u16*)take((size_t)2 * 4096 * 128 * 2);
  u16*   sc16h = (u16*)take((size_t)2 * 128 * 4096 * 2);
  u16*   sc16l = (u16*)take((size_t)2 * 128 * 4096 * 2);
  float* qb    = (float*)take((size_t)2 * 16 * 4096 * 4);
  float* kbuf  = (float*)take((size_t)2 * 16 * 4096 * 4);
  u16*   vt16  = (u16*)take((size_t)2 * 128 * 4096 * 2);
  float* rmax  = (float*)take((size_t)2 * 4096 * 4);
  float* rinv  = (float*)take((size_t)2 * 4096 * 4);
  float* pvpart = (float*)take((size_t)2 * 2 * 128 * 4096 * 4);
  float* sc1   = (float*)take((size_t)2 * 128 * 4096 * 4);
  float* epart = (float*)take((size_t)8 * 2 * 128 * 128 * 4);
  float* attn  = (float*)take((size_t)2 * 128 * 128 * 4);
  u16*   sa2   = (u16*)take((size_t)2 * 512 * 4096 * 2);
  u16*   sc2   = (u16*)take((size_t)2 * 512 * 4096 * 2);
  float* clsacc = (float*)take((size_t)3 * 2 * 5 * 4096 * 4);

  float* outF = (float*)d_out;
  float* outCls = outF + (size_t)2 * 512 * 4096;

  hipMemsetAsync(clsacc, 0, (size_t)3 * 2 * 5 * 4096 * 4, stream);

  k_prep_w<<<4608, 256, 0, stream>>>(convaw, convcw, Wb);
  k_prep_w1<<<512, 256, 0, stream>>>(conva1w, convc1w, W1b);
  k_prep_wqkv<<<80, 256, 0, stream>>>(pqw, pkw, pvw, Wqkvb);
  k_bnrelu2t<<<dim3(64, 2), 256, 0, stream>>>(x, bnaw, bnab, bnam, bnav,
                                              bncw, bncb, bncm, bncv, xa16, xcb16);
  k_conv3n<<<dim3(64, 4, 2), 256, 0, stream>>>(xa16, xcb16, Wb, sa0, sc0,
                                               sa_nhwc, sc16h, sc16l);
  k_qkv<<<dim3(32, 2), 256, 0, stream>>>(sa_nhwc, Wqkvb, pqb, pkb, pvb,
                                         qb, kbuf, vt16);
  k_pam_stats<<<dim3(256, 2), 256, 0, stream>>>(qb, kbuf, rmax, rinv);
  k_pam_pv<<<dim3(128, 2, 2), 512, 0, stream>>>(qb, kbuf, vt16, rmax, rinv, pgam, pvpart);
  k_cam_energy_m<<<dim3(8, 8, 2), 512, 0, stream>>>(sc16h, sc16l, epart);
  k_cam_softmax<<<dim3(128, 2), 64, 0, stream>>>(epart, attn);
  k_cam_out<<<dim3(16, 8, 2), 256, 0, stream>>>(sc0, attn, cgam, sc1);
  k_bout_m<<<dim3(128, 2, 2), 256, 0, stream>>>(sa0, pvpart, sc1,
      bna1w, bna1b, bna1m, bna1v, bnc1w, bnc1b, bnc1m, bnc1v,
      W1b, conva1b, convc1b, sa2, sc2);
  k_heads<<<dim3(16, 2, 8), 256, 0, stream>>>(sa2, sc2, outfw, outaw, outcw, outF, clsacc);
  k_heads_final<<<480, 256, 0, stream>>>(clsacc, outfb, outab, outcb, outCls);
}

// Round 8
// 337.734 us; speedup vs baseline: 1.7034x; 1.0115x over previous
//
#include <hip/hip_runtime.h>

using u16 = unsigned short;
using short8 = __attribute__((ext_vector_type(8))) short;
using f32x4 = __attribute__((ext_vector_type(4))) float;

struct alignas(8) U16x4 { u16 x, y, z, w; };

__device__ __forceinline__ float bf2f(u16 u) {
  return __uint_as_float(((unsigned int)u) << 16);
}
__device__ __forceinline__ u16 f2bf(float f) {
  unsigned int u = __float_as_uint(f);
  unsigned int r = u + 0x7FFFu + ((u >> 16) & 1u);
  return (u16)(r >> 16);
}

// ---------------- K0b: conv weights -> bf16, MFMA-fragment order -------------
// Layout: [br][mt(8)][chunk(4)][tap(9)][ks(4)][lane(64)][j(8)]
__global__ void k_prep_w(const float* __restrict__ wa, const float* __restrict__ wc,
                         u16* __restrict__ Wb) {
  int idx = blockIdx.x * 256 + threadIdx.x;   // 1179648
  int j = idx & 7;
  int l = (idx >> 3) & 63;
  int ks = (idx >> 9) & 3;
  int rest = idx >> 11;
  int tap = rest % 9;
  int rest2 = rest / 9;
  int chunk = rest2 & 3;
  int mt = (rest2 >> 2) & 7;
  int br = rest2 >> 5;
  int co = mt * 16 + (l & 15);
  int ci = chunk * 128 + ks * 32 + (l >> 4) * 8 + j;
  const float* w = br ? wc : wa;
  Wb[idx] = f2bf(w[co * 4608 + ci * 9 + tap]);
}

// ---------------- K0c: 1x1 out-conv weights (128->512) -> bf16 A-frag order --
__global__ void k_prep_w1(const float* __restrict__ wa, const float* __restrict__ wc,
                          u16* __restrict__ W1b) {
  int idx = blockIdx.x * 256 + threadIdx.x;   // 131072
  int j = idx & 7;
  int l = (idx >> 3) & 63;
  int ks = (idx >> 9) & 3;
  int cot = (idx >> 11) & 31;
  int br = idx >> 16;
  int co = cot * 16 + (l & 15);
  int ci = ks * 32 + (l >> 4) * 8 + j;
  const float* w = br ? wc : wa;
  W1b[idx] = f2bf(w[co * 128 + ci]);
}

// ---------------- K0d: qkv weights (160x128) -> bf16 A-frag order ------------
// rows 0-15: wq, 16-31: wk, 32-159: wv. [cot(10)][ks(4)][lane(64)][j(8)]
__global__ void k_prep_wqkv(const float* __restrict__ wq, const float* __restrict__ wk,
                            const float* __restrict__ wv, u16* __restrict__ Wq) {
  int idx = blockIdx.x * 256 + threadIdx.x;   // 20480
  if (idx >= 20480) return;
  int j = idx & 7;
  int l = (idx >> 3) & 63;
  int ks = (idx >> 9) & 3;
  int cot = idx >> 11;
  int co = cot * 16 + (l & 15);
  int ci = ks * 32 + (l >> 4) * 8 + j;
  float w = co < 16 ? wq[co * 128 + ci]
          : (co < 32 ? wk[(co - 16) * 128 + ci] : wv[(co - 32) * 128 + ci]);
  Wq[idx] = f2bf(w);
}

// ---------------- K1: BN+ReLU both branches, NHWC bf16 out -------------------
__global__ __launch_bounds__(256) void k_bnrelu2t(const float* __restrict__ x,
    const float* __restrict__ wa, const float* __restrict__ ba,
    const float* __restrict__ ma, const float* __restrict__ va,
    const float* __restrict__ wc, const float* __restrict__ bc,
    const float* __restrict__ mc, const float* __restrict__ vc,
    u16* __restrict__ xa16, u16* __restrict__ xcb16) {
  __shared__ float sA[512], bA[512], sC[512], bC[512];
  __shared__ u16 ta[64 * 136], tc[64 * 136];
  int t = threadIdx.x;
  int h = blockIdx.x, b = blockIdx.y;
  for (int c = t; c < 512; c += 256) {
    float s1 = wa[c] * rsqrtf(va[c] + 1e-5f);
    sA[c] = s1; bA[c] = ba[c] - ma[c] * s1;
    float s2 = wc[c] * rsqrtf(vc[c] + 1e-5f);
    sC[c] = s2; bC[c] = bc[c] - mc[c] * s2;
  }
  __syncthreads();
  const float* xb = x + ((size_t)b << 21) + (h << 6);
  u16* oa = xa16 + ((size_t)b << 21) + ((size_t)h << 15);
  u16* oc = xcb16 + ((size_t)b << 21) + ((size_t)h << 15);
  int w = t & 63, cg = t >> 6;
  for (int c0 = 0; c0 < 512; c0 += 128) {
#pragma unroll
    for (int i = 0; i < 8; ++i) {
      int cl = cg * 4 + i * 16;
      int c = c0 + cl;
      const float* xp = xb + (size_t)c * 4096 + w;
      float v0 = xp[0], v1 = xp[4096], v2 = xp[8192], v3 = xp[12288];
      U16x4 pa, pc;
      pa.x = f2bf(fmaxf(fmaf(v0, sA[c], bA[c]), 0.f));
      pa.y = f2bf(fmaxf(fmaf(v1, sA[c + 1], bA[c + 1]), 0.f));
      pa.z = f2bf(fmaxf(fmaf(v2, sA[c + 2], bA[c + 2]), 0.f));
      pa.w = f2bf(fmaxf(fmaf(v3, sA[c + 3], bA[c + 3]), 0.f));
      pc.x = f2bf(fmaxf(fmaf(v0, sC[c], bC[c]), 0.f));
      pc.y = f2bf(fmaxf(fmaf(v1, sC[c + 1], bC[c + 1]), 0.f));
      pc.z = f2bf(fmaxf(fmaf(v2, sC[c + 2], bC[c + 2]), 0.f));
      pc.w = f2bf(fmaxf(fmaf(v3, sC[c + 3], bC[c + 3]), 0.f));
      *(U16x4*)(ta + w * 136 + cl) = pa;
      *(U16x4*)(tc + w * 136 + cl) = pc;
    }
    __syncthreads();
#pragma unroll
    for (int i = 0; i < 4; ++i) {
      int idx = t + i * 256;
      int ww = idx >> 4, c8 = (idx & 15) << 3;
      *(short8*)(oa + (size_t)ww * 512 + c0 + c8) = *(const short8*)(ta + ww * 136 + c8);
      *(short8*)(oc + (size_t)ww * 512 + c0 + c8) = *(const short8*)(tc + ww * 136 + c8);
    }
    __syncthreads();
  }
}

// ---------------- K2: 3x3 conv, implicit GEMM, NHWC input --------------------
__global__ __launch_bounds__(256, 2) void k_conv3n(
    const u16* __restrict__ xa16, const u16* __restrict__ xcb16,
    const u16* __restrict__ Wb,
    float* __restrict__ sa0, float* __restrict__ sc0,
    u16* __restrict__ sa_nhwc, u16* __restrict__ sc16h, u16* __restrict__ sc16l) {
  __shared__ u16 xs[3 * 66 * 136];
  int t = threadIdx.x;
  int h = blockIdx.x;
  int z = blockIdx.y; int b = z & 1, br = z >> 1;
  int cosplit = blockIdx.z;
  const u16* xb = (br ? xcb16 : xa16) + ((size_t)b << 21);
  const u16* wb = Wb + (size_t)br * 589824;
  float* out = (br ? sc0 : sa0) + (((size_t)b * 128) << 12) + (h << 6);

  int lane = t & 63, wave = t >> 6;
  int mi = lane & 15, quad = lane >> 4;
  int mt = cosplit * 4 + wave;

  if (t < 96) {
    int dh = t >> 5, side = (t >> 4) & 1, c8 = t & 15;
    short8 z8 = {0, 0, 0, 0, 0, 0, 0, 0};
    *(short8*)(xs + (dh * 66 + side * 65) * 136 + c8 * 8) = z8;
  }

  f32x4 acc[4] = {};

  const u16* wlane = wb + lane * 8;
  const u16* bbase0 = xs + mi * 136 + quad * 8;

  for (int chunk = 0; chunk < 4; ++chunk) {
    int ci0 = chunk << 7;
    __syncthreads();
#pragma unroll
    for (int dh = 0; dh < 3; ++dh) {
      int hh = h + dh - 1;
      bool val = (hh >= 0) && (hh < 64);
      const u16* src = xb + (((size_t)hh << 6) << 9) + ci0;
#pragma unroll
      for (int i = 0; i < 4; ++i) {
        int idx = t + i * 256;
        int w = idx >> 4, c8 = (idx & 15) << 3;
        short8 v = {0, 0, 0, 0, 0, 0, 0, 0};
        if (val) v = *(const short8*)(src + ((size_t)w << 9) + c8);
        *(short8*)(xs + (dh * 66 + 1 + w) * 136 + c8) = v;
      }
    }
    __syncthreads();
    const u16* wchunk = wlane + (size_t)(mt * 4 + chunk) * 18432;
    short8 wreg[2][4];
#pragma unroll
    for (int ks = 0; ks < 4; ++ks)
      wreg[0][ks] = *(const short8*)(wchunk + ks * 512);
#pragma unroll
    for (int tap = 0; tap < 9; ++tap) {
      const int cb = tap & 1;
      if (tap < 8) {
        const u16* wn = wchunk + (tap + 1) * 2048;
#pragma unroll
        for (int ks = 0; ks < 4; ++ks)
          wreg[cb ^ 1][ks] = *(const short8*)(wn + ks * 512);
      }
      const int dh = tap / 3, dw = tap % 3;
      const u16* bp = bbase0 + (dh * 66 + dw) * 136;
#pragma unroll
      for (int ks = 0; ks < 4; ++ks) {
        short8 a = wreg[cb][ks];
#pragma unroll
        for (int nt = 0; nt < 4; ++nt) {
          short8 bf = *(const short8*)(bp + nt * 2176 + ks * 32);
          acc[nt] = __builtin_amdgcn_mfma_f32_16x16x32_bf16(a, bf, acc[nt], 0, 0, 0);
        }
      }
    }
  }
#pragma unroll
  for (int nt = 0; nt < 4; ++nt)
#pragma unroll
    for (int r = 0; r < 4; ++r) {
      int co = mt * 16 + quad * 4 + r;
      out[((size_t)co << 12) + nt * 16 + mi] = acc[nt][r];
    }
  if (br == 0) {
    u16* dstq = sa_nhwc + ((size_t)b << 19) + ((size_t)h << 6) * 128;
#pragma unroll
    for (int nt = 0; nt < 4; ++nt) {
      U16x4 v4;
      v4.x = f2bf(acc[nt][0]); v4.y = f2bf(acc[nt][1]);
      v4.z = f2bf(acc[nt][2]); v4.w = f2bf(acc[nt][3]);
      *(U16x4*)(dstq + (size_t)(nt * 16 + mi) * 128 + mt * 16 + quad * 4) = v4;
    }
  } else {
    u16* dh_ = sc16h + ((size_t)b << 19) + (h << 6);
    u16* dl_ = sc16l + ((size_t)b << 19) + (h << 6);
#pragma unroll
    for (int nt = 0; nt < 4; ++nt)
#pragma unroll
      for (int r = 0; r < 4; ++r) {
        int co = mt * 16 + quad * 4 + r;
        float xv = acc[nt][r];
        u16 hi = f2bf(xv);
        float lo = xv - bf2f(hi);
        size_t o = ((size_t)co << 12) + nt * 16 + mi;
        dh_[o] = hi;
        dl_[o] = f2bf(lo);
      }
  }
}

// ---------------- K3: fused q,k,v 1x1 convs via MFMA -------------------------
__global__ __launch_bounds__(256) void k_qkv(
    const u16* __restrict__ sa_nhwc, const u16* __restrict__ Wqkvb,
    const float* __restrict__ bq, const float* __restrict__ bk,
    const float* __restrict__ bv,
    float* __restrict__ qb, float* __restrict__ kbuf, u16* __restrict__ vt16) {
  __shared__ float bs[160];
  int t = threadIdx.x;
  int b = blockIdx.y, n0 = blockIdx.x * 128;
  if (t < 160) bs[t] = t < 16 ? bq[t] : (t < 32 ? bk[t - 16] : bv[t - 32]);
  __syncthreads();
  int lane = t & 63, wave = t >> 6;
  int mi = lane & 15, quad = lane >> 4;
  const u16* xb = sa_nhwc + ((size_t)b << 19) + (size_t)n0 * 128;
  const u16* wb = Wqkvb + lane * 8;
  f32x4 acc[2][10] = {};
  short8 bf[2][4];
#pragma unroll
  for (int ns = 0; ns < 2; ++ns) {
    int n = wave * 32 + ns * 16 + mi;
#pragma unroll
    for (int ks = 0; ks < 4; ++ks)
      bf[ns][ks] = *(const short8*)(xb + (size_t)n * 128 + ks * 32 + quad * 8);
  }
#pragma unroll
  for (int cot = 0; cot < 10; ++cot) {
    short8 a0 = *(const short8*)(wb + (size_t)(cot * 4 + 0) * 512);
    short8 a1 = *(const short8*)(wb + (size_t)(cot * 4 + 1) * 512);
    short8 a2 = *(const short8*)(wb + (size_t)(cot * 4 + 2) * 512);
    short8 a3 = *(const short8*)(wb + (size_t)(cot * 4 + 3) * 512);
#pragma unroll
    for (int ns = 0; ns < 2; ++ns) {
      acc[ns][cot] = __builtin_amdgcn_mfma_f32_16x16x32_bf16(a0, bf[ns][0], acc[ns][cot], 0, 0, 0);
      acc[ns][cot] = __builtin_amdgcn_mfma_f32_16x16x32_bf16(a1, bf[ns][1], acc[ns][cot], 0, 0, 0);
      acc[ns][cot] = __builtin_amdgcn_mfma_f32_16x16x32_bf16(a2, bf[ns][2], acc[ns][cot], 0, 0, 0);
      acc[ns][cot] = __builtin_amdgcn_mfma_f32_16x16x32_bf16(a3, bf[ns][3], acc[ns][cot], 0, 0, 0);
    }
  }
#pragma unroll
  for (int cot = 0; cot < 10; ++cot)
#pragma unroll
    for (int ns = 0; ns < 2; ++ns)
#pragma unroll
      for (int r = 0; r < 4; ++r) {
        int co = cot * 16 + quad * 4 + r;
        int n = n0 + wave * 32 + ns * 16 + mi;
        float v = acc[ns][cot][r] + bs[co];
        if (co < 16) qb[((b * 16 + co) << 12) + n] = v;
        else if (co < 32) kbuf[((b * 16 + co - 16) << 12) + n] = v;
        else vt16[((size_t)(b * 128 + co - 32) << 12) + n] = f2bf(v);
      }
}

// ---------------- K4: PAM softmax row stats; 4 n per lane, 16 n per block ----
__global__ __launch_bounds__(256) void k_pam_stats(const float* __restrict__ qb,
    const float* __restrict__ kb, float* __restrict__ rmax, float* __restrict__ rinv) {
  int t = threadIdx.x, lane = t & 63, wid = t >> 6;
  int b = blockIdx.y;
  int n0 = blockIdx.x * 16 + wid * 4;
  float qreg[4][16];
  const float* qp = qb + ((size_t)b * 16 << 12) + n0;
#pragma unroll
  for (int ch = 0; ch < 16; ++ch)
#pragma unroll
    for (int j = 0; j < 4; ++j) qreg[j][ch] = qp[(ch << 12) + j];
  const float* kp = kb + ((size_t)b * 16 << 12);
  float mx[4], se[4];
#pragma unroll
  for (int j = 0; j < 4; ++j) { mx[j] = -1e30f; se[j] = 0.f; }
  for (int m4 = lane * 4; m4 < 4096; m4 += 256) {
    float e[4][4] = {};
#pragma unroll
    for (int ch = 0; ch < 16; ++ch) {
      float4 kv = *(const float4*)(kp + (ch << 12) + m4);
#pragma unroll
      for (int j = 0; j < 4; ++j) {
        float qv = qreg[j][ch];
        e[j][0] = fmaf(qv, kv.x, e[j][0]);
        e[j][1] = fmaf(qv, kv.y, e[j][1]);
        e[j][2] = fmaf(qv, kv.z, e[j][2]);
        e[j][3] = fmaf(qv, kv.w, e[j][3]);
      }
    }
#pragma unroll
    for (int j = 0; j < 4; ++j) {
      float lm = fmaxf(fmaxf(e[j][0], e[j][1]), fmaxf(e[j][2], e[j][3]));
      float nm = fmaxf(mx[j], lm);
      se[j] = se[j] * __expf(mx[j] - nm)
            + __expf(e[j][0] - nm) + __expf(e[j][1] - nm)
            + __expf(e[j][2] - nm) + __expf(e[j][3] - nm);
      mx[j] = nm;
    }
  }
#pragma unroll
  for (int off = 32; off >= 1; off >>= 1) {
#pragma unroll
    for (int j = 0; j < 4; ++j) {
      float om = __shfl_xor(mx[j], off);
      float os = __shfl_xor(se[j], off);
      float nm = fmaxf(mx[j], om);
      se[j] = se[j] * __expf(mx[j] - nm) + os * __expf(om - nm);
      mx[j] = nm;
    }
  }
  if (lane == 0) {
#pragma unroll
    for (int j = 0; j < 4; ++j) {
      rmax[(b << 12) + n0 + j] = mx[j];
      rinv[(b << 12) + n0 + j] = 1.f / se[j];
    }
  }
}

// ---------------- K5: PAM PV, MFMA energy (split-bf16) + MFMA PV -------------
// grid (128, 2, 2): block = 32 n x 2048 m x 128 c. 8 waves; per 256-m chunk:
// wave w owns m slice [32w,32w+32). Energy e = K^T Q via 2 split-MFMAs/tile;
// exp -> pL[n][m]; PV MFMA. K staged as split bf16 A-frags in LDS (dbuf),
// VECTOR writes: thread (m=t&255, half=t>>8) loads 8 consecutive channels
// (coalesced per-j) and writes 2 short8 -> conflict-free (KSTR=40 rows).
__global__ __launch_bounds__(512, 4) void k_pam_pv(const float* __restrict__ qb,
    const float* __restrict__ kb, const u16* __restrict__ vt16,
    const float* __restrict__ rmax, const float* __restrict__ rinv,
    const float* __restrict__ gamma, float* __restrict__ pvpart) {
  constexpr int KSTR = 40;           // u16 per m-row (80B)
  constexpr int PSTR = 264;          // u16; odd 16B stride
  __shared__ u16 kst[2][256 * KSTR]; // [buf][m][kh(16)|kl(16)]
  __shared__ u16 pL[32 * PSTR];      // [n][m] bf16
  __shared__ u16 qfh[32 * 16], qfl[32 * 16];   // [n][ch]
  int t = threadIdx.x;
  int b = blockIdx.y, n0 = blockIdx.x * 32;
  int mbeg = blockIdx.z << 11;       // 0 or 2048
  int lane = t & 63, wave = t >> 6;
  int mi = lane & 15, quad = lane >> 4;
  int c0 = wave * 16;
  // build q hi/lo fragments (once)
  {
    int ch = t & 15, nl = t >> 4;    // 512 = 32 n x 16 ch
    float qv = qb[((size_t)(b * 16 + ch) << 12) + n0 + nl];
    u16 hi = f2bf(qv);
    qfh[nl * 16 + ch] = hi;
    qfl[nl * 16 + ch] = f2bf(qv - bf2f(hi));
  }
  float mv0 = rmax[(b << 12) + n0 + mi],      iv0 = rinv[(b << 12) + n0 + mi];
  float mv1 = rmax[(b << 12) + n0 + 16 + mi], iv1 = rinv[(b << 12) + n0 + 16 + mi];
  const float* kpb = kb + ((size_t)b * 16 << 12) + mbeg;
  const u16* vb = vt16 + ((size_t)b * 128 << 12);
  f32x4 acc[2] = {};
  // staging mapping: m = t&255, half = t>>8 -> channels half*8 .. half*8+7
  int sm = t & 255, shalf = t >> 8;
  {
    short8 hi8, lo8;
#pragma unroll
    for (int j = 0; j < 8; ++j) {
      float v = kpb[((size_t)(shalf * 8 + j) << 12) + sm];
      u16 hi = f2bf(v);
      hi8[j] = (short)hi;
      lo8[j] = (short)f2bf(v - bf2f(hi));
    }
    *(short8*)(kst[0] + sm * KSTR + shalf * 8) = hi8;
    *(short8*)(kst[0] + sm * KSTR + 16 + shalf * 8) = lo8;
  }
  __syncthreads();   // kst[0] + qfh/qfl ready
  // hoist Q B-frags: B1=[qh|qh], B2=[ql|ql]; col=n=mi, k=quad*8+j -> ch=(k&15)
  int qoff = (quad & 1) * 8;
  short8 bq1[2], bq2[2];
  bq1[0] = *(const short8*)(qfh + mi * 16 + qoff);
  bq1[1] = *(const short8*)(qfh + (16 + mi) * 16 + qoff);
  bq2[0] = *(const short8*)(qfl + mi * 16 + qoff);
  bq2[1] = *(const short8*)(qfl + (16 + mi) * 16 + qoff);
  int cur = 0;
  for (int it = 0; it < 8; ++it) {
    int m0 = mbeg + (it << 8);
    // prefetch this chunk's V fragments
    short8 vreg[8];
#pragma unroll
    for (int ksl = 0; ksl < 8; ++ksl)
      vreg[ksl] = *(const short8*)(vb + ((size_t)(c0 + mi) << 12) + m0 + ksl * 32 + quad * 8);
    // issue next-chunk K loads early
    float kreg[8];
    if (it < 7) {
#pragma unroll
      for (int j = 0; j < 8; ++j)
        kreg[j] = kpb[((size_t)(shalf * 8 + j) << 12) + ((it + 1) << 8) + sm];
    }
    // energy via MFMA: wave's m slice [wave*32, +32), all 32 n
    {
      const u16* ka = kst[cur] + (wave * 32) * KSTR;
      short8 a0 = *(const short8*)(ka + mi * KSTR + quad * 8);
      short8 a1 = *(const short8*)(ka + (16 + mi) * KSTR + quad * 8);
      f32x4 e00 = {}, e01 = {}, e10 = {}, e11 = {};
      e00 = __builtin_amdgcn_mfma_f32_16x16x32_bf16(a0, bq1[0], e00, 0, 0, 0);
      e00 = __builtin_amdgcn_mfma_f32_16x16x32_bf16(a0, bq2[0], e00, 0, 0, 0);
      e01 = __builtin_amdgcn_mfma_f32_16x16x32_bf16(a0, bq1[1], e01, 0, 0, 0);
      e01 = __builtin_amdgcn_mfma_f32_16x16x32_bf16(a0, bq2[1], e01, 0, 0, 0);
      e10 = __builtin_amdgcn_mfma_f32_16x16x32_bf16(a1, bq1[0], e10, 0, 0, 0);
      e10 = __builtin_amdgcn_mfma_f32_16x16x32_bf16(a1, bq2[0], e10, 0, 0, 0);
      e11 = __builtin_amdgcn_mfma_f32_16x16x32_bf16(a1, bq1[1], e11, 0, 0, 0);
      e11 = __builtin_amdgcn_mfma_f32_16x16x32_bf16(a1, bq2[1], e11, 0, 0, 0);
      // D: m = wave*32 + mt*16 + quad*4 + r, n = nt*16 + mi
      u16* prow0 = pL + mi * PSTR + wave * 32 + quad * 4;          // nt=0
      u16* prow1 = pL + (16 + mi) * PSTR + wave * 32 + quad * 4;   // nt=1
      U16x4 p;
      p.x = f2bf(__expf(fminf(e00[0] - mv0, 0.f)) * iv0);
      p.y = f2bf(__expf(fminf(e00[1] - mv0, 0.f)) * iv0);
      p.z = f2bf(__expf(fminf(e00[2] - mv0, 0.f)) * iv0);
      p.w = f2bf(__expf(fminf(e00[3] - mv0, 0.f)) * iv0);
      *(U16x4*)(prow0) = p;
      p.x = f2bf(__expf(fminf(e10[0] - mv0, 0.f)) * iv0);
      p.y = f2bf(__expf(fminf(e10[1] - mv0, 0.f)) * iv0);
      p.z = f2bf(__expf(fminf(e10[2] - mv0, 0.f)) * iv0);
      p.w = f2bf(__expf(fminf(e10[3] - mv0, 0.f)) * iv0);
      *(U16x4*)(prow0 + 16) = p;
      p.x = f2bf(__expf(fminf(e01[0] - mv1, 0.f)) * iv1);
      p.y = f2bf(__expf(fminf(e01[1] - mv1, 0.f)) * iv1);
      p.z = f2bf(__expf(fminf(e01[2] - mv1, 0.f)) * iv1);
      p.w = f2bf(__expf(fminf(e01[3] - mv1, 0.f)) * iv1);
      *(U16x4*)(prow1) = p;
      p.x = f2bf(__expf(fminf(e11[0] - mv1, 0.f)) * iv1);
      p.y = f2bf(__expf(fminf(e11[1] - mv1, 0.f)) * iv1);
      p.z = f2bf(__expf(fminf(e11[2] - mv1, 0.f)) * iv1);
      p.w = f2bf(__expf(fminf(e11[3] - mv1, 0.f)) * iv1);
      *(U16x4*)(prow1 + 16) = p;
    }
    __syncthreads();   // P ready; kst[cur] energy reads done
    // stage next K into alternate buffer (overlaps PV MFMA phase)
    if (it < 7) {
      short8 hi8, lo8;
#pragma unroll
      for (int j = 0; j < 8; ++j) {
        u16 hi = f2bf(kreg[j]);
        hi8[j] = (short)hi;
        lo8[j] = (short)f2bf(kreg[j] - bf2f(hi));
      }
      *(short8*)(kst[cur ^ 1] + sm * KSTR + shalf * 8) = hi8;
      *(short8*)(kst[cur ^ 1] + sm * KSTR + 16 + shalf * 8) = lo8;
    }
    // PV MFMA: acc[c][n] += V[c][m] * P[n][m]
#pragma unroll
    for (int ksl = 0; ksl < 8; ++ksl) {
      const u16* pb0 = pL + mi * PSTR + ksl * 32 + quad * 8;
      short8 b0 = *(const short8*)(pb0);
      short8 b1 = *(const short8*)(pb0 + 16 * PSTR);
      acc[0] = __builtin_amdgcn_mfma_f32_16x16x32_bf16(vreg[ksl], b0, acc[0], 0, 0, 0);
      acc[1] = __builtin_amdgcn_mfma_f32_16x16x32_bf16(vreg[ksl], b1, acc[1], 0, 0, 0);
    }
    __syncthreads();   // pL free; kst[cur^1] writes done
    cur ^= 1;
  }
  float g = gamma[0];
  float* dst = pvpart + (((size_t)(blockIdx.z * 2 + b) * 128) << 12);
#pragma unroll
  for (int nh = 0; nh < 2; ++nh)
#pragma unroll
    for (int r = 0; r < 4; ++r) {
      int c = c0 + quad * 4 + r;
      dst[((size_t)c << 12) + n0 + nh * 16 + mi] = g * acc[nh][r];
    }
}

// ---------------- K6a: CAM Gram energy via MFMA, split-bf16 ------------------
__global__ __launch_bounds__(512) void k_cam_energy_m(
    const u16* __restrict__ sc16h, const u16* __restrict__ sc16l,
    float* __restrict__ epart) {
  int t = threadIdx.x;
  int ti = blockIdx.x, kc = blockIdx.y, b = blockIdx.z;
  int lane = t & 63, wave = t >> 6;
  int mi = lane & 15, quad = lane >> 4;
  const u16* fh = sc16h + ((size_t)b << 19);
  const u16* fl = sc16l + ((size_t)b << 19);
  size_t ao = ((size_t)(ti * 16 + mi) << 12) + (kc << 9) + quad * 8;
  size_t bo = ((size_t)(wave * 16 + mi) << 12) + (kc << 9) + quad * 8;
  const u16* ah = fh + ao; const u16* al = fl + ao;
  const u16* bh = fh + bo; const u16* bl = fl + bo;
  f32x4 acc = {};
#pragma unroll
  for (int k = 0; k < 16; ++k) {
    short8 vah = *(const short8*)(ah + k * 32);
    short8 val = *(const short8*)(al + k * 32);
    short8 vbh = *(const short8*)(bh + k * 32);
    short8 vbl = *(const short8*)(bl + k * 32);
    acc = __builtin_amdgcn_mfma_f32_16x16x32_bf16(vah, vbh, acc, 0, 0, 0);
    acc = __builtin_amdgcn_mfma_f32_16x16x32_bf16(vah, vbl, acc, 0, 0, 0);
    acc = __builtin_amdgcn_mfma_f32_16x16x32_bf16(val, vbh, acc, 0, 0, 0);
  }
  float* ep = epart + (((size_t)(kc * 2 + b)) << 14);
#pragma unroll
  for (int r = 0; r < 4; ++r)
    ep[((ti * 16 + quad * 4 + r) << 7) + wave * 16 + mi] = acc[r];
}

// ---------------- K6b: CAM softmax row (reduce 8 partials) -------------------
__global__ void k_cam_softmax(const float* __restrict__ epart, float* __restrict__ attn) {
  int lane = threadIdx.x;
  int c = blockIdx.x, b = blockIdx.y;
  float e0 = 0.f, e1 = 0.f;
#pragma unroll
  for (int kc = 0; kc < 8; ++kc) {
    const float* ep = epart + (((size_t)(kc * 2 + b)) << 14) + (c << 7);
    e0 += ep[lane];
    e1 += ep[lane + 64];
  }
  float mn = fminf(e0, e1);
#pragma unroll
  for (int off = 32; off >= 1; off >>= 1) mn = fminf(mn, __shfl_xor(mn, off));
  float p0 = __expf(fminf(mn - e0, 0.f)), p1 = __expf(fminf(mn - e1, 0.f));
  float s = p0 + p1;
#pragma unroll
  for (int off = 32; off >= 1; off >>= 1) s += __shfl_xor(s, off);
  float inv = 1.f / s;
  float* a = attn + ((b * 128 + c) << 7);
  a[lane] = p0 * inv;
  a[lane + 64] = p1 * inv;
}

// ---------------- K7: CAM out + residual -------------------------------------
__global__ __launch_bounds__(256) void k_cam_out(const float* __restrict__ f,
    const float* __restrict__ attn, const float* __restrict__ gamma,
    float* __restrict__ sc1) {
  __shared__ float at2[128 * 16];
  int t = threadIdx.x;
  int b = blockIdx.z, c0 = blockIdx.y * 16;
  int n = blockIdx.x * 256 + t;
  for (int idx = t; idx < 2048; idx += 256) {
    int d = idx >> 4, cc = idx & 15;
    at2[idx] = attn[((b * 128 + c0 + cc) << 7) + d];
  }
  __syncthreads();
  float acc[16] = {};
  const float* fb = f + ((size_t)b * 128 << 12) + n;
  for (int d = 0; d < 128; ++d) {
    float fv = fb[d << 12];
    const float* ap = at2 + d * 16;
#pragma unroll
    for (int cc = 0; cc < 16; ++cc) acc[cc] = fmaf(ap[cc], fv, acc[cc]);
  }
  float g = gamma[0];
#pragma unroll
  for (int cc = 0; cc < 16; ++cc) {
    size_t o = ((size_t)(b * 128 + c0 + cc) << 12) + n;
    sc1[o] = fmaf(g, acc[cc], f[o]);
  }
}

// ---------------- K8: BN+ReLU + 1x1 conv 128->512 via MFMA -------------------
__global__ __launch_bounds__(256, 2) void k_bout_m(
    const float* __restrict__ sa0, const float* __restrict__ pvpart,
    const float* __restrict__ sc1,
    const float* __restrict__ wa_, const float* __restrict__ ba_,
    const float* __restrict__ ma_, const float* __restrict__ va_,
    const float* __restrict__ wc_, const float* __restrict__ bc_,
    const float* __restrict__ mc_, const float* __restrict__ vc_,
    const u16* __restrict__ W1b, const float* __restrict__ Ba,
    const float* __restrict__ Bc,
    u16* __restrict__ sa2, u16* __restrict__ sc2) {
  __shared__ u16 xl[32 * 136];
  __shared__ float scl[128], shf[128];
  int t = threadIdx.x;
  int n0 = blockIdx.x * 32;
  int b = blockIdx.y, br = blockIdx.z;
  const float* bw = br ? wc_ : wa_;
  const float* bb = br ? bc_ : ba_;
  const float* bm = br ? mc_ : ma_;
  const float* bvv = br ? vc_ : va_;
  if (t < 128) {
    float s = bw[t] * rsqrtf(bvv[t] + 1e-5f);
    scl[t] = s;
    shf[t] = bb[t] - bm[t] * s;
  }
  __syncthreads();
  {
    int nl = t & 31, cio = t >> 5;
    const float* s0 = (br ? sc1 : sa0) + ((size_t)b * 128 << 12) + n0 + nl;
    const float* p0 = pvpart + ((size_t)b * 128 << 12) + n0 + nl;
    const float* p1 = pvpart + (((size_t)(2 + b) * 128) << 12) + n0 + nl;
#pragma unroll
    for (int half = 0; half < 2; ++half) {
      short8 v;
#pragma unroll
      for (int i = 0; i < 8; ++i) {
        int ci = cio * 16 + half * 8 + i;
        float xv = s0[(size_t)ci << 12];
        if (!br) xv += p0[(size_t)ci << 12] + p1[(size_t)ci << 12];
        v[i] = (short)f2bf(fmaxf(fmaf(xv, scl[ci], shf[ci]), 0.f));
      }
      *(short8*)(xl + nl * 136 + cio * 16 + half * 8) = v;
    }
  }
  __syncthreads();
  int lane = t & 63, wave = t >> 6;
  int mi = lane & 15, quad = lane >> 4;
  const u16* wb = W1b + (size_t)br * 65536 + lane * 8;
  f32x4 acc[8][2] = {};
#pragma unroll
  for (int ks = 0; ks < 4; ++ks) {
    short8 b0 = *(const short8*)(xl + mi * 136 + ks * 32 + quad * 8);
    short8 b1 = *(const short8*)(xl + (16 + mi) * 136 + ks * 32 + quad * 8);
#pragma unroll
    for (int ct = 0; ct < 8; ++ct) {
      int cot = wave * 8 + ct;
      short8 a = *(const short8*)(wb + ((size_t)(cot * 4 + ks) << 9));
      acc[ct][0] = __builtin_amdgcn_mfma_f32_16x16x32_bf16(a, b0, acc[ct][0], 0, 0, 0);
      acc[ct][1] = __builtin_amdgcn_mfma_f32_16x16x32_bf16(a, b1, acc[ct][1], 0, 0, 0);
    }
  }
  const float* Bs = br ? Bc : Ba;
  u16* dst = br ? sc2 : sa2;
#pragma unroll
  for (int ct = 0; ct < 8; ++ct)
#pragma unroll
    for (int nh = 0; nh < 2; ++nh)
#pragma unroll
      for (int r = 0; r < 4; ++r) {
        int co = (wave * 8 + ct) * 16 + quad * 4 + r;
        dst[((size_t)(b * 512 + co) << 12) + n0 + nh * 16 + mi] =
            f2bf(acc[ct][nh][r] + Bs[co]);
      }
}

// ---------------- K9a: fusion + partial class-head sums (8-way c split) ------
__global__ __launch_bounds__(256) void k_heads(const u16* __restrict__ sa2,
    const u16* __restrict__ sc2,
    const float* __restrict__ wf, const float* __restrict__ wa, const float* __restrict__ wc,
    float* __restrict__ outFusion, float* __restrict__ clsacc) {
  __shared__ float lw[3 * 5 * 64];
  int t = threadIdx.x;
  int b = blockIdx.y, co0 = blockIdx.z * 64;
  int n = blockIdx.x * 256 + t;
  for (int idx = t; idx < 960; idx += 256) {
    int arr = idx / 320, rest = idx - arr * 320;
    int cls = rest >> 6, cc = rest & 63;
    const float* w = arr == 0 ? wf : (arr == 1 ? wa : wc);
    lw[idx] = w[cls * 512 + co0 + cc];
  }
  __syncthreads();
  float af[5] = {}, aa[5] = {}, ac[5] = {};
  for (int cc = 0; cc < 64; ++cc) {
    size_t o = ((size_t)(b * 512 + co0 + cc) << 12) + n;
    float a = bf2f(sa2[o]), c = bf2f(sc2[o]);
    float s = a + c;
    outFusion[o] = s;
#pragma unroll
    for (int cls = 0; cls < 5; ++cls) {
      af[cls] = fmaf(lw[0 * 320 + cls * 64 + cc], s, af[cls]);
      aa[cls] = fmaf(lw[1 * 320 + cls * 64 + cc], a, aa[cls]);
      ac[cls] = fmaf(lw[2 * 320 + cls * 64 + cc], c, ac[cls]);
    }
  }
#pragma unroll
  for (int cls = 0; cls < 5; ++cls) {
    int o = ((b * 5 + cls) << 12) + n;
    atomicAdd(&clsacc[o], af[cls]);
    atomicAdd(&clsacc[40960 + o], aa[cls]);
    atomicAdd(&clsacc[81920 + o], ac[cls]);
  }
}

// ---------------- K9b: add bias, f32 out -------------------------------------
__global__ void k_heads_final(const float* __restrict__ clsacc,
    const float* __restrict__ bf_, const float* __restrict__ ba_,
    const float* __restrict__ bc_, float* __restrict__ outCls) {
  int idx = blockIdx.x * 256 + threadIdx.x;   // 122880
  int arr = idx / 40960;
  int rest = idx - arr * 40960;
  int cls = (rest >> 12) % 5;
  const float* bp = arr == 0 ? bf_ : (arr == 1 ? ba_ : bc_);
  outCls[idx] = clsacc[idx] + bp[cls];
}

extern "C" void kernel_launch(void* const* d_in, const int* in_sizes, int n_in,
                              void* d_out, int out_size, void* d_ws, size_t ws_size,
                              hipStream_t stream) {
  (void)in_sizes; (void)n_in; (void)out_size; (void)ws_size;
  const float* x      = (const float*)d_in[0];
  const float* bnaw   = (const float*)d_in[1];
  const float* bnab   = (const float*)d_in[2];
  const float* bnam   = (const float*)d_in[3];
  const float* bnav   = (const float*)d_in[4];
  const float* convaw = (const float*)d_in[5];
  const float* bncw   = (const float*)d_in[6];
  const float* bncb   = (const float*)d_in[7];
  const float* bncm   = (const float*)d_in[8];
  const float* bncv   = (const float*)d_in[9];
  const float* convcw = (const float*)d_in[10];
  const float* pqw    = (const float*)d_in[11];
  const float* pqb    = (const float*)d_in[12];
  const float* pkw    = (const float*)d_in[13];
  const float* pkb    = (const float*)d_in[14];
  const float* pvw    = (const float*)d_in[15];
  const float* pvb    = (const float*)d_in[16];
  const float* pgam   = (const float*)d_in[17];
  const float* cgam   = (const float*)d_in[18];
  const float* bna1w  = (const float*)d_in[19];
  const float* bna1b  = (const float*)d_in[20];
  const float* bna1m  = (const float*)d_in[21];
  const float* bna1v  = (const float*)d_in[22];
  const float* conva1w = (const float*)d_in[23];
  const float* conva1b = (const float*)d_in[24];
  const float* bnc1w  = (const float*)d_in[25];
  const float* bnc1b  = (const float*)d_in[26];
  const float* bnc1m  = (const float*)d_in[27];
  const float* bnc1v  = (const float*)d_in[28];
  const float* convc1w = (const float*)d_in[29];
  const float* convc1b = (const float*)d_in[30];
  const float* outaw  = (const float*)d_in[31];
  const float* outab  = (const float*)d_in[32];
  const float* outcw  = (const float*)d_in[33];
  const float* outcb  = (const float*)d_in[34];
  const float* outfw  = (const float*)d_in[35];
  const float* outfb  = (const float*)d_in[36];

  char* wsb = (char*)d_ws;
  size_t off = 0;
  auto take = [&](size_t bytes) -> void* {
    void* p = wsb + off;
    off += (bytes + 255) & ~(size_t)255;
    return p;
  };
  u16*   Wb    = (u16*)take((size_t)2 * 128 * 9 * 512 * 2);
  u16*   W1b   = (u16*)take((size_t)2 * 512 * 128 * 2);
  u16*   Wqkvb = (u16*)take((size_t)160 * 128 * 2);
  u16*   xa16  = (u16*)take((size_t)2 * 512 * 4096 * 2);
  u16*   xcb16 = (u16*)take((size_t)2 * 512 * 4096 * 2);
  float* sa0   = (float*)take((size_t)2 * 128 * 4096 * 4);
  float* sc0   = (float*)take((size_t)2 * 128 * 4096 * 4);
  u16*   sa_nhwc = (u16*)take((size_t)2 * 4096 * 128 * 2);
  u16*   sc16h = (u16*)take((size_t)2 * 128 * 4096 * 2);
  u16*   sc16l = (u16*)take((size_t)2 * 128 * 4096 * 2);
  float* qb    = (float*)take((size_t)2 * 16 * 4096 * 4);
  float* kbuf  = (float*)take((size_t)2 * 16 * 4096 * 4);
  u16*   vt16  = (u16*)take((size_t)2 * 128 * 4096 * 2);
  float* rmax  = (float*)take((size_t)2 * 4096 * 4);
  float* rinv  = (float*)take((size_t)2 * 4096 * 4);
  float* pvpart = (float*)take((size_t)2 * 2 * 128 * 4096 * 4);
  float* sc1   = (float*)take((size_t)2 * 128 * 4096 * 4);
  float* epart = (float*)take((size_t)8 * 2 * 128 * 128 * 4);
  float* attn  = (float*)take((size_t)2 * 128 * 128 * 4);
  u16*   sa2   = (u16*)take((size_t)2 * 512 * 4096 * 2);
  u16*   sc2   = (u16*)take((size_t)2 * 512 * 4096 * 2);
  float* clsacc = (float*)take((size_t)3 * 2 * 5 * 4096 * 4);

  float* outF = (float*)d_out;
  float* outCls = outF + (size_t)2 * 512 * 4096;

  hipMemsetAsync(clsacc, 0, (size_t)3 * 2 * 5 * 4096 * 4, stream);

  k_prep_w<<<4608, 256, 0, stream>>>(convaw, convcw, Wb);
  k_prep_w1<<<512, 256, 0, stream>>>(conva1w, convc1w, W1b);
  k_prep_wqkv<<<80, 256, 0, stream>>>(pqw, pkw, pvw, Wqkvb);
  k_bnrelu2t<<<dim3(64, 2), 256, 0, stream>>>(x, bnaw, bnab, bnam, bnav,
                                              bncw, bncb, bncm, bncv, xa16, xcb16);
  k_conv3n<<<dim3(64, 4, 2), 256, 0, stream>>>(xa16, xcb16, Wb, sa0, sc0,
                                               sa_nhwc, sc16h, sc16l);
  k_qkv<<<dim3(32, 2), 256, 0, stream>>>(sa_nhwc, Wqkvb, pqb, pkb, pvb,
                                         qb, kbuf, vt16);
  k_pam_stats<<<dim3(256, 2), 256, 0, stream>>>(qb, kbuf, rmax, rinv);
  k_pam_pv<<<dim3(128, 2, 2), 512, 0, stream>>>(qb, kbuf, vt16, rmax, rinv, pgam, pvpart);
  k_cam_energy_m<<<dim3(8, 8, 2), 512, 0, stream>>>(sc16h, sc16l, epart);
  k_cam_softmax<<<dim3(128, 2), 64, 0, stream>>>(epart, attn);
  k_cam_out<<<dim3(16, 8, 2), 256, 0, stream>>>(sc0, attn, cgam, sc1);
  k_bout_m<<<dim3(128, 2, 2), 256, 0, stream>>>(sa0, pvpart, sc1,
      bna1w, bna1b, bna1m, bna1v, bnc1w, bnc1b, bnc1m, bnc1v,
      W1b, conva1b, convc1b, sa2, sc2);
  k_heads<<<dim3(16, 2, 8), 256, 0, stream>>>(sa2, sc2, outfw, outaw, outcw, outF, clsacc);
  k_heads_final<<<480, 256, 0, stream>>>(clsacc, outfb, outab, outcb, outCls);
}

// Round 9
// 312.293 us; speedup vs baseline: 1.8422x; 1.0815x over previous
//
#include <hip/hip_runtime.h>

using u16 = unsigned short;
using short8 = __attribute__((ext_vector_type(8))) short;
using f32x4 = __attribute__((ext_vector_type(4))) float;

struct alignas(8) U16x4 { u16 x, y, z, w; };

__device__ __forceinline__ float bf2f(u16 u) {
  return __uint_as_float(((unsigned int)u) << 16);
}
__device__ __forceinline__ u16 f2bf(float f) {
  unsigned int u = __float_as_uint(f);
  unsigned int r = u + 0x7FFFu + ((u >> 16) & 1u);
  return (u16)(r >> 16);
}

// ---------------- K0b: conv weights -> bf16, MFMA-fragment order -------------
// Layout: [br][mt(8)][chunk(4)][tap(9)][ks(4)][lane(64)][j(8)]
__global__ void k_prep_w(const float* __restrict__ wa, const float* __restrict__ wc,
                         u16* __restrict__ Wb) {
  int idx = blockIdx.x * 256 + threadIdx.x;   // 1179648
  int j = idx & 7;
  int l = (idx >> 3) & 63;
  int ks = (idx >> 9) & 3;
  int rest = idx >> 11;
  int tap = rest % 9;
  int rest2 = rest / 9;
  int chunk = rest2 & 3;
  int mt = (rest2 >> 2) & 7;
  int br = rest2 >> 5;
  int co = mt * 16 + (l & 15);
  int ci = chunk * 128 + ks * 32 + (l >> 4) * 8 + j;
  const float* w = br ? wc : wa;
  Wb[idx] = f2bf(w[co * 4608 + ci * 9 + tap]);
}

// ---------------- K0c: 1x1 out-conv weights (128->512) -> bf16 A-frag order --
__global__ void k_prep_w1(const float* __restrict__ wa, const float* __restrict__ wc,
                          u16* __restrict__ W1b) {
  int idx = blockIdx.x * 256 + threadIdx.x;   // 131072
  int j = idx & 7;
  int l = (idx >> 3) & 63;
  int ks = (idx >> 9) & 3;
  int cot = (idx >> 11) & 31;
  int br = idx >> 16;
  int co = cot * 16 + (l & 15);
  int ci = ks * 32 + (l >> 4) * 8 + j;
  const float* w = br ? wc : wa;
  W1b[idx] = f2bf(w[co * 128 + ci]);
}

// ---------------- K0d: qkv weights (160x128) -> bf16 A-frag order ------------
__global__ void k_prep_wqkv(const float* __restrict__ wq, const float* __restrict__ wk,
                            const float* __restrict__ wv, u16* __restrict__ Wq) {
  int idx = blockIdx.x * 256 + threadIdx.x;   // 20480
  if (idx >= 20480) return;
  int j = idx & 7;
  int l = (idx >> 3) & 63;
  int ks = (idx >> 9) & 3;
  int cot = idx >> 11;
  int co = cot * 16 + (l & 15);
  int ci = ks * 32 + (l >> 4) * 8 + j;
  float w = co < 16 ? wq[co * 128 + ci]
          : (co < 32 ? wk[(co - 16) * 128 + ci] : wv[(co - 32) * 128 + ci]);
  Wq[idx] = f2bf(w);
}

// ---------------- K1: BN+ReLU both branches, NHWC bf16 out -------------------
__global__ __launch_bounds__(256) void k_bnrelu2t(const float* __restrict__ x,
    const float* __restrict__ wa, const float* __restrict__ ba,
    const float* __restrict__ ma, const float* __restrict__ va,
    const float* __restrict__ wc, const float* __restrict__ bc,
    const float* __restrict__ mc, const float* __restrict__ vc,
    u16* __restrict__ xa16, u16* __restrict__ xcb16) {
  __shared__ float sA[512], bA[512], sC[512], bC[512];
  __shared__ u16 ta[64 * 136], tc[64 * 136];
  int t = threadIdx.x;
  int h = blockIdx.x, b = blockIdx.y;
  for (int c = t; c < 512; c += 256) {
    float s1 = wa[c] * rsqrtf(va[c] + 1e-5f);
    sA[c] = s1; bA[c] = ba[c] - ma[c] * s1;
    float s2 = wc[c] * rsqrtf(vc[c] + 1e-5f);
    sC[c] = s2; bC[c] = bc[c] - mc[c] * s2;
  }
  __syncthreads();
  const float* xb = x + ((size_t)b << 21) + (h << 6);
  u16* oa = xa16 + ((size_t)b << 21) + ((size_t)h << 15);
  u16* oc = xcb16 + ((size_t)b << 21) + ((size_t)h << 15);
  int w = t & 63, cg = t >> 6;
  for (int c0 = 0; c0 < 512; c0 += 128) {
#pragma unroll
    for (int i = 0; i < 8; ++i) {
      int cl = cg * 4 + i * 16;
      int c = c0 + cl;
      const float* xp = xb + (size_t)c * 4096 + w;
      float v0 = xp[0], v1 = xp[4096], v2 = xp[8192], v3 = xp[12288];
      U16x4 pa, pc;
      pa.x = f2bf(fmaxf(fmaf(v0, sA[c], bA[c]), 0.f));
      pa.y = f2bf(fmaxf(fmaf(v1, sA[c + 1], bA[c + 1]), 0.f));
      pa.z = f2bf(fmaxf(fmaf(v2, sA[c + 2], bA[c + 2]), 0.f));
      pa.w = f2bf(fmaxf(fmaf(v3, sA[c + 3], bA[c + 3]), 0.f));
      pc.x = f2bf(fmaxf(fmaf(v0, sC[c], bC[c]), 0.f));
      pc.y = f2bf(fmaxf(fmaf(v1, sC[c + 1], bC[c + 1]), 0.f));
      pc.z = f2bf(fmaxf(fmaf(v2, sC[c + 2], bC[c + 2]), 0.f));
      pc.w = f2bf(fmaxf(fmaf(v3, sC[c + 3], bC[c + 3]), 0.f));
      *(U16x4*)(ta + w * 136 + cl) = pa;
      *(U16x4*)(tc + w * 136 + cl) = pc;
    }
    __syncthreads();
#pragma unroll
    for (int i = 0; i < 4; ++i) {
      int idx = t + i * 256;
      int ww = idx >> 4, c8 = (idx & 15) << 3;
      *(short8*)(oa + (size_t)ww * 512 + c0 + c8) = *(const short8*)(ta + ww * 136 + c8);
      *(short8*)(oc + (size_t)ww * 512 + c0 + c8) = *(const short8*)(tc + ww * 136 + c8);
    }
    __syncthreads();
  }
}

// ---------------- K2: 3x3 conv, implicit GEMM, NHWC input --------------------
__global__ __launch_bounds__(256, 2) void k_conv3n(
    const u16* __restrict__ xa16, const u16* __restrict__ xcb16,
    const u16* __restrict__ Wb,
    float* __restrict__ sa0, float* __restrict__ sc0,
    u16* __restrict__ sa_nhwc, u16* __restrict__ sc16h, u16* __restrict__ sc16l) {
  __shared__ u16 xs[3 * 66 * 136];
  int t = threadIdx.x;
  int h = blockIdx.x;
  int z = blockIdx.y; int b = z & 1, br = z >> 1;
  int cosplit = blockIdx.z;
  const u16* xb = (br ? xcb16 : xa16) + ((size_t)b << 21);
  const u16* wb = Wb + (size_t)br * 589824;
  float* out = (br ? sc0 : sa0) + (((size_t)b * 128) << 12) + (h << 6);

  int lane = t & 63, wave = t >> 6;
  int mi = lane & 15, quad = lane >> 4;
  int mt = cosplit * 4 + wave;

  if (t < 96) {
    int dh = t >> 5, side = (t >> 4) & 1, c8 = t & 15;
    short8 z8 = {0, 0, 0, 0, 0, 0, 0, 0};
    *(short8*)(xs + (dh * 66 + side * 65) * 136 + c8 * 8) = z8;
  }

  f32x4 acc[4] = {};

  const u16* wlane = wb + lane * 8;
  const u16* bbase0 = xs + mi * 136 + quad * 8;

  for (int chunk = 0; chunk < 4; ++chunk) {
    int ci0 = chunk << 7;
    __syncthreads();
#pragma unroll
    for (int dh = 0; dh < 3; ++dh) {
      int hh = h + dh - 1;
      bool val = (hh >= 0) && (hh < 64);
      const u16* src = xb + (((size_t)hh << 6) << 9) + ci0;
#pragma unroll
      for (int i = 0; i < 4; ++i) {
        int idx = t + i * 256;
        int w = idx >> 4, c8 = (idx & 15) << 3;
        short8 v = {0, 0, 0, 0, 0, 0, 0, 0};
        if (val) v = *(const short8*)(src + ((size_t)w << 9) + c8);
        *(short8*)(xs + (dh * 66 + 1 + w) * 136 + c8) = v;
      }
    }
    __syncthreads();
    const u16* wchunk = wlane + (size_t)(mt * 4 + chunk) * 18432;
    short8 wreg[2][4];
#pragma unroll
    for (int ks = 0; ks < 4; ++ks)
      wreg[0][ks] = *(const short8*)(wchunk + ks * 512);
#pragma unroll
    for (int tap = 0; tap < 9; ++tap) {
      const int cb = tap & 1;
      if (tap < 8) {
        const u16* wn = wchunk + (tap + 1) * 2048;
#pragma unroll
        for (int ks = 0; ks < 4; ++ks)
          wreg[cb ^ 1][ks] = *(const short8*)(wn + ks * 512);
      }
      const int dh = tap / 3, dw = tap % 3;
      const u16* bp = bbase0 + (dh * 66 + dw) * 136;
#pragma unroll
      for (int ks = 0; ks < 4; ++ks) {
        short8 a = wreg[cb][ks];
#pragma unroll
        for (int nt = 0; nt < 4; ++nt) {
          short8 bf = *(const short8*)(bp + nt * 2176 + ks * 32);
          acc[nt] = __builtin_amdgcn_mfma_f32_16x16x32_bf16(a, bf, acc[nt], 0, 0, 0);
        }
      }
    }
  }
#pragma unroll
  for (int nt = 0; nt < 4; ++nt)
#pragma unroll
    for (int r = 0; r < 4; ++r) {
      int co = mt * 16 + quad * 4 + r;
      out[((size_t)co << 12) + nt * 16 + mi] = acc[nt][r];
    }
  if (br == 0) {
    u16* dstq = sa_nhwc + ((size_t)b << 19) + ((size_t)h << 6) * 128;
#pragma unroll
    for (int nt = 0; nt < 4; ++nt) {
      U16x4 v4;
      v4.x = f2bf(acc[nt][0]); v4.y = f2bf(acc[nt][1]);
      v4.z = f2bf(acc[nt][2]); v4.w = f2bf(acc[nt][3]);
      *(U16x4*)(dstq + (size_t)(nt * 16 + mi) * 128 + mt * 16 + quad * 4) = v4;
    }
  } else {
    u16* dh_ = sc16h + ((size_t)b << 19) + (h << 6);
    u16* dl_ = sc16l + ((size_t)b << 19) + (h << 6);
#pragma unroll
    for (int nt = 0; nt < 4; ++nt)
#pragma unroll
      for (int r = 0; r < 4; ++r) {
        int co = mt * 16 + quad * 4 + r;
        float xv = acc[nt][r];
        u16 hi = f2bf(xv);
        float lo = xv - bf2f(hi);
        size_t o = ((size_t)co << 12) + nt * 16 + mi;
        dh_[o] = hi;
        dl_[o] = f2bf(lo);
      }
  }
}

// ---------------- K3: fused q,k,v 1x1 convs via MFMA -------------------------
__global__ __launch_bounds__(256) void k_qkv(
    const u16* __restrict__ sa_nhwc, const u16* __restrict__ Wqkvb,
    const float* __restrict__ bq, const float* __restrict__ bk,
    const float* __restrict__ bv,
    float* __restrict__ qb, float* __restrict__ kbuf, u16* __restrict__ vt16) {
  __shared__ float bs[160];
  int t = threadIdx.x;
  int b = blockIdx.y, n0 = blockIdx.x * 128;
  if (t < 160) bs[t] = t < 16 ? bq[t] : (t < 32 ? bk[t - 16] : bv[t - 32]);
  __syncthreads();
  int lane = t & 63, wave = t >> 6;
  int mi = lane & 15, quad = lane >> 4;
  const u16* xb = sa_nhwc + ((size_t)b << 19) + (size_t)n0 * 128;
  const u16* wb = Wqkvb + lane * 8;
  f32x4 acc[2][10] = {};
  short8 bf[2][4];
#pragma unroll
  for (int ns = 0; ns < 2; ++ns) {
    int n = wave * 32 + ns * 16 + mi;
#pragma unroll
    for (int ks = 0; ks < 4; ++ks)
      bf[ns][ks] = *(const short8*)(xb + (size_t)n * 128 + ks * 32 + quad * 8);
  }
#pragma unroll
  for (int cot = 0; cot < 10; ++cot) {
    short8 a0 = *(const short8*)(wb + (size_t)(cot * 4 + 0) * 512);
    short8 a1 = *(const short8*)(wb + (size_t)(cot * 4 + 1) * 512);
    short8 a2 = *(const short8*)(wb + (size_t)(cot * 4 + 2) * 512);
    short8 a3 = *(const short8*)(wb + (size_t)(cot * 4 + 3) * 512);
#pragma unroll
    for (int ns = 0; ns < 2; ++ns) {
      acc[ns][cot] = __builtin_amdgcn_mfma_f32_16x16x32_bf16(a0, bf[ns][0], acc[ns][cot], 0, 0, 0);
      acc[ns][cot] = __builtin_amdgcn_mfma_f32_16x16x32_bf16(a1, bf[ns][1], acc[ns][cot], 0, 0, 0);
      acc[ns][cot] = __builtin_amdgcn_mfma_f32_16x16x32_bf16(a2, bf[ns][2], acc[ns][cot], 0, 0, 0);
      acc[ns][cot] = __builtin_amdgcn_mfma_f32_16x16x32_bf16(a3, bf[ns][3], acc[ns][cot], 0, 0, 0);
    }
  }
#pragma unroll
  for (int cot = 0; cot < 10; ++cot)
#pragma unroll
    for (int ns = 0; ns < 2; ++ns)
#pragma unroll
      for (int r = 0; r < 4; ++r) {
        int co = cot * 16 + quad * 4 + r;
        int n = n0 + wave * 32 + ns * 16 + mi;
        float v = acc[ns][cot][r] + bs[co];
        if (co < 16) qb[((b * 16 + co) << 12) + n] = v;
        else if (co < 32) kbuf[((b * 16 + co - 16) << 12) + n] = v;
        else vt16[((size_t)(b * 128 + co - 32) << 12) + n] = f2bf(v);
      }
}

// ---------------- K5: PAM PV with ONLINE softmax (no stats pass) -------------
// grid (128, 2, 2): block = 32 n x 2048 m. Per 256-m chunk: energy via
// split-bf16 MFMA -> block-wide per-n chunk max (quad shuffle + LDS) ->
// rescale acc/sums -> P = exp(e - m_run) (unnormalized) -> PV MFMA.
// Outputs: pvpart (unnormalized), pmax/psum per (mh,b,n); combined in k_bout_m.
__global__ __launch_bounds__(512, 4) void k_pam_pv(const float* __restrict__ qb,
    const float* __restrict__ kb, const u16* __restrict__ vt16,
    float* __restrict__ pvpart, float* __restrict__ pmax, float* __restrict__ psum) {
  constexpr int KSTR = 40;
  constexpr int PSTR = 264;
  __shared__ u16 kst[2][256 * KSTR];
  __shared__ u16 pL[32 * PSTR];
  __shared__ u16 qfh[32 * 16], qfl[32 * 16];
  __shared__ float wmx[8][2][16];
  __shared__ float wsm[8][2][16];
  int t = threadIdx.x;
  int b = blockIdx.y, n0 = blockIdx.x * 32;
  int mbeg = blockIdx.z << 11;
  int lane = t & 63, wave = t >> 6;
  int mi = lane & 15, quad = lane >> 4;
  int c0 = wave * 16;
  {
    int ch = t & 15, nl = t >> 4;
    float qv = qb[((size_t)(b * 16 + ch) << 12) + n0 + nl];
    u16 hi = f2bf(qv);
    qfh[nl * 16 + ch] = hi;
    qfl[nl * 16 + ch] = f2bf(qv - bf2f(hi));
  }
  const float* kpb = kb + ((size_t)b * 16 << 12) + mbeg;
  const u16* vb = vt16 + ((size_t)b * 128 << 12);
  f32x4 acc[2] = {};
  float mr0 = -1e30f, mr1 = -1e30f, ssum0 = 0.f, ssum1 = 0.f;
  int sm = t & 255, shalf = t >> 8;
  {
    short8 hi8, lo8;
#pragma unroll
    for (int j = 0; j < 8; ++j) {
      float v = kpb[((size_t)(shalf * 8 + j) << 12) + sm];
      u16 hi = f2bf(v);
      hi8[j] = (short)hi;
      lo8[j] = (short)f2bf(v - bf2f(hi));
    }
    *(short8*)(kst[0] + sm * KSTR + shalf * 8) = hi8;
    *(short8*)(kst[0] + sm * KSTR + 16 + shalf * 8) = lo8;
  }
  __syncthreads();
  int qoff = (quad & 1) * 8;
  short8 bq1[2], bq2[2];
  bq1[0] = *(const short8*)(qfh + mi * 16 + qoff);
  bq1[1] = *(const short8*)(qfh + (16 + mi) * 16 + qoff);
  bq2[0] = *(const short8*)(qfl + mi * 16 + qoff);
  bq2[1] = *(const short8*)(qfl + (16 + mi) * 16 + qoff);
  int cur = 0;
  for (int it = 0; it < 8; ++it) {
    int m0 = mbeg + (it << 8);
    short8 vreg[8];
#pragma unroll
    for (int ksl = 0; ksl < 8; ++ksl)
      vreg[ksl] = *(const short8*)(vb + ((size_t)(c0 + mi) << 12) + m0 + ksl * 32 + quad * 8);
    float kreg[8];
    if (it < 7) {
#pragma unroll
      for (int j = 0; j < 8; ++j)
        kreg[j] = kpb[((size_t)(shalf * 8 + j) << 12) + ((it + 1) << 8) + sm];
    }
    // energy MFMA
    const u16* ka = kst[cur] + (wave * 32) * KSTR;
    short8 a0 = *(const short8*)(ka + mi * KSTR + quad * 8);
    short8 a1 = *(const short8*)(ka + (16 + mi) * KSTR + quad * 8);
    f32x4 e00 = {}, e01 = {}, e10 = {}, e11 = {};
    e00 = __builtin_amdgcn_mfma_f32_16x16x32_bf16(a0, bq1[0], e00, 0, 0, 0);
    e00 = __builtin_amdgcn_mfma_f32_16x16x32_bf16(a0, bq2[0], e00, 0, 0, 0);
    e01 = __builtin_amdgcn_mfma_f32_16x16x32_bf16(a0, bq1[1], e01, 0, 0, 0);
    e01 = __builtin_amdgcn_mfma_f32_16x16x32_bf16(a0, bq2[1], e01, 0, 0, 0);
    e10 = __builtin_amdgcn_mfma_f32_16x16x32_bf16(a1, bq1[0], e10, 0, 0, 0);
    e10 = __builtin_amdgcn_mfma_f32_16x16x32_bf16(a1, bq2[0], e10, 0, 0, 0);
    e11 = __builtin_amdgcn_mfma_f32_16x16x32_bf16(a1, bq1[1], e11, 0, 0, 0);
    e11 = __builtin_amdgcn_mfma_f32_16x16x32_bf16(a1, bq2[1], e11, 0, 0, 0);
    // per-wave per-n max (over this wave's 32 m)
    float lm0 = fmaxf(fmaxf(fmaxf(e00[0], e00[1]), fmaxf(e00[2], e00[3])),
                      fmaxf(fmaxf(e10[0], e10[1]), fmaxf(e10[2], e10[3])));
    float lm1 = fmaxf(fmaxf(fmaxf(e01[0], e01[1]), fmaxf(e01[2], e01[3])),
                      fmaxf(fmaxf(e11[0], e11[1]), fmaxf(e11[2], e11[3])));
    lm0 = fmaxf(lm0, __shfl_xor(lm0, 16)); lm0 = fmaxf(lm0, __shfl_xor(lm0, 32));
    lm1 = fmaxf(lm1, __shfl_xor(lm1, 16)); lm1 = fmaxf(lm1, __shfl_xor(lm1, 32));
    if (quad == 0) { wmx[wave][0][mi] = lm0; wmx[wave][1][mi] = lm1; }
    __syncthreads();   // B1: wmx ready; kst[cur] energy reads done
    // stage next K (overlaps softmax VALU)
    if (it < 7) {
      short8 hi8, lo8;
#pragma unroll
      for (int j = 0; j < 8; ++j) {
        u16 hi = f2bf(kreg[j]);
        hi8[j] = (short)hi;
        lo8[j] = (short)f2bf(kreg[j] - bf2f(hi));
      }
      *(short8*)(kst[cur ^ 1] + sm * KSTR + shalf * 8) = hi8;
      *(short8*)(kst[cur ^ 1] + sm * KSTR + 16 + shalf * 8) = lo8;
    }
    // block-wide chunk max, online update
    float cm0 = wmx[0][0][mi], cm1 = wmx[0][1][mi];
#pragma unroll
    for (int w = 1; w < 8; ++w) {
      cm0 = fmaxf(cm0, wmx[w][0][mi]);
      cm1 = fmaxf(cm1, wmx[w][1][mi]);
    }
    float mn0 = fmaxf(mr0, cm0), mn1 = fmaxf(mr1, cm1);
    float rs0 = __expf(mr0 - mn0), rs1 = __expf(mr1 - mn1);
#pragma unroll
    for (int r = 0; r < 4; ++r) { acc[0][r] *= rs0; acc[1][r] *= rs1; }
    float p00[4], p10[4], p01[4], p11[4];
    float ls0 = 0.f, ls1 = 0.f;
#pragma unroll
    for (int j = 0; j < 4; ++j) {
      p00[j] = __expf(e00[j] - mn0); p10[j] = __expf(e10[j] - mn0);
      p01[j] = __expf(e01[j] - mn1); p11[j] = __expf(e11[j] - mn1);
      ls0 += p00[j] + p10[j];
      ls1 += p01[j] + p11[j];
    }
    ssum0 = ssum0 * rs0 + ls0;
    ssum1 = ssum1 * rs1 + ls1;
    mr0 = mn0; mr1 = mn1;
    u16* prow0 = pL + mi * PSTR + wave * 32 + quad * 4;
    u16* prow1 = pL + (16 + mi) * PSTR + wave * 32 + quad * 4;
    U16x4 p;
    p.x = f2bf(p00[0]); p.y = f2bf(p00[1]); p.z = f2bf(p00[2]); p.w = f2bf(p00[3]);
    *(U16x4*)(prow0) = p;
    p.x = f2bf(p10[0]); p.y = f2bf(p10[1]); p.z = f2bf(p10[2]); p.w = f2bf(p10[3]);
    *(U16x4*)(prow0 + 16) = p;
    p.x = f2bf(p01[0]); p.y = f2bf(p01[1]); p.z = f2bf(p01[2]); p.w = f2bf(p01[3]);
    *(U16x4*)(prow1) = p;
    p.x = f2bf(p11[0]); p.y = f2bf(p11[1]); p.z = f2bf(p11[2]); p.w = f2bf(p11[3]);
    *(U16x4*)(prow1 + 16) = p;
    __syncthreads();   // B2: pL ready; kst[cur^1] writes done
    // PV MFMA
#pragma unroll
    for (int ksl = 0; ksl < 8; ++ksl) {
      const u16* pb0 = pL + mi * PSTR + ksl * 32 + quad * 8;
      short8 b0 = *(const short8*)(pb0);
      short8 b1 = *(const short8*)(pb0 + 16 * PSTR);
      acc[0] = __builtin_amdgcn_mfma_f32_16x16x32_bf16(vreg[ksl], b0, acc[0], 0, 0, 0);
      acc[1] = __builtin_amdgcn_mfma_f32_16x16x32_bf16(vreg[ksl], b1, acc[1], 0, 0, 0);
    }
    cur ^= 1;
  }
  // final per-n sum reduce (quad shuffle + cross-wave LDS)
  ssum0 += __shfl_xor(ssum0, 16); ssum0 += __shfl_xor(ssum0, 32);
  ssum1 += __shfl_xor(ssum1, 16); ssum1 += __shfl_xor(ssum1, 32);
  if (quad == 0) { wsm[wave][0][mi] = ssum0; wsm[wave][1][mi] = ssum1; }
  __syncthreads();
  if (t < 16) {
    float sA = 0.f, sB = 0.f;
#pragma unroll
    for (int w = 0; w < 8; ++w) { sA += wsm[w][0][t]; sB += wsm[w][1][t]; }
    size_t base = ((size_t)(blockIdx.z * 2 + b) << 12) + n0;
    psum[base + t] = sA;
    psum[base + 16 + t] = sB;
    pmax[base + t] = mr0;
    pmax[base + 16 + t] = mr1;
  }
  float* dst = pvpart + (((size_t)(blockIdx.z * 2 + b) * 128) << 12);
#pragma unroll
  for (int nh = 0; nh < 2; ++nh)
#pragma unroll
    for (int r = 0; r < 4; ++r) {
      int c = c0 + quad * 4 + r;
      dst[((size_t)c << 12) + n0 + nh * 16 + mi] = acc[nh][r];
    }
}

// ---------------- K6a: CAM Gram energy via MFMA, split-bf16 ------------------
__global__ __launch_bounds__(512) void k_cam_energy_m(
    const u16* __restrict__ sc16h, const u16* __restrict__ sc16l,
    float* __restrict__ epart) {
  int t = threadIdx.x;
  int ti = blockIdx.x, kc = blockIdx.y, b = blockIdx.z;
  int lane = t & 63, wave = t >> 6;
  int mi = lane & 15, quad = lane >> 4;
  const u16* fh = sc16h + ((size_t)b << 19);
  const u16* fl = sc16l + ((size_t)b << 19);
  size_t ao = ((size_t)(ti * 16 + mi) << 12) + (kc << 9) + quad * 8;
  size_t bo = ((size_t)(wave * 16 + mi) << 12) + (kc << 9) + quad * 8;
  const u16* ah = fh + ao; const u16* al = fl + ao;
  const u16* bh = fh + bo; const u16* bl = fl + bo;
  f32x4 acc = {};
#pragma unroll
  for (int k = 0; k < 16; ++k) {
    short8 vah = *(const short8*)(ah + k * 32);
    short8 val = *(const short8*)(al + k * 32);
    short8 vbh = *(const short8*)(bh + k * 32);
    short8 vbl = *(const short8*)(bl + k * 32);
    acc = __builtin_amdgcn_mfma_f32_16x16x32_bf16(vah, vbh, acc, 0, 0, 0);
    acc = __builtin_amdgcn_mfma_f32_16x16x32_bf16(vah, vbl, acc, 0, 0, 0);
    acc = __builtin_amdgcn_mfma_f32_16x16x32_bf16(val, vbh, acc, 0, 0, 0);
  }
  float* ep = epart + (((size_t)(kc * 2 + b)) << 14);
#pragma unroll
  for (int r = 0; r < 4; ++r)
    ep[((ti * 16 + quad * 4 + r) << 7) + wave * 16 + mi] = acc[r];
}

// ---------------- K6b: CAM softmax row (reduce 8 partials) -------------------
__global__ void k_cam_softmax(const float* __restrict__ epart, float* __restrict__ attn) {
  int lane = threadIdx.x;
  int c = blockIdx.x, b = blockIdx.y;
  float e0 = 0.f, e1 = 0.f;
#pragma unroll
  for (int kc = 0; kc < 8; ++kc) {
    const float* ep = epart + (((size_t)(kc * 2 + b)) << 14) + (c << 7);
    e0 += ep[lane];
    e1 += ep[lane + 64];
  }
  float mn = fminf(e0, e1);
#pragma unroll
  for (int off = 32; off >= 1; off >>= 1) mn = fminf(mn, __shfl_xor(mn, off));
  float p0 = __expf(fminf(mn - e0, 0.f)), p1 = __expf(fminf(mn - e1, 0.f));
  float s = p0 + p1;
#pragma unroll
  for (int off = 32; off >= 1; off >>= 1) s += __shfl_xor(s, off);
  float inv = 1.f / s;
  float* a = attn + ((b * 128 + c) << 7);
  a[lane] = p0 * inv;
  a[lane + 64] = p1 * inv;
}

// ---------------- K7: CAM out + residual -------------------------------------
__global__ __launch_bounds__(256) void k_cam_out(const float* __restrict__ f,
    const float* __restrict__ attn, const float* __restrict__ gamma,
    float* __restrict__ sc1) {
  __shared__ float at2[128 * 16];
  int t = threadIdx.x;
  int b = blockIdx.z, c0 = blockIdx.y * 16;
  int n = blockIdx.x * 256 + t;
  for (int idx = t; idx < 2048; idx += 256) {
    int d = idx >> 4, cc = idx & 15;
    at2[idx] = attn[((b * 128 + c0 + cc) << 7) + d];
  }
  __syncthreads();
  float acc[16] = {};
  const float* fb = f + ((size_t)b * 128 << 12) + n;
  for (int d = 0; d < 128; ++d) {
    float fv = fb[d << 12];
    const float* ap = at2 + d * 16;
#pragma unroll
    for (int cc = 0; cc < 16; ++cc) acc[cc] = fmaf(ap[cc], fv, acc[cc]);
  }
  float g = gamma[0];
#pragma unroll
  for (int cc = 0; cc < 16; ++cc) {
    size_t o = ((size_t)(b * 128 + c0 + cc) << 12) + n;
    sc1[o] = fmaf(g, acc[cc], f[o]);
  }
}

// ---------------- K8: BN+ReLU + 1x1 conv 128->512 via MFMA -------------------
// sa input = sa0 + k0*pv0 + k1*pv1 (online-softmax combine, gamma folded in).
__global__ __launch_bounds__(256, 2) void k_bout_m(
    const float* __restrict__ sa0, const float* __restrict__ pvpart,
    const float* __restrict__ pmax, const float* __restrict__ psum,
    const float* __restrict__ gamma,
    const float* __restrict__ sc1,
    const float* __restrict__ wa_, const float* __restrict__ ba_,
    const float* __restrict__ ma_, const float* __restrict__ va_,
    const float* __restrict__ wc_, const float* __restrict__ bc_,
    const float* __restrict__ mc_, const float* __restrict__ vc_,
    const u16* __restrict__ W1b, const float* __restrict__ Ba,
    const float* __restrict__ Bc,
    u16* __restrict__ sa2, u16* __restrict__ sc2) {
  __shared__ u16 xl[32 * 136];
  __shared__ float scl[128], shf[128];
  int t = threadIdx.x;
  int n0 = blockIdx.x * 32;
  int b = blockIdx.y, br = blockIdx.z;
  const float* bw = br ? wc_ : wa_;
  const float* bb = br ? bc_ : ba_;
  const float* bm = br ? mc_ : ma_;
  const float* bvv = br ? vc_ : va_;
  if (t < 128) {
    float s = bw[t] * rsqrtf(bvv[t] + 1e-5f);
    scl[t] = s;
    shf[t] = bb[t] - bm[t] * s;
  }
  __syncthreads();
  {
    int nl = t & 31, cio = t >> 5;
    const float* s0 = (br ? sc1 : sa0) + ((size_t)b * 128 << 12) + n0 + nl;
    const float* p0 = pvpart + ((size_t)b * 128 << 12) + n0 + nl;
    const float* p1 = pvpart + (((size_t)(2 + b) * 128) << 12) + n0 + nl;
    float k0 = 0.f, k1 = 0.f;
    if (!br) {
      int n = n0 + nl;
      float m0 = pmax[((size_t)b << 12) + n];
      float m1 = pmax[((size_t)(2 + b) << 12) + n];
      float sA = psum[((size_t)b << 12) + n];
      float sB = psum[((size_t)(2 + b) << 12) + n];
      float M = fmaxf(m0, m1);
      float w0 = __expf(m0 - M), w1 = __expf(m1 - M);
      float inv = gamma[0] / (w0 * sA + w1 * sB);
      k0 = w0 * inv; k1 = w1 * inv;
    }
#pragma unroll
    for (int half = 0; half < 2; ++half) {
      short8 v;
#pragma unroll
      for (int i = 0; i < 8; ++i) {
        int ci = cio * 16 + half * 8 + i;
        float xv = s0[(size_t)ci << 12];
        if (!br) xv += k0 * p0[(size_t)ci << 12] + k1 * p1[(size_t)ci << 12];
        v[i] = (short)f2bf(fmaxf(fmaf(xv, scl[ci], shf[ci]), 0.f));
      }
      *(short8*)(xl + nl * 136 + cio * 16 + half * 8) = v;
    }
  }
  __syncthreads();
  int lane = t & 63, wave = t >> 6;
  int mi = lane & 15, quad = lane >> 4;
  const u16* wb = W1b + (size_t)br * 65536 + lane * 8;
  f32x4 acc[8][2] = {};
#pragma unroll
  for (int ks = 0; ks < 4; ++ks) {
    short8 b0 = *(const short8*)(xl + mi * 136 + ks * 32 + quad * 8);
    short8 b1 = *(const short8*)(xl + (16 + mi) * 136 + ks * 32 + quad * 8);
#pragma unroll
    for (int ct = 0; ct < 8; ++ct) {
      int cot = wave * 8 + ct;
      short8 a = *(const short8*)(wb + ((size_t)(cot * 4 + ks) << 9));
      acc[ct][0] = __builtin_amdgcn_mfma_f32_16x16x32_bf16(a, b0, acc[ct][0], 0, 0, 0);
      acc[ct][1] = __builtin_amdgcn_mfma_f32_16x16x32_bf16(a, b1, acc[ct][1], 0, 0, 0);
    }
  }
  const float* Bs = br ? Bc : Ba;
  u16* dst = br ? sc2 : sa2;
#pragma unroll
  for (int ct = 0; ct < 8; ++ct)
#pragma unroll
    for (int nh = 0; nh < 2; ++nh)
#pragma unroll
      for (int r = 0; r < 4; ++r) {
        int co = (wave * 8 + ct) * 16 + quad * 4 + r;
        dst[((size_t)(b * 512 + co) << 12) + n0 + nh * 16 + mi] =
            f2bf(acc[ct][nh][r] + Bs[co]);
      }
}

// ---------------- K9: fusion + class heads, atomic-free, fused bias ----------
// grid (128, 2), 256 thr. Block = 32 n x ALL 512 co: complete head sums via
// per-thread 64-co partials + LDS tree reduce. Replaces k_heads + k_heads_final
// + clsacc memset.
__global__ __launch_bounds__(256) void k_heads2(const u16* __restrict__ sa2,
    const u16* __restrict__ sc2,
    const float* __restrict__ wf, const float* __restrict__ wa, const float* __restrict__ wc,
    const float* __restrict__ bfb, const float* __restrict__ bab,
    const float* __restrict__ bcb,
    float* __restrict__ outFusion, float* __restrict__ outCls) {
  __shared__ float lw[3 * 5 * 512];
  __shared__ float hs[8][15][32];
  int t = threadIdx.x;
  int b = blockIdx.y, n0 = blockIdx.x * 32;
  for (int idx = t; idx < 7680; idx += 256) {
    int arr = idx / 2560, rest = idx - arr * 2560;
    int cls = rest >> 9, co = rest & 511;
    const float* w = arr == 0 ? wf : (arr == 1 ? wa : wc);
    lw[idx] = w[cls * 512 + co];
  }
  __syncthreads();
  int nl = t & 31, ck = t >> 5;
  float acc[15] = {};
  for (int co = ck * 64; co < ck * 64 + 64; ++co) {
    size_t o = ((size_t)(b * 512 + co) << 12) + n0 + nl;
    float a = bf2f(sa2[o]), c = bf2f(sc2[o]);
    float s = a + c;
    outFusion[o] = s;
    const float* lf = lw + co;
#pragma unroll
    for (int cls = 0; cls < 5; ++cls) {
      acc[cls]      = fmaf(lf[cls * 512], s, acc[cls]);
      acc[5 + cls]  = fmaf(lf[2560 + cls * 512], a, acc[5 + cls]);
      acc[10 + cls] = fmaf(lf[5120 + cls * 512], c, acc[10 + cls]);
    }
  }
#pragma unroll
  for (int k = 0; k < 15; ++k) hs[ck][k][nl] = acc[k];
  __syncthreads();
  for (int idx = t; idx < 480; idx += 256) {
    int k = idx >> 5, nl2 = idx & 31;
    float s = 0.f;
#pragma unroll
    for (int c8 = 0; c8 < 8; ++c8) s += hs[c8][k][nl2];
    int arr = k / 5, cls = k - arr * 5;
    float bias = arr == 0 ? bfb[cls] : (arr == 1 ? bab[cls] : bcb[cls]);
    outCls[arr * 40960 + ((b * 5 + cls) << 12) + n0 + nl2] = s + bias;
  }
}

extern "C" void kernel_launch(void* const* d_in, const int* in_sizes, int n_in,
                              void* d_out, int out_size, void* d_ws, size_t ws_size,
                              hipStream_t stream) {
  (void)in_sizes; (void)n_in; (void)out_size; (void)ws_size;
  const float* x      = (const float*)d_in[0];
  const float* bnaw   = (const float*)d_in[1];
  const float* bnab   = (const float*)d_in[2];
  const float* bnam   = (const float*)d_in[3];
  const float* bnav   = (const float*)d_in[4];
  const float* convaw = (const float*)d_in[5];
  const float* bncw   = (const float*)d_in[6];
  const float* bncb   = (const float*)d_in[7];
  const float* bncm   = (const float*)d_in[8];
  const float* bncv   = (const float*)d_in[9];
  const float* convcw = (const float*)d_in[10];
  const float* pqw    = (const float*)d_in[11];
  const float* pqb    = (const float*)d_in[12];
  const float* pkw    = (const float*)d_in[13];
  const float* pkb    = (const float*)d_in[14];
  const float* pvw    = (const float*)d_in[15];
  const float* pvb    = (const float*)d_in[16];
  const float* pgam   = (const float*)d_in[17];
  const float* cgam   = (const float*)d_in[18];
  const float* bna1w  = (const float*)d_in[19];
  const float* bna1b  = (const float*)d_in[20];
  const float* bna1m  = (const float*)d_in[21];
  const float* bna1v  = (const float*)d_in[22];
  const float* conva1w = (const float*)d_in[23];
  const float* conva1b = (const float*)d_in[24];
  const float* bnc1w  = (const float*)d_in[25];
  const float* bnc1b  = (const float*)d_in[26];
  const float* bnc1m  = (const float*)d_in[27];
  const float* bnc1v  = (const float*)d_in[28];
  const float* convc1w = (const float*)d_in[29];
  const float* convc1b = (const float*)d_in[30];
  const float* outaw  = (const float*)d_in[31];
  const float* outab  = (const float*)d_in[32];
  const float* outcw  = (const float*)d_in[33];
  const float* outcb  = (const float*)d_in[34];
  const float* outfw  = (const float*)d_in[35];
  const float* outfb  = (const float*)d_in[36];

  char* wsb = (char*)d_ws;
  size_t off = 0;
  auto take = [&](size_t bytes) -> void* {
    void* p = wsb + off;
    off += (bytes + 255) & ~(size_t)255;
    return p;
  };
  u16*   Wb    = (u16*)take((size_t)2 * 128 * 9 * 512 * 2);
  u16*   W1b   = (u16*)take((size_t)2 * 512 * 128 * 2);
  u16*   Wqkvb = (u16*)take((size_t)160 * 128 * 2);
  u16*   xa16  = (u16*)take((size_t)2 * 512 * 4096 * 2);
  u16*   xcb16 = (u16*)take((size_t)2 * 512 * 4096 * 2);
  float* sa0   = (float*)take((size_t)2 * 128 * 4096 * 4);
  float* sc0   = (float*)take((size_t)2 * 128 * 4096 * 4);
  u16*   sa_nhwc = (u16*)take((size_t)2 * 4096 * 128 * 2);
  u16*   sc16h = (u16*)take((size_t)2 * 128 * 4096 * 2);
  u16*   sc16l = (u16*)take((size_t)2 * 128 * 4096 * 2);
  float* qb    = (float*)take((size_t)2 * 16 * 4096 * 4);
  float* kbuf  = (float*)take((size_t)2 * 16 * 4096 * 4);
  u16*   vt16  = (u16*)take((size_t)2 * 128 * 4096 * 2);
  float* pvpart = (float*)take((size_t)2 * 2 * 128 * 4096 * 4);
  float* pmax  = (float*)take((size_t)2 * 2 * 4096 * 4);
  float* psum  = (float*)take((size_t)2 * 2 * 4096 * 4);
  float* sc1   = (float*)take((size_t)2 * 128 * 4096 * 4);
  float* epart = (float*)take((size_t)8 * 2 * 128 * 128 * 4);
  float* attn  = (float*)take((size_t)2 * 128 * 128 * 4);
  u16*   sa2   = (u16*)take((size_t)2 * 512 * 4096 * 2);
  u16*   sc2   = (u16*)take((size_t)2 * 512 * 4096 * 2);

  float* outF = (float*)d_out;
  float* outCls = outF + (size_t)2 * 512 * 4096;

  k_prep_w<<<4608, 256, 0, stream>>>(convaw, convcw, Wb);
  k_prep_w1<<<512, 256, 0, stream>>>(conva1w, convc1w, W1b);
  k_prep_wqkv<<<80, 256, 0, stream>>>(pqw, pkw, pvw, Wqkvb);
  k_bnrelu2t<<<dim3(64, 2), 256, 0, stream>>>(x, bnaw, bnab, bnam, bnav,
                                              bncw, bncb, bncm, bncv, xa16, xcb16);
  k_conv3n<<<dim3(64, 4, 2), 256, 0, stream>>>(xa16, xcb16, Wb, sa0, sc0,
                                               sa_nhwc, sc16h, sc16l);
  k_qkv<<<dim3(32, 2), 256, 0, stream>>>(sa_nhwc, Wqkvb, pqb, pkb, pvb,
                                         qb, kbuf, vt16);
  k_pam_pv<<<dim3(128, 2, 2), 512, 0, stream>>>(qb, kbuf, vt16, pvpart, pmax, psum);
  k_cam_energy_m<<<dim3(8, 8, 2), 512, 0, stream>>>(sc16h, sc16l, epart);
  k_cam_softmax<<<dim3(128, 2), 64, 0, stream>>>(epart, attn);
  k_cam_out<<<dim3(16, 8, 2), 256, 0, stream>>>(sc0, attn, cgam, sc1);
  k_bout_m<<<dim3(128, 2, 2), 256, 0, stream>>>(sa0, pvpart, pmax, psum, pgam, sc1,
      bna1w, bna1b, bna1m, bna1v, bnc1w, bnc1b, bnc1m, bnc1v,
      W1b, conva1b, convc1b, sa2, sc2);
  k_heads2<<<dim3(128, 2), 256, 0, stream>>>(sa2, sc2, outfw, outaw, outcw,
                                             outfb, outab, outcb, outF, outCls);
}

// Round 10
// 308.125 us; speedup vs baseline: 1.8671x; 1.0135x over previous
//
#include <hip/hip_runtime.h>

using u16 = unsigned short;
using short8 = __attribute__((ext_vector_type(8))) short;
using f32x4 = __attribute__((ext_vector_type(4))) float;

struct alignas(8) U16x4 { u16 x, y, z, w; };

__device__ __forceinline__ float bf2f(u16 u) {
  return __uint_as_float(((unsigned int)u) << 16);
}
__device__ __forceinline__ u16 f2bf(float f) {
  unsigned int u = __float_as_uint(f);
  unsigned int r = u + 0x7FFFu + ((u >> 16) & 1u);
  return (u16)(r >> 16);
}

// ---------------- K0b: conv weights -> bf16, MFMA-fragment order -------------
// Layout: [br][mt(8)][chunk(4)][tap(9)][ks(4)][lane(64)][j(8)]
__global__ void k_prep_w(const float* __restrict__ wa, const float* __restrict__ wc,
                         u16* __restrict__ Wb) {
  int idx = blockIdx.x * 256 + threadIdx.x;   // 1179648
  int j = idx & 7;
  int l = (idx >> 3) & 63;
  int ks = (idx >> 9) & 3;
  int rest = idx >> 11;
  int tap = rest % 9;
  int rest2 = rest / 9;
  int chunk = rest2 & 3;
  int mt = (rest2 >> 2) & 7;
  int br = rest2 >> 5;
  int co = mt * 16 + (l & 15);
  int ci = chunk * 128 + ks * 32 + (l >> 4) * 8 + j;
  const float* w = br ? wc : wa;
  Wb[idx] = f2bf(w[co * 4608 + ci * 9 + tap]);
}

// ---------------- K0c: 1x1 out-conv weights (128->512) -> bf16 A-frag order --
__global__ void k_prep_w1(const float* __restrict__ wa, const float* __restrict__ wc,
                          u16* __restrict__ W1b) {
  int idx = blockIdx.x * 256 + threadIdx.x;   // 131072
  int j = idx & 7;
  int l = (idx >> 3) & 63;
  int ks = (idx >> 9) & 3;
  int cot = (idx >> 11) & 31;
  int br = idx >> 16;
  int co = cot * 16 + (l & 15);
  int ci = ks * 32 + (l >> 4) * 8 + j;
  const float* w = br ? wc : wa;
  W1b[idx] = f2bf(w[co * 128 + ci]);
}

// ---------------- K0d: qkv weights (160x128) -> bf16 A-frag order ------------
__global__ void k_prep_wqkv(const float* __restrict__ wq, const float* __restrict__ wk,
                            const float* __restrict__ wv, u16* __restrict__ Wq) {
  int idx = blockIdx.x * 256 + threadIdx.x;   // 20480
  if (idx >= 20480) return;
  int j = idx & 7;
  int l = (idx >> 3) & 63;
  int ks = (idx >> 9) & 3;
  int cot = idx >> 11;
  int co = cot * 16 + (l & 15);
  int ci = ks * 32 + (l >> 4) * 8 + j;
  float w = co < 16 ? wq[co * 128 + ci]
          : (co < 32 ? wk[(co - 16) * 128 + ci] : wv[(co - 32) * 128 + ci]);
  Wq[idx] = f2bf(w);
}

// ---------------- K1: BN+ReLU both branches, NHWC bf16 out -------------------
__global__ __launch_bounds__(256) void k_bnrelu2t(const float* __restrict__ x,
    const float* __restrict__ wa, const float* __restrict__ ba,
    const float* __restrict__ ma, const float* __restrict__ va,
    const float* __restrict__ wc, const float* __restrict__ bc,
    const float* __restrict__ mc, const float* __restrict__ vc,
    u16* __restrict__ xa16, u16* __restrict__ xcb16) {
  __shared__ float sA[512], bA[512], sC[512], bC[512];
  __shared__ u16 ta[64 * 136], tc[64 * 136];
  int t = threadIdx.x;
  int h = blockIdx.x, b = blockIdx.y;
  for (int c = t; c < 512; c += 256) {
    float s1 = wa[c] * rsqrtf(va[c] + 1e-5f);
    sA[c] = s1; bA[c] = ba[c] - ma[c] * s1;
    float s2 = wc[c] * rsqrtf(vc[c] + 1e-5f);
    sC[c] = s2; bC[c] = bc[c] - mc[c] * s2;
  }
  __syncthreads();
  const float* xb = x + ((size_t)b << 21) + (h << 6);
  u16* oa = xa16 + ((size_t)b << 21) + ((size_t)h << 15);
  u16* oc = xcb16 + ((size_t)b << 21) + ((size_t)h << 15);
  int w = t & 63, cg = t >> 6;
  for (int c0 = 0; c0 < 512; c0 += 128) {
#pragma unroll
    for (int i = 0; i < 8; ++i) {
      int cl = cg * 4 + i * 16;
      int c = c0 + cl;
      const float* xp = xb + (size_t)c * 4096 + w;
      float v0 = xp[0], v1 = xp[4096], v2 = xp[8192], v3 = xp[12288];
      U16x4 pa, pc;
      pa.x = f2bf(fmaxf(fmaf(v0, sA[c], bA[c]), 0.f));
      pa.y = f2bf(fmaxf(fmaf(v1, sA[c + 1], bA[c + 1]), 0.f));
      pa.z = f2bf(fmaxf(fmaf(v2, sA[c + 2], bA[c + 2]), 0.f));
      pa.w = f2bf(fmaxf(fmaf(v3, sA[c + 3], bA[c + 3]), 0.f));
      pc.x = f2bf(fmaxf(fmaf(v0, sC[c], bC[c]), 0.f));
      pc.y = f2bf(fmaxf(fmaf(v1, sC[c + 1], bC[c + 1]), 0.f));
      pc.z = f2bf(fmaxf(fmaf(v2, sC[c + 2], bC[c + 2]), 0.f));
      pc.w = f2bf(fmaxf(fmaf(v3, sC[c + 3], bC[c + 3]), 0.f));
      *(U16x4*)(ta + w * 136 + cl) = pa;
      *(U16x4*)(tc + w * 136 + cl) = pc;
    }
    __syncthreads();
#pragma unroll
    for (int i = 0; i < 4; ++i) {
      int idx = t + i * 256;
      int ww = idx >> 4, c8 = (idx & 15) << 3;
      *(short8*)(oa + (size_t)ww * 512 + c0 + c8) = *(const short8*)(ta + ww * 136 + c8);
      *(short8*)(oc + (size_t)ww * 512 + c0 + c8) = *(const short8*)(tc + ww * 136 + c8);
    }
    __syncthreads();
  }
}

// ---------------- K2: 3x3 conv, implicit GEMM, NHWC input --------------------
__global__ __launch_bounds__(256, 2) void k_conv3n(
    const u16* __restrict__ xa16, const u16* __restrict__ xcb16,
    const u16* __restrict__ Wb,
    float* __restrict__ sa0, float* __restrict__ sc0,
    u16* __restrict__ sa_nhwc, u16* __restrict__ sc16h, u16* __restrict__ sc16l) {
  __shared__ u16 xs[3 * 66 * 136];
  int t = threadIdx.x;
  int h = blockIdx.x;
  int z = blockIdx.y; int b = z & 1, br = z >> 1;
  int cosplit = blockIdx.z;
  const u16* xb = (br ? xcb16 : xa16) + ((size_t)b << 21);
  const u16* wb = Wb + (size_t)br * 589824;
  float* out = (br ? sc0 : sa0) + (((size_t)b * 128) << 12) + (h << 6);

  int lane = t & 63, wave = t >> 6;
  int mi = lane & 15, quad = lane >> 4;
  int mt = cosplit * 4 + wave;

  if (t < 96) {
    int dh = t >> 5, side = (t >> 4) & 1, c8 = t & 15;
    short8 z8 = {0, 0, 0, 0, 0, 0, 0, 0};
    *(short8*)(xs + (dh * 66 + side * 65) * 136 + c8 * 8) = z8;
  }

  f32x4 acc[4] = {};

  const u16* wlane = wb + lane * 8;
  const u16* bbase0 = xs + mi * 136 + quad * 8;

  for (int chunk = 0; chunk < 4; ++chunk) {
    int ci0 = chunk << 7;
    __syncthreads();
#pragma unroll
    for (int dh = 0; dh < 3; ++dh) {
      int hh = h + dh - 1;
      bool val = (hh >= 0) && (hh < 64);
      const u16* src = xb + (((size_t)hh << 6) << 9) + ci0;
#pragma unroll
      for (int i = 0; i < 4; ++i) {
        int idx = t + i * 256;
        int w = idx >> 4, c8 = (idx & 15) << 3;
        short8 v = {0, 0, 0, 0, 0, 0, 0, 0};
        if (val) v = *(const short8*)(src + ((size_t)w << 9) + c8);
        *(short8*)(xs + (dh * 66 + 1 + w) * 136 + c8) = v;
      }
    }
    __syncthreads();
    const u16* wchunk = wlane + (size_t)(mt * 4 + chunk) * 18432;
    short8 wreg[2][4];
#pragma unroll
    for (int ks = 0; ks < 4; ++ks)
      wreg[0][ks] = *(const short8*)(wchunk + ks * 512);
#pragma unroll
    for (int tap = 0; tap < 9; ++tap) {
      const int cb = tap & 1;
      if (tap < 8) {
        const u16* wn = wchunk + (tap + 1) * 2048;
#pragma unroll
        for (int ks = 0; ks < 4; ++ks)
          wreg[cb ^ 1][ks] = *(const short8*)(wn + ks * 512);
      }
      const int dh = tap / 3, dw = tap % 3;
      const u16* bp = bbase0 + (dh * 66 + dw) * 136;
#pragma unroll
      for (int ks = 0; ks < 4; ++ks) {
        short8 a = wreg[cb][ks];
#pragma unroll
        for (int nt = 0; nt < 4; ++nt) {
          short8 bf = *(const short8*)(bp + nt * 2176 + ks * 32);
          acc[nt] = __builtin_amdgcn_mfma_f32_16x16x32_bf16(a, bf, acc[nt], 0, 0, 0);
        }
      }
    }
  }
#pragma unroll
  for (int nt = 0; nt < 4; ++nt)
#pragma unroll
    for (int r = 0; r < 4; ++r) {
      int co = mt * 16 + quad * 4 + r;
      out[((size_t)co << 12) + nt * 16 + mi] = acc[nt][r];
    }
  if (br == 0) {
    u16* dstq = sa_nhwc + ((size_t)b << 19) + ((size_t)h << 6) * 128;
#pragma unroll
    for (int nt = 0; nt < 4; ++nt) {
      U16x4 v4;
      v4.x = f2bf(acc[nt][0]); v4.y = f2bf(acc[nt][1]);
      v4.z = f2bf(acc[nt][2]); v4.w = f2bf(acc[nt][3]);
      *(U16x4*)(dstq + (size_t)(nt * 16 + mi) * 128 + mt * 16 + quad * 4) = v4;
    }
  } else {
    u16* dh_ = sc16h + ((size_t)b << 19) + (h << 6);
    u16* dl_ = sc16l + ((size_t)b << 19) + (h << 6);
#pragma unroll
    for (int nt = 0; nt < 4; ++nt)
#pragma unroll
      for (int r = 0; r < 4; ++r) {
        int co = mt * 16 + quad * 4 + r;
        float xv = acc[nt][r];
        u16 hi = f2bf(xv);
        float lo = xv - bf2f(hi);
        size_t o = ((size_t)co << 12) + nt * 16 + mi;
        dh_[o] = hi;
        dl_[o] = f2bf(lo);
      }
  }
}

// ---------------- K3: fused q,k,v 1x1 convs via MFMA -------------------------
// Outputs: qb f32 [b][16][n]; k16t split-bf16 A-frag rows [b][n][32]
// (16 hi | 16 lo); vt16 bf16 [b][c][n].
__global__ __launch_bounds__(256) void k_qkv(
    const u16* __restrict__ sa_nhwc, const u16* __restrict__ Wqkvb,
    const float* __restrict__ bq, const float* __restrict__ bk,
    const float* __restrict__ bv,
    float* __restrict__ qb, u16* __restrict__ k16t, u16* __restrict__ vt16) {
  __shared__ float bs[160];
  int t = threadIdx.x;
  int b = blockIdx.y, n0 = blockIdx.x * 128;
  if (t < 160) bs[t] = t < 16 ? bq[t] : (t < 32 ? bk[t - 16] : bv[t - 32]);
  __syncthreads();
  int lane = t & 63, wave = t >> 6;
  int mi = lane & 15, quad = lane >> 4;
  const u16* xb = sa_nhwc + ((size_t)b << 19) + (size_t)n0 * 128;
  const u16* wb = Wqkvb + lane * 8;
  f32x4 acc[2][10] = {};
  short8 bf[2][4];
#pragma unroll
  for (int ns = 0; ns < 2; ++ns) {
    int n = wave * 32 + ns * 16 + mi;
#pragma unroll
    for (int ks = 0; ks < 4; ++ks)
      bf[ns][ks] = *(const short8*)(xb + (size_t)n * 128 + ks * 32 + quad * 8);
  }
#pragma unroll
  for (int cot = 0; cot < 10; ++cot) {
    short8 a0 = *(const short8*)(wb + (size_t)(cot * 4 + 0) * 512);
    short8 a1 = *(const short8*)(wb + (size_t)(cot * 4 + 1) * 512);
    short8 a2 = *(const short8*)(wb + (size_t)(cot * 4 + 2) * 512);
    short8 a3 = *(const short8*)(wb + (size_t)(cot * 4 + 3) * 512);
#pragma unroll
    for (int ns = 0; ns < 2; ++ns) {
      acc[ns][cot] = __builtin_amdgcn_mfma_f32_16x16x32_bf16(a0, bf[ns][0], acc[ns][cot], 0, 0, 0);
      acc[ns][cot] = __builtin_amdgcn_mfma_f32_16x16x32_bf16(a1, bf[ns][1], acc[ns][cot], 0, 0, 0);
      acc[ns][cot] = __builtin_amdgcn_mfma_f32_16x16x32_bf16(a2, bf[ns][2], acc[ns][cot], 0, 0, 0);
      acc[ns][cot] = __builtin_amdgcn_mfma_f32_16x16x32_bf16(a3, bf[ns][3], acc[ns][cot], 0, 0, 0);
    }
  }
#pragma unroll
  for (int cot = 0; cot < 10; ++cot)
#pragma unroll
    for (int ns = 0; ns < 2; ++ns) {
      int n = n0 + wave * 32 + ns * 16 + mi;
      if (cot == 1) {
        u16 hv[4], lv[4];
#pragma unroll
        for (int r = 0; r < 4; ++r) {
          float v = acc[ns][1][r] + bs[16 + quad * 4 + r];
          u16 hi = f2bf(v);
          hv[r] = hi;
          lv[r] = f2bf(v - bf2f(hi));
        }
        u16* kd = k16t + (((size_t)b << 12) + n) * 32;
        U16x4 h4{hv[0], hv[1], hv[2], hv[3]};
        U16x4 l4{lv[0], lv[1], lv[2], lv[3]};
        *(U16x4*)(kd + quad * 4) = h4;
        *(U16x4*)(kd + 16 + quad * 4) = l4;
      } else {
#pragma unroll
        for (int r = 0; r < 4; ++r) {
          int co = cot * 16 + quad * 4 + r;
          float v = acc[ns][cot][r] + bs[co];
          if (co < 16) qb[((b * 16 + co) << 12) + n] = v;
          else vt16[((size_t)(b * 128 + co - 32) << 12) + n] = f2bf(v);
        }
      }
    }
}

// ---------------- K5: PAM PV, online softmax, K A-frags direct from global ---
// grid (128, 2, 2): block = 32 n x 2048 m. No K LDS staging: k16t[b][m][32]
// already IS the split-bf16 energy A-frag; loaded per chunk (prefetched),
// coalesced, L2-resident. LDS = pL + qf + reduce bufs (~21 KB) -> 4 blocks/CU.
__global__ __launch_bounds__(512, 4) void k_pam_pv(const float* __restrict__ qb,
    const u16* __restrict__ k16t, const u16* __restrict__ vt16,
    float* __restrict__ pvpart, float* __restrict__ pmax, float* __restrict__ psum) {
  constexpr int PSTR = 264;
  __shared__ u16 pL[32 * PSTR];
  __shared__ u16 qfh[32 * 16], qfl[32 * 16];
  __shared__ float wmx[8][2][16];
  __shared__ float wsm[8][2][16];
  int t = threadIdx.x;
  int b = blockIdx.y, n0 = blockIdx.x * 32;
  int mbeg = blockIdx.z << 11;
  int lane = t & 63, wave = t >> 6;
  int mi = lane & 15, quad = lane >> 4;
  int c0 = wave * 16;
  {
    int ch = t & 15, nl = t >> 4;
    float qv = qb[((size_t)(b * 16 + ch) << 12) + n0 + nl];
    u16 hi = f2bf(qv);
    qfh[nl * 16 + ch] = hi;
    qfl[nl * 16 + ch] = f2bf(qv - bf2f(hi));
  }
  const u16* kp = k16t + (((size_t)b << 12) + mbeg) * 32;
  const u16* vb = vt16 + ((size_t)b * 128 << 12);
  f32x4 acc[2] = {};
  float mr0 = -1e30f, mr1 = -1e30f, ssum0 = 0.f, ssum1 = 0.f;
  __syncthreads();   // qf ready
  int qoff = (quad & 1) * 8;
  short8 bq1[2], bq2[2];
  bq1[0] = *(const short8*)(qfh + mi * 16 + qoff);
  bq1[1] = *(const short8*)(qfh + (16 + mi) * 16 + qoff);
  bq2[0] = *(const short8*)(qfl + mi * 16 + qoff);
  bq2[1] = *(const short8*)(qfl + (16 + mi) * 16 + qoff);
  // prologue: chunk-0 A-frags
  size_t abase = (size_t)(wave * 32 + mi) * 32 + quad * 8;
  short8 a0c = *(const short8*)(kp + abase);
  short8 a1c = *(const short8*)(kp + abase + 512);
  for (int it = 0; it < 8; ++it) {
    int m0r = it << 8;
    short8 vreg[8];
#pragma unroll
    for (int ksl = 0; ksl < 8; ++ksl)
      vreg[ksl] = *(const short8*)(vb + ((size_t)(c0 + mi) << 12) + mbeg + m0r + ksl * 32 + quad * 8);
    short8 a0n, a1n;
    if (it < 7) {
      a0n = *(const short8*)(kp + (size_t)(it + 1) * 8192 + abase);
      a1n = *(const short8*)(kp + (size_t)(it + 1) * 8192 + abase + 512);
    }
    // energy MFMA
    f32x4 e00 = {}, e01 = {}, e10 = {}, e11 = {};
    e00 = __builtin_amdgcn_mfma_f32_16x16x32_bf16(a0c, bq1[0], e00, 0, 0, 0);
    e00 = __builtin_amdgcn_mfma_f32_16x16x32_bf16(a0c, bq2[0], e00, 0, 0, 0);
    e01 = __builtin_amdgcn_mfma_f32_16x16x32_bf16(a0c, bq1[1], e01, 0, 0, 0);
    e01 = __builtin_amdgcn_mfma_f32_16x16x32_bf16(a0c, bq2[1], e01, 0, 0, 0);
    e10 = __builtin_amdgcn_mfma_f32_16x16x32_bf16(a1c, bq1[0], e10, 0, 0, 0);
    e10 = __builtin_amdgcn_mfma_f32_16x16x32_bf16(a1c, bq2[0], e10, 0, 0, 0);
    e11 = __builtin_amdgcn_mfma_f32_16x16x32_bf16(a1c, bq1[1], e11, 0, 0, 0);
    e11 = __builtin_amdgcn_mfma_f32_16x16x32_bf16(a1c, bq2[1], e11, 0, 0, 0);
    // per-wave per-n max (over this wave's 32 m)
    float lm0 = fmaxf(fmaxf(fmaxf(e00[0], e00[1]), fmaxf(e00[2], e00[3])),
                      fmaxf(fmaxf(e10[0], e10[1]), fmaxf(e10[2], e10[3])));
    float lm1 = fmaxf(fmaxf(fmaxf(e01[0], e01[1]), fmaxf(e01[2], e01[3])),
                      fmaxf(fmaxf(e11[0], e11[1]), fmaxf(e11[2], e11[3])));
    lm0 = fmaxf(lm0, __shfl_xor(lm0, 16)); lm0 = fmaxf(lm0, __shfl_xor(lm0, 32));
    lm1 = fmaxf(lm1, __shfl_xor(lm1, 16)); lm1 = fmaxf(lm1, __shfl_xor(lm1, 32));
    if (quad == 0) { wmx[wave][0][mi] = lm0; wmx[wave][1][mi] = lm1; }
    __syncthreads();   // B1: wmx ready; prior pL reads done
    // block-wide chunk max, online update
    float cm0 = wmx[0][0][mi], cm1 = wmx[0][1][mi];
#pragma unroll
    for (int w = 1; w < 8; ++w) {
      cm0 = fmaxf(cm0, wmx[w][0][mi]);
      cm1 = fmaxf(cm1, wmx[w][1][mi]);
    }
    float mn0 = fmaxf(mr0, cm0), mn1 = fmaxf(mr1, cm1);
    float rs0 = __expf(mr0 - mn0), rs1 = __expf(mr1 - mn1);
#pragma unroll
    for (int r = 0; r < 4; ++r) { acc[0][r] *= rs0; acc[1][r] *= rs1; }
    float p00[4], p10[4], p01[4], p11[4];
    float ls0 = 0.f, ls1 = 0.f;
#pragma unroll
    for (int j = 0; j < 4; ++j) {
      p00[j] = __expf(e00[j] - mn0); p10[j] = __expf(e10[j] - mn0);
      p01[j] = __expf(e01[j] - mn1); p11[j] = __expf(e11[j] - mn1);
      ls0 += p00[j] + p10[j];
      ls1 += p01[j] + p11[j];
    }
    ssum0 = ssum0 * rs0 + ls0;
    ssum1 = ssum1 * rs1 + ls1;
    mr0 = mn0; mr1 = mn1;
    u16* prow0 = pL + mi * PSTR + wave * 32 + quad * 4;
    u16* prow1 = pL + (16 + mi) * PSTR + wave * 32 + quad * 4;
    U16x4 p;
    p.x = f2bf(p00[0]); p.y = f2bf(p00[1]); p.z = f2bf(p00[2]); p.w = f2bf(p00[3]);
    *(U16x4*)(prow0) = p;
    p.x = f2bf(p10[0]); p.y = f2bf(p10[1]); p.z = f2bf(p10[2]); p.w = f2bf(p10[3]);
    *(U16x4*)(prow0 + 16) = p;
    p.x = f2bf(p01[0]); p.y = f2bf(p01[1]); p.z = f2bf(p01[2]); p.w = f2bf(p01[3]);
    *(U16x4*)(prow1) = p;
    p.x = f2bf(p11[0]); p.y = f2bf(p11[1]); p.z = f2bf(p11[2]); p.w = f2bf(p11[3]);
    *(U16x4*)(prow1 + 16) = p;
    __syncthreads();   // B2: pL ready
    // PV MFMA
#pragma unroll
    for (int ksl = 0; ksl < 8; ++ksl) {
      const u16* pb0 = pL + mi * PSTR + ksl * 32 + quad * 8;
      short8 b0 = *(const short8*)(pb0);
      short8 b1 = *(const short8*)(pb0 + 16 * PSTR);
      acc[0] = __builtin_amdgcn_mfma_f32_16x16x32_bf16(vreg[ksl], b0, acc[0], 0, 0, 0);
      acc[1] = __builtin_amdgcn_mfma_f32_16x16x32_bf16(vreg[ksl], b1, acc[1], 0, 0, 0);
    }
    a0c = a0n; a1c = a1n;
  }
  // final per-n sum reduce (quad shuffle + cross-wave LDS)
  ssum0 += __shfl_xor(ssum0, 16); ssum0 += __shfl_xor(ssum0, 32);
  ssum1 += __shfl_xor(ssum1, 16); ssum1 += __shfl_xor(ssum1, 32);
  if (quad == 0) { wsm[wave][0][mi] = ssum0; wsm[wave][1][mi] = ssum1; }
  __syncthreads();
  if (t < 16) {
    float sA = 0.f, sB = 0.f;
#pragma unroll
    for (int w = 0; w < 8; ++w) { sA += wsm[w][0][t]; sB += wsm[w][1][t]; }
    size_t base = ((size_t)(blockIdx.z * 2 + b) << 12) + n0;
    psum[base + t] = sA;
    psum[base + 16 + t] = sB;
    pmax[base + t] = mr0;
    pmax[base + 16 + t] = mr1;
  }
  float* dst = pvpart + (((size_t)(blockIdx.z * 2 + b) * 128) << 12);
#pragma unroll
  for (int nh = 0; nh < 2; ++nh)
#pragma unroll
    for (int r = 0; r < 4; ++r) {
      int c = c0 + quad * 4 + r;
      dst[((size_t)c << 12) + n0 + nh * 16 + mi] = acc[nh][r];
    }
}

// ---------------- K6a: CAM Gram energy via MFMA, split-bf16 ------------------
__global__ __launch_bounds__(512) void k_cam_energy_m(
    const u16* __restrict__ sc16h, const u16* __restrict__ sc16l,
    float* __restrict__ epart) {
  int t = threadIdx.x;
  int ti = blockIdx.x, kc = blockIdx.y, b = blockIdx.z;
  int lane = t & 63, wave = t >> 6;
  int mi = lane & 15, quad = lane >> 4;
  const u16* fh = sc16h + ((size_t)b << 19);
  const u16* fl = sc16l + ((size_t)b << 19);
  size_t ao = ((size_t)(ti * 16 + mi) << 12) + (kc << 9) + quad * 8;
  size_t bo = ((size_t)(wave * 16 + mi) << 12) + (kc << 9) + quad * 8;
  const u16* ah = fh + ao; const u16* al = fl + ao;
  const u16* bh = fh + bo; const u16* bl = fl + bo;
  f32x4 acc = {};
#pragma unroll
  for (int k = 0; k < 16; ++k) {
    short8 vah = *(const short8*)(ah + k * 32);
    short8 val = *(const short8*)(al + k * 32);
    short8 vbh = *(const short8*)(bh + k * 32);
    short8 vbl = *(const short8*)(bl + k * 32);
    acc = __builtin_amdgcn_mfma_f32_16x16x32_bf16(vah, vbh, acc, 0, 0, 0);
    acc = __builtin_amdgcn_mfma_f32_16x16x32_bf16(vah, vbl, acc, 0, 0, 0);
    acc = __builtin_amdgcn_mfma_f32_16x16x32_bf16(val, vbh, acc, 0, 0, 0);
  }
  float* ep = epart + (((size_t)(kc * 2 + b)) << 14);
#pragma unroll
  for (int r = 0; r < 4; ++r)
    ep[((ti * 16 + quad * 4 + r) << 7) + wave * 16 + mi] = acc[r];
}

// ---------------- K6b: CAM softmax row (reduce 8 partials) -------------------
__global__ void k_cam_softmax(const float* __restrict__ epart, float* __restrict__ attn) {
  int lane = threadIdx.x;
  int c = blockIdx.x, b = blockIdx.y;
  float e0 = 0.f, e1 = 0.f;
#pragma unroll
  for (int kc = 0; kc < 8; ++kc) {
    const float* ep = epart + (((size_t)(kc * 2 + b)) << 14) + (c << 7);
    e0 += ep[lane];
    e1 += ep[lane + 64];
  }
  float mn = fminf(e0, e1);
#pragma unroll
  for (int off = 32; off >= 1; off >>= 1) mn = fminf(mn, __shfl_xor(mn, off));
  float p0 = __expf(fminf(mn - e0, 0.f)), p1 = __expf(fminf(mn - e1, 0.f));
  float s = p0 + p1;
#pragma unroll
  for (int off = 32; off >= 1; off >>= 1) s += __shfl_xor(s, off);
  float inv = 1.f / s;
  float* a = attn + ((b * 128 + c) << 7);
  a[lane] = p0 * inv;
  a[lane + 64] = p1 * inv;
}

// ---------------- K7: CAM out + residual -------------------------------------
__global__ __launch_bounds__(256) void k_cam_out(const float* __restrict__ f,
    const float* __restrict__ attn, const float* __restrict__ gamma,
    float* __restrict__ sc1) {
  __shared__ float at2[128 * 16];
  int t = threadIdx.x;
  int b = blockIdx.z, c0 = blockIdx.y * 16;
  int n = blockIdx.x * 256 + t;
  for (int idx = t; idx < 2048; idx += 256) {
    int d = idx >> 4, cc = idx & 15;
    at2[idx] = attn[((b * 128 + c0 + cc) << 7) + d];
  }
  __syncthreads();
  float acc[16] = {};
  const float* fb = f + ((size_t)b * 128 << 12) + n;
  for (int d = 0; d < 128; ++d) {
    float fv = fb[d << 12];
    const float* ap = at2 + d * 16;
#pragma unroll
    for (int cc = 0; cc < 16; ++cc) acc[cc] = fmaf(ap[cc], fv, acc[cc]);
  }
  float g = gamma[0];
#pragma unroll
  for (int cc = 0; cc < 16; ++cc) {
    size_t o = ((size_t)(b * 128 + c0 + cc) << 12) + n;
    sc1[o] = fmaf(g, acc[cc], f[o]);
  }
}

// ---------------- K8: BN+ReLU + 1x1 conv 128->512 via MFMA -------------------
__global__ __launch_bounds__(256, 2) void k_bout_m(
    const float* __restrict__ sa0, const float* __restrict__ pvpart,
    const float* __restrict__ pmax, const float* __restrict__ psum,
    const float* __restrict__ gamma,
    const float* __restrict__ sc1,
    const float* __restrict__ wa_, const float* __restrict__ ba_,
    const float* __restrict__ ma_, const float* __restrict__ va_,
    const float* __restrict__ wc_, const float* __restrict__ bc_,
    const float* __restrict__ mc_, const float* __restrict__ vc_,
    const u16* __restrict__ W1b, const float* __restrict__ Ba,
    const float* __restrict__ Bc,
    u16* __restrict__ sa2, u16* __restrict__ sc2) {
  __shared__ u16 xl[32 * 136];
  __shared__ float scl[128], shf[128];
  int t = threadIdx.x;
  int n0 = blockIdx.x * 32;
  int b = blockIdx.y, br = blockIdx.z;
  const float* bw = br ? wc_ : wa_;
  const float* bb = br ? bc_ : ba_;
  const float* bm = br ? mc_ : ma_;
  const float* bvv = br ? vc_ : va_;
  if (t < 128) {
    float s = bw[t] * rsqrtf(bvv[t] + 1e-5f);
    scl[t] = s;
    shf[t] = bb[t] - bm[t] * s;
  }
  __syncthreads();
  {
    int nl = t & 31, cio = t >> 5;
    const float* s0 = (br ? sc1 : sa0) + ((size_t)b * 128 << 12) + n0 + nl;
    const float* p0 = pvpart + ((size_t)b * 128 << 12) + n0 + nl;
    const float* p1 = pvpart + (((size_t)(2 + b) * 128) << 12) + n0 + nl;
    float k0 = 0.f, k1 = 0.f;
    if (!br) {
      int n = n0 + nl;
      float m0 = pmax[((size_t)b << 12) + n];
      float m1 = pmax[((size_t)(2 + b) << 12) + n];
      float sA = psum[((size_t)b << 12) + n];
      float sB = psum[((size_t)(2 + b) << 12) + n];
      float M = fmaxf(m0, m1);
      float w0 = __expf(m0 - M), w1 = __expf(m1 - M);
      float inv = gamma[0] / (w0 * sA + w1 * sB);
      k0 = w0 * inv; k1 = w1 * inv;
    }
#pragma unroll
    for (int half = 0; half < 2; ++half) {
      short8 v;
#pragma unroll
      for (int i = 0; i < 8; ++i) {
        int ci = cio * 16 + half * 8 + i;
        float xv = s0[(size_t)ci << 12];
        if (!br) xv += k0 * p0[(size_t)ci << 12] + k1 * p1[(size_t)ci << 12];
        v[i] = (short)f2bf(fmaxf(fmaf(xv, scl[ci], shf[ci]), 0.f));
      }
      *(short8*)(xl + nl * 136 + cio * 16 + half * 8) = v;
    }
  }
  __syncthreads();
  int lane = t & 63, wave = t >> 6;
  int mi = lane & 15, quad = lane >> 4;
  const u16* wb = W1b + (size_t)br * 65536 + lane * 8;
  f32x4 acc[8][2] = {};
#pragma unroll
  for (int ks = 0; ks < 4; ++ks) {
    short8 b0 = *(const short8*)(xl + mi * 136 + ks * 32 + quad * 8);
    short8 b1 = *(const short8*)(xl + (16 + mi) * 136 + ks * 32 + quad * 8);
#pragma unroll
    for (int ct = 0; ct < 8; ++ct) {
      int cot = wave * 8 + ct;
      short8 a = *(const short8*)(wb + ((size_t)(cot * 4 + ks) << 9));
      acc[ct][0] = __builtin_amdgcn_mfma_f32_16x16x32_bf16(a, b0, acc[ct][0], 0, 0, 0);
      acc[ct][1] = __builtin_amdgcn_mfma_f32_16x16x32_bf16(a, b1, acc[ct][1], 0, 0, 0);
    }
  }
  const float* Bs = br ? Bc : Ba;
  u16* dst = br ? sc2 : sa2;
#pragma unroll
  for (int ct = 0; ct < 8; ++ct)
#pragma unroll
    for (int nh = 0; nh < 2; ++nh)
#pragma unroll
      for (int r = 0; r < 4; ++r) {
        int co = (wave * 8 + ct) * 16 + quad * 4 + r;
        dst[((size_t)(b * 512 + co) << 12) + n0 + nh * 16 + mi] =
            f2bf(acc[ct][nh][r] + Bs[co]);
      }
}

// ---------------- K9: fusion + class heads, atomic-free, fused bias ----------
__global__ __launch_bounds__(256) void k_heads2(const u16* __restrict__ sa2,
    const u16* __restrict__ sc2,
    const float* __restrict__ wf, const float* __restrict__ wa, const float* __restrict__ wc,
    const float* __restrict__ bfb, const float* __restrict__ bab,
    const float* __restrict__ bcb,
    float* __restrict__ outFusion, float* __restrict__ outCls) {
  __shared__ float lw[3 * 5 * 512];
  __shared__ float hs[8][15][32];
  int t = threadIdx.x;
  int b = blockIdx.y, n0 = blockIdx.x * 32;
  for (int idx = t; idx < 7680; idx += 256) {
    int arr = idx / 2560, rest = idx - arr * 2560;
    int cls = rest >> 9, co = rest & 511;
    const float* w = arr == 0 ? wf : (arr == 1 ? wa : wc);
    lw[idx] = w[cls * 512 + co];
  }
  __syncthreads();
  int nl = t & 31, ck = t >> 5;
  float acc[15] = {};
  for (int co = ck * 64; co < ck * 64 + 64; ++co) {
    size_t o = ((size_t)(b * 512 + co) << 12) + n0 + nl;
    float a = bf2f(sa2[o]), c = bf2f(sc2[o]);
    float s = a + c;
    outFusion[o] = s;
    const float* lf = lw + co;
#pragma unroll
    for (int cls = 0; cls < 5; ++cls) {
      acc[cls]      = fmaf(lf[cls * 512], s, acc[cls]);
      acc[5 + cls]  = fmaf(lf[2560 + cls * 512], a, acc[5 + cls]);
      acc[10 + cls] = fmaf(lf[5120 + cls * 512], c, acc[10 + cls]);
    }
  }
#pragma unroll
  for (int k = 0; k < 15; ++k) hs[ck][k][nl] = acc[k];
  __syncthreads();
  for (int idx = t; idx < 480; idx += 256) {
    int k = idx >> 5, nl2 = idx & 31;
    float s = 0.f;
#pragma unroll
    for (int c8 = 0; c8 < 8; ++c8) s += hs[c8][k][nl2];
    int arr = k / 5, cls = k - arr * 5;
    float bias = arr == 0 ? bfb[cls] : (arr == 1 ? bab[cls] : bcb[cls]);
    outCls[arr * 40960 + ((b * 5 + cls) << 12) + n0 + nl2] = s + bias;
  }
}

extern "C" void kernel_launch(void* const* d_in, const int* in_sizes, int n_in,
                              void* d_out, int out_size, void* d_ws, size_t ws_size,
                              hipStream_t stream) {
  (void)in_sizes; (void)n_in; (void)out_size; (void)ws_size;
  const float* x      = (const float*)d_in[0];
  const float* bnaw   = (const float*)d_in[1];
  const float* bnab   = (const float*)d_in[2];
  const float* bnam   = (const float*)d_in[3];
  const float* bnav   = (const float*)d_in[4];
  const float* convaw = (const float*)d_in[5];
  const float* bncw   = (const float*)d_in[6];
  const float* bncb   = (const float*)d_in[7];
  const float* bncm   = (const float*)d_in[8];
  const float* bncv   = (const float*)d_in[9];
  const float* convcw = (const float*)d_in[10];
  const float* pqw    = (const float*)d_in[11];
  const float* pqb    = (const float*)d_in[12];
  const float* pkw    = (const float*)d_in[13];
  const float* pkb    = (const float*)d_in[14];
  const float* pvw    = (const float*)d_in[15];
  const float* pvb    = (const float*)d_in[16];
  const float* pgam   = (const float*)d_in[17];
  const float* cgam   = (const float*)d_in[18];
  const float* bna1w  = (const float*)d_in[19];
  const float* bna1b  = (const float*)d_in[20];
  const float* bna1m  = (const float*)d_in[21];
  const float* bna1v  = (const float*)d_in[22];
  const float* conva1w = (const float*)d_in[23];
  const float* conva1b = (const float*)d_in[24];
  const float* bnc1w  = (const float*)d_in[25];
  const float* bnc1b  = (const float*)d_in[26];
  const float* bnc1m  = (const float*)d_in[27];
  const float* bnc1v  = (const float*)d_in[28];
  const float* convc1w = (const float*)d_in[29];
  const float* convc1b = (const float*)d_in[30];
  const float* outaw  = (const float*)d_in[31];
  const float* outab  = (const float*)d_in[32];
  const float* outcw  = (const float*)d_in[33];
  const float* outcb  = (const float*)d_in[34];
  const float* outfw  = (const float*)d_in[35];
  const float* outfb  = (const float*)d_in[36];

  char* wsb = (char*)d_ws;
  size_t off = 0;
  auto take = [&](size_t bytes) -> void* {
    void* p = wsb + off;
    off += (bytes + 255) & ~(size_t)255;
    return p;
  };
  u16*   Wb    = (u16*)take((size_t)2 * 128 * 9 * 512 * 2);
  u16*   W1b   = (u16*)take((size_t)2 * 512 * 128 * 2);
  u16*   Wqkvb = (u16*)take((size_t)160 * 128 * 2);
  u16*   xa16  = (u16*)take((size_t)2 * 512 * 4096 * 2);
  u16*   xcb16 = (u16*)take((size_t)2 * 512 * 4096 * 2);
  float* sa0   = (float*)take((size_t)2 * 128 * 4096 * 4);
  float* sc0   = (float*)take((size_t)2 * 128 * 4096 * 4);
  u16*   sa_nhwc = (u16*)take((size_t)2 * 4096 * 128 * 2);
  u16*   sc16h = (u16*)take((size_t)2 * 128 * 4096 * 2);
  u16*   sc16l = (u16*)take((size_t)2 * 128 * 4096 * 2);
  float* qb    = (float*)take((size_t)2 * 16 * 4096 * 4);
  u16*   k16t  = (u16*)take((size_t)2 * 4096 * 32 * 2);
  u16*   vt16  = (u16*)take((size_t)2 * 128 * 4096 * 2);
  float* pvpart = (float*)take((size_t)2 * 2 * 128 * 4096 * 4);
  float* pmax  = (float*)take((size_t)2 * 2 * 4096 * 4);
  float* psum  = (float*)take((size_t)2 * 2 * 4096 * 4);
  float* sc1   = (float*)take((size_t)2 * 128 * 4096 * 4);
  float* epart = (float*)take((size_t)8 * 2 * 128 * 128 * 4);
  float* attn  = (float*)take((size_t)2 * 128 * 128 * 4);
  u16*   sa2   = (u16*)take((size_t)2 * 512 * 4096 * 2);
  u16*   sc2   = (u16*)take((size_t)2 * 512 * 4096 * 2);

  float* outF = (float*)d_out;
  float* outCls = outF + (size_t)2 * 512 * 4096;

  k_prep_w<<<4608, 256, 0, stream>>>(convaw, convcw, Wb);
  k_prep_w1<<<512, 256, 0, stream>>>(conva1w, convc1w, W1b);
  k_prep_wqkv<<<80, 256, 0, stream>>>(pqw, pkw, pvw, Wqkvb);
  k_bnrelu2t<<<dim3(64, 2), 256, 0, stream>>>(x, bnaw, bnab, bnam, bnav,
                                              bncw, bncb, bncm, bncv, xa16, xcb16);
  k_conv3n<<<dim3(64, 4, 2), 256, 0, stream>>>(xa16, xcb16, Wb, sa0, sc0,
                                               sa_nhwc, sc16h, sc16l);
  k_qkv<<<dim3(32, 2), 256, 0, stream>>>(sa_nhwc, Wqkvb, pqb, pkb, pvb,
                                         qb, k16t, vt16);
  k_pam_pv<<<dim3(128, 2, 2), 512, 0, stream>>>(qb, k16t, vt16, pvpart, pmax, psum);
  k_cam_energy_m<<<dim3(8, 8, 2), 512, 0, stream>>>(sc16h, sc16l, epart);
  k_cam_softmax<<<dim3(128, 2), 64, 0, stream>>>(epart, attn);
  k_cam_out<<<dim3(16, 8, 2), 256, 0, stream>>>(sc0, attn, cgam, sc1);
  k_bout_m<<<dim3(128, 2, 2), 256, 0, stream>>>(sa0, pvpart, pmax, psum, pgam, sc1,
      bna1w, bna1b, bna1m, bna1v, bnc1w, bnc1b, bnc1m, bnc1v,
      W1b, conva1b, convc1b, sa2, sc2);
  k_heads2<<<dim3(128, 2), 256, 0, stream>>>(sa2, sc2, outfw, outaw, outcw,
                                             outfb, outab, outcb, outF, outCls);
}

// Round 11
// 290.816 us; speedup vs baseline: 1.9782x; 1.0595x over previous
//
#include <hip/hip_runtime.h>

using u16 = unsigned short;
using short8 = __attribute__((ext_vector_type(8))) short;
using f32x4 = __attribute__((ext_vector_type(4))) float;

struct alignas(8) U16x4 { u16 x, y, z, w; };

__device__ __forceinline__ float bf2f(u16 u) {
  return __uint_as_float(((unsigned int)u) << 16);
}
__device__ __forceinline__ u16 f2bf(float f) {
  unsigned int u = __float_as_uint(f);
  unsigned int r = u + 0x7FFFu + ((u >> 16) & 1u);
  return (u16)(r >> 16);
}

// ---------------- K0b: conv weights -> bf16, MFMA-fragment order -------------
__global__ void k_prep_w(const float* __restrict__ wa, const float* __restrict__ wc,
                         u16* __restrict__ Wb) {
  int idx = blockIdx.x * 256 + threadIdx.x;   // 1179648
  int j = idx & 7;
  int l = (idx >> 3) & 63;
  int ks = (idx >> 9) & 3;
  int rest = idx >> 11;
  int tap = rest % 9;
  int rest2 = rest / 9;
  int chunk = rest2 & 3;
  int mt = (rest2 >> 2) & 7;
  int br = rest2 >> 5;
  int co = mt * 16 + (l & 15);
  int ci = chunk * 128 + ks * 32 + (l >> 4) * 8 + j;
  const float* w = br ? wc : wa;
  Wb[idx] = f2bf(w[co * 4608 + ci * 9 + tap]);
}

// ---------------- K0c: 1x1 out-conv weights (128->512) -> bf16 A-frag order --
__global__ void k_prep_w1(const float* __restrict__ wa, const float* __restrict__ wc,
                          u16* __restrict__ W1b) {
  int idx = blockIdx.x * 256 + threadIdx.x;   // 131072
  int j = idx & 7;
  int l = (idx >> 3) & 63;
  int ks = (idx >> 9) & 3;
  int cot = (idx >> 11) & 31;
  int br = idx >> 16;
  int co = cot * 16 + (l & 15);
  int ci = ks * 32 + (l >> 4) * 8 + j;
  const float* w = br ? wc : wa;
  W1b[idx] = f2bf(w[co * 128 + ci]);
}

// ---------------- K0d: qkv weights (160x128) -> bf16 A-frag order ------------
__global__ void k_prep_wqkv(const float* __restrict__ wq, const float* __restrict__ wk,
                            const float* __restrict__ wv, u16* __restrict__ Wq) {
  int idx = blockIdx.x * 256 + threadIdx.x;   // 20480
  if (idx >= 20480) return;
  int j = idx & 7;
  int l = (idx >> 3) & 63;
  int ks = (idx >> 9) & 3;
  int cot = idx >> 11;
  int co = cot * 16 + (l & 15);
  int ci = ks * 32 + (l >> 4) * 8 + j;
  float w = co < 16 ? wq[co * 128 + ci]
          : (co < 32 ? wk[(co - 16) * 128 + ci] : wv[(co - 32) * 128 + ci]);
  Wq[idx] = f2bf(w);
}

// ---------------- K1: BN+ReLU both branches, NHWC bf16; c-split 4 ------------
// grid (64 h, 2 b, 4 cstep): 512 blocks = 2/CU.
__global__ __launch_bounds__(256) void k_bnrelu2t(const float* __restrict__ x,
    const float* __restrict__ wa, const float* __restrict__ ba,
    const float* __restrict__ ma, const float* __restrict__ va,
    const float* __restrict__ wc, const float* __restrict__ bc,
    const float* __restrict__ mc, const float* __restrict__ vc,
    u16* __restrict__ xa16, u16* __restrict__ xcb16) {
  __shared__ float sA[128], bA[128], sC[128], bC[128];
  __shared__ u16 ta[64 * 136], tc[64 * 136];
  int t = threadIdx.x;
  int h = blockIdx.x, b = blockIdx.y;
  int c0 = blockIdx.z * 128;
  if (t < 128) {
    int c = c0 + t;
    float s1 = wa[c] * rsqrtf(va[c] + 1e-5f);
    sA[t] = s1; bA[t] = ba[c] - ma[c] * s1;
    float s2 = wc[c] * rsqrtf(vc[c] + 1e-5f);
    sC[t] = s2; bC[t] = bc[c] - mc[c] * s2;
  }
  __syncthreads();
  const float* xb = x + ((size_t)b << 21) + (h << 6);
  u16* oa = xa16 + ((size_t)b << 21) + ((size_t)h << 15);
  u16* oc = xcb16 + ((size_t)b << 21) + ((size_t)h << 15);
  int w = t & 63, cg = t >> 6;
#pragma unroll
  for (int i = 0; i < 8; ++i) {
    int cl = cg * 4 + i * 16;
    int c = c0 + cl;
    const float* xp = xb + (size_t)c * 4096 + w;
    float v0 = xp[0], v1 = xp[4096], v2 = xp[8192], v3 = xp[12288];
    U16x4 pa, pc;
    pa.x = f2bf(fmaxf(fmaf(v0, sA[cl], bA[cl]), 0.f));
    pa.y = f2bf(fmaxf(fmaf(v1, sA[cl + 1], bA[cl + 1]), 0.f));
    pa.z = f2bf(fmaxf(fmaf(v2, sA[cl + 2], bA[cl + 2]), 0.f));
    pa.w = f2bf(fmaxf(fmaf(v3, sA[cl + 3], bA[cl + 3]), 0.f));
    pc.x = f2bf(fmaxf(fmaf(v0, sC[cl], bC[cl]), 0.f));
    pc.y = f2bf(fmaxf(fmaf(v1, sC[cl + 1], bC[cl + 1]), 0.f));
    pc.z = f2bf(fmaxf(fmaf(v2, sC[cl + 2], bC[cl + 2]), 0.f));
    pc.w = f2bf(fmaxf(fmaf(v3, sC[cl + 3], bC[cl + 3]), 0.f));
    *(U16x4*)(ta + w * 136 + cl) = pa;
    *(U16x4*)(tc + w * 136 + cl) = pc;
  }
  __syncthreads();
#pragma unroll
  for (int i = 0; i < 4; ++i) {
    int idx = t + i * 256;
    int ww = idx >> 4, c8 = (idx & 15) << 3;
    *(short8*)(oa + (size_t)ww * 512 + c0 + c8) = *(const short8*)(ta + ww * 136 + c8);
    *(short8*)(oc + (size_t)ww * 512 + c0 + c8) = *(const short8*)(tc + ww * 136 + c8);
  }
}

// ---------------- K2: 3x3 conv, implicit GEMM, NHWC input --------------------
__global__ __launch_bounds__(256, 2) void k_conv3n(
    const u16* __restrict__ xa16, const u16* __restrict__ xcb16,
    const u16* __restrict__ Wb,
    float* __restrict__ sa0, float* __restrict__ sc0,
    u16* __restrict__ sa_nhwc, u16* __restrict__ sc16h, u16* __restrict__ sc16l) {
  __shared__ u16 xs[3 * 66 * 136];
  int t = threadIdx.x;
  int h = blockIdx.x;
  int z = blockIdx.y; int b = z & 1, br = z >> 1;
  int cosplit = blockIdx.z;
  const u16* xb = (br ? xcb16 : xa16) + ((size_t)b << 21);
  const u16* wb = Wb + (size_t)br * 589824;
  float* out = (br ? sc0 : sa0) + (((size_t)b * 128) << 12) + (h << 6);

  int lane = t & 63, wave = t >> 6;
  int mi = lane & 15, quad = lane >> 4;
  int mt = cosplit * 4 + wave;

  if (t < 96) {
    int dh = t >> 5, side = (t >> 4) & 1, c8 = t & 15;
    short8 z8 = {0, 0, 0, 0, 0, 0, 0, 0};
    *(short8*)(xs + (dh * 66 + side * 65) * 136 + c8 * 8) = z8;
  }

  f32x4 acc[4] = {};

  const u16* wlane = wb + lane * 8;
  const u16* bbase0 = xs + mi * 136 + quad * 8;

  for (int chunk = 0; chunk < 4; ++chunk) {
    int ci0 = chunk << 7;
    __syncthreads();
#pragma unroll
    for (int dh = 0; dh < 3; ++dh) {
      int hh = h + dh - 1;
      bool val = (hh >= 0) && (hh < 64);
      const u16* src = xb + (((size_t)hh << 6) << 9) + ci0;
#pragma unroll
      for (int i = 0; i < 4; ++i) {
        int idx = t + i * 256;
        int w = idx >> 4, c8 = (idx & 15) << 3;
        short8 v = {0, 0, 0, 0, 0, 0, 0, 0};
        if (val) v = *(const short8*)(src + ((size_t)w << 9) + c8);
        *(short8*)(xs + (dh * 66 + 1 + w) * 136 + c8) = v;
      }
    }
    __syncthreads();
    const u16* wchunk = wlane + (size_t)(mt * 4 + chunk) * 18432;
    short8 wreg[2][4];
#pragma unroll
    for (int ks = 0; ks < 4; ++ks)
      wreg[0][ks] = *(const short8*)(wchunk + ks * 512);
#pragma unroll
    for (int tap = 0; tap < 9; ++tap) {
      const int cb = tap & 1;
      if (tap < 8) {
        const u16* wn = wchunk + (tap + 1) * 2048;
#pragma unroll
        for (int ks = 0; ks < 4; ++ks)
          wreg[cb ^ 1][ks] = *(const short8*)(wn + ks * 512);
      }
      const int dh = tap / 3, dw = tap % 3;
      const u16* bp = bbase0 + (dh * 66 + dw) * 136;
#pragma unroll
      for (int ks = 0; ks < 4; ++ks) {
        short8 a = wreg[cb][ks];
#pragma unroll
        for (int nt = 0; nt < 4; ++nt) {
          short8 bf = *(const short8*)(bp + nt * 2176 + ks * 32);
          acc[nt] = __builtin_amdgcn_mfma_f32_16x16x32_bf16(a, bf, acc[nt], 0, 0, 0);
        }
      }
    }
  }
#pragma unroll
  for (int nt = 0; nt < 4; ++nt)
#pragma unroll
    for (int r = 0; r < 4; ++r) {
      int co = mt * 16 + quad * 4 + r;
      out[((size_t)co << 12) + nt * 16 + mi] = acc[nt][r];
    }
  if (br == 0) {
    u16* dstq = sa_nhwc + ((size_t)b << 19) + ((size_t)h << 6) * 128;
#pragma unroll
    for (int nt = 0; nt < 4; ++nt) {
      U16x4 v4;
      v4.x = f2bf(acc[nt][0]); v4.y = f2bf(acc[nt][1]);
      v4.z = f2bf(acc[nt][2]); v4.w = f2bf(acc[nt][3]);
      *(U16x4*)(dstq + (size_t)(nt * 16 + mi) * 128 + mt * 16 + quad * 4) = v4;
    }
  } else {
    u16* dh_ = sc16h + ((size_t)b << 19) + (h << 6);
    u16* dl_ = sc16l + ((size_t)b << 19) + (h << 6);
#pragma unroll
    for (int nt = 0; nt < 4; ++nt)
#pragma unroll
      for (int r = 0; r < 4; ++r) {
        int co = mt * 16 + quad * 4 + r;
        float xv = acc[nt][r];
        u16 hi = f2bf(xv);
        float lo = xv - bf2f(hi);
        size_t o = ((size_t)co << 12) + nt * 16 + mi;
        dh_[o] = hi;
        dl_[o] = f2bf(lo);
      }
  }
}

// ---------------- K3: fused q,k,v 1x1 convs via MFMA -------------------------
__global__ __launch_bounds__(256) void k_qkv(
    const u16* __restrict__ sa_nhwc, const u16* __restrict__ Wqkvb,
    const float* __restrict__ bq, const float* __restrict__ bk,
    const float* __restrict__ bv,
    float* __restrict__ qb, u16* __restrict__ k16t, u16* __restrict__ vt16) {
  __shared__ float bs[160];
  int t = threadIdx.x;
  int b = blockIdx.y, n0 = blockIdx.x * 128;
  if (t < 160) bs[t] = t < 16 ? bq[t] : (t < 32 ? bk[t - 16] : bv[t - 32]);
  __syncthreads();
  int lane = t & 63, wave = t >> 6;
  int mi = lane & 15, quad = lane >> 4;
  const u16* xb = sa_nhwc + ((size_t)b << 19) + (size_t)n0 * 128;
  const u16* wb = Wqkvb + lane * 8;
  f32x4 acc[2][10] = {};
  short8 bf[2][4];
#pragma unroll
  for (int ns = 0; ns < 2; ++ns) {
    int n = wave * 32 + ns * 16 + mi;
#pragma unroll
    for (int ks = 0; ks < 4; ++ks)
      bf[ns][ks] = *(const short8*)(xb + (size_t)n * 128 + ks * 32 + quad * 8);
  }
#pragma unroll
  for (int cot = 0; cot < 10; ++cot) {
    short8 a0 = *(const short8*)(wb + (size_t)(cot * 4 + 0) * 512);
    short8 a1 = *(const short8*)(wb + (size_t)(cot * 4 + 1) * 512);
    short8 a2 = *(const short8*)(wb + (size_t)(cot * 4 + 2) * 512);
    short8 a3 = *(const short8*)(wb + (size_t)(cot * 4 + 3) * 512);
#pragma unroll
    for (int ns = 0; ns < 2; ++ns) {
      acc[ns][cot] = __builtin_amdgcn_mfma_f32_16x16x32_bf16(a0, bf[ns][0], acc[ns][cot], 0, 0, 0);
      acc[ns][cot] = __builtin_amdgcn_mfma_f32_16x16x32_bf16(a1, bf[ns][1], acc[ns][cot], 0, 0, 0);
      acc[ns][cot] = __builtin_amdgcn_mfma_f32_16x16x32_bf16(a2, bf[ns][2], acc[ns][cot], 0, 0, 0);
      acc[ns][cot] = __builtin_amdgcn_mfma_f32_16x16x32_bf16(a3, bf[ns][3], acc[ns][cot], 0, 0, 0);
    }
  }
#pragma unroll
  for (int cot = 0; cot < 10; ++cot)
#pragma unroll
    for (int ns = 0; ns < 2; ++ns) {
      int n = n0 + wave * 32 + ns * 16 + mi;
      if (cot == 1) {
        u16 hv[4], lv[4];
#pragma unroll
        for (int r = 0; r < 4; ++r) {
          float v = acc[ns][1][r] + bs[16 + quad * 4 + r];
          u16 hi = f2bf(v);
          hv[r] = hi;
          lv[r] = f2bf(v - bf2f(hi));
        }
        u16* kd = k16t + (((size_t)b << 12) + n) * 32;
        U16x4 h4{hv[0], hv[1], hv[2], hv[3]};
        U16x4 l4{lv[0], lv[1], lv[2], lv[3]};
        *(U16x4*)(kd + quad * 4) = h4;
        *(U16x4*)(kd + 16 + quad * 4) = l4;
      } else {
#pragma unroll
        for (int r = 0; r < 4; ++r) {
          int co = cot * 16 + quad * 4 + r;
          float v = acc[ns][cot][r] + bs[co];
          if (co < 16) qb[((b * 16 + co) << 12) + n] = v;
          else vt16[((size_t)(b * 128 + co - 32) << 12) + n] = f2bf(v);
        }
      }
    }
}

// ---------------- K5: PAM PV, online softmax, m-split 4 ----------------------
// grid (128, 2, 4): block = 32 n x 1024 m (4 chunks of 256). 1024 blocks =
// 4 blocks/CU. K A-frags direct from k16t (L2), V prefetched to regs.
__global__ __launch_bounds__(512, 4) void k_pam_pv(const float* __restrict__ qb,
    const u16* __restrict__ k16t, const u16* __restrict__ vt16,
    float* __restrict__ pvpart, float* __restrict__ pmax, float* __restrict__ psum) {
  constexpr int PSTR = 264;
  __shared__ u16 pL[32 * PSTR];
  __shared__ u16 qfh[32 * 16], qfl[32 * 16];
  __shared__ float wmx[8][2][16];
  __shared__ float wsm[8][2][16];
  int t = threadIdx.x;
  int b = blockIdx.y, n0 = blockIdx.x * 32;
  int mq = blockIdx.z;
  int mbeg = mq << 10;
  int lane = t & 63, wave = t >> 6;
  int mi = lane & 15, quad = lane >> 4;
  int c0 = wave * 16;
  {
    int ch = t & 15, nl = t >> 4;
    float qv = qb[((size_t)(b * 16 + ch) << 12) + n0 + nl];
    u16 hi = f2bf(qv);
    qfh[nl * 16 + ch] = hi;
    qfl[nl * 16 + ch] = f2bf(qv - bf2f(hi));
  }
  const u16* kp = k16t + (((size_t)b << 12) + mbeg) * 32;
  const u16* vb = vt16 + ((size_t)b * 128 << 12);
  f32x4 acc[2] = {};
  float mr0 = -1e30f, mr1 = -1e30f, ssum0 = 0.f, ssum1 = 0.f;
  __syncthreads();   // qf ready
  int qoff = (quad & 1) * 8;
  short8 bq1[2], bq2[2];
  bq1[0] = *(const short8*)(qfh + mi * 16 + qoff);
  bq1[1] = *(const short8*)(qfh + (16 + mi) * 16 + qoff);
  bq2[0] = *(const short8*)(qfl + mi * 16 + qoff);
  bq2[1] = *(const short8*)(qfl + (16 + mi) * 16 + qoff);
  size_t abase = (size_t)(wave * 32 + mi) * 32 + quad * 8;
  short8 a0c = *(const short8*)(kp + abase);
  short8 a1c = *(const short8*)(kp + abase + 512);
  for (int it = 0; it < 4; ++it) {
    int m0r = it << 8;
    short8 vreg[8];
#pragma unroll
    for (int ksl = 0; ksl < 8; ++ksl)
      vreg[ksl] = *(const short8*)(vb + ((size_t)(c0 + mi) << 12) + mbeg + m0r + ksl * 32 + quad * 8);
    short8 a0n, a1n;
    if (it < 3) {
      a0n = *(const short8*)(kp + (size_t)(it + 1) * 8192 + abase);
      a1n = *(const short8*)(kp + (size_t)(it + 1) * 8192 + abase + 512);
    }
    // energy MFMA
    f32x4 e00 = {}, e01 = {}, e10 = {}, e11 = {};
    e00 = __builtin_amdgcn_mfma_f32_16x16x32_bf16(a0c, bq1[0], e00, 0, 0, 0);
    e00 = __builtin_amdgcn_mfma_f32_16x16x32_bf16(a0c, bq2[0], e00, 0, 0, 0);
    e01 = __builtin_amdgcn_mfma_f32_16x16x32_bf16(a0c, bq1[1], e01, 0, 0, 0);
    e01 = __builtin_amdgcn_mfma_f32_16x16x32_bf16(a0c, bq2[1], e01, 0, 0, 0);
    e10 = __builtin_amdgcn_mfma_f32_16x16x32_bf16(a1c, bq1[0], e10, 0, 0, 0);
    e10 = __builtin_amdgcn_mfma_f32_16x16x32_bf16(a1c, bq2[0], e10, 0, 0, 0);
    e11 = __builtin_amdgcn_mfma_f32_16x16x32_bf16(a1c, bq1[1], e11, 0, 0, 0);
    e11 = __builtin_amdgcn_mfma_f32_16x16x32_bf16(a1c, bq2[1], e11, 0, 0, 0);
    float lm0 = fmaxf(fmaxf(fmaxf(e00[0], e00[1]), fmaxf(e00[2], e00[3])),
                      fmaxf(fmaxf(e10[0], e10[1]), fmaxf(e10[2], e10[3])));
    float lm1 = fmaxf(fmaxf(fmaxf(e01[0], e01[1]), fmaxf(e01[2], e01[3])),
                      fmaxf(fmaxf(e11[0], e11[1]), fmaxf(e11[2], e11[3])));
    lm0 = fmaxf(lm0, __shfl_xor(lm0, 16)); lm0 = fmaxf(lm0, __shfl_xor(lm0, 32));
    lm1 = fmaxf(lm1, __shfl_xor(lm1, 16)); lm1 = fmaxf(lm1, __shfl_xor(lm1, 32));
    if (quad == 0) { wmx[wave][0][mi] = lm0; wmx[wave][1][mi] = lm1; }
    __syncthreads();   // B1: wmx ready; prior pL reads done
    float cm0 = wmx[0][0][mi], cm1 = wmx[0][1][mi];
#pragma unroll
    for (int w = 1; w < 8; ++w) {
      cm0 = fmaxf(cm0, wmx[w][0][mi]);
      cm1 = fmaxf(cm1, wmx[w][1][mi]);
    }
    float mn0 = fmaxf(mr0, cm0), mn1 = fmaxf(mr1, cm1);
    float rs0 = __expf(mr0 - mn0), rs1 = __expf(mr1 - mn1);
#pragma unroll
    for (int r = 0; r < 4; ++r) { acc[0][r] *= rs0; acc[1][r] *= rs1; }
    float p00[4], p10[4], p01[4], p11[4];
    float ls0 = 0.f, ls1 = 0.f;
#pragma unroll
    for (int j = 0; j < 4; ++j) {
      p00[j] = __expf(e00[j] - mn0); p10[j] = __expf(e10[j] - mn0);
      p01[j] = __expf(e01[j] - mn1); p11[j] = __expf(e11[j] - mn1);
      ls0 += p00[j] + p10[j];
      ls1 += p01[j] + p11[j];
    }
    ssum0 = ssum0 * rs0 + ls0;
    ssum1 = ssum1 * rs1 + ls1;
    mr0 = mn0; mr1 = mn1;
    u16* prow0 = pL + mi * PSTR + wave * 32 + quad * 4;
    u16* prow1 = pL + (16 + mi) * PSTR + wave * 32 + quad * 4;
    U16x4 p;
    p.x = f2bf(p00[0]); p.y = f2bf(p00[1]); p.z = f2bf(p00[2]); p.w = f2bf(p00[3]);
    *(U16x4*)(prow0) = p;
    p.x = f2bf(p10[0]); p.y = f2bf(p10[1]); p.z = f2bf(p10[2]); p.w = f2bf(p10[3]);
    *(U16x4*)(prow0 + 16) = p;
    p.x = f2bf(p01[0]); p.y = f2bf(p01[1]); p.z = f2bf(p01[2]); p.w = f2bf(p01[3]);
    *(U16x4*)(prow1) = p;
    p.x = f2bf(p11[0]); p.y = f2bf(p11[1]); p.z = f2bf(p11[2]); p.w = f2bf(p11[3]);
    *(U16x4*)(prow1 + 16) = p;
    __syncthreads();   // B2: pL ready
#pragma unroll
    for (int ksl = 0; ksl < 8; ++ksl) {
      const u16* pb0 = pL + mi * PSTR + ksl * 32 + quad * 8;
      short8 b0 = *(const short8*)(pb0);
      short8 b1 = *(const short8*)(pb0 + 16 * PSTR);
      acc[0] = __builtin_amdgcn_mfma_f32_16x16x32_bf16(vreg[ksl], b0, acc[0], 0, 0, 0);
      acc[1] = __builtin_amdgcn_mfma_f32_16x16x32_bf16(vreg[ksl], b1, acc[1], 0, 0, 0);
    }
    a0c = a0n; a1c = a1n;
  }
  ssum0 += __shfl_xor(ssum0, 16); ssum0 += __shfl_xor(ssum0, 32);
  ssum1 += __shfl_xor(ssum1, 16); ssum1 += __shfl_xor(ssum1, 32);
  if (quad == 0) { wsm[wave][0][mi] = ssum0; wsm[wave][1][mi] = ssum1; }
  __syncthreads();
  if (t < 16) {
    float sA = 0.f, sB = 0.f;
#pragma unroll
    for (int w = 0; w < 8; ++w) { sA += wsm[w][0][t]; sB += wsm[w][1][t]; }
    size_t base = ((size_t)(mq * 2 + b) << 12) + n0;
    psum[base + t] = sA;
    psum[base + 16 + t] = sB;
    pmax[base + t] = mr0;
    pmax[base + 16 + t] = mr1;
  }
  float* dst = pvpart + (((size_t)(mq * 2 + b) * 128) << 12);
#pragma unroll
  for (int nh = 0; nh < 2; ++nh)
#pragma unroll
    for (int r = 0; r < 4; ++r) {
      int c = c0 + quad * 4 + r;
      dst[((size_t)c << 12) + n0 + nh * 16 + mi] = acc[nh][r];
    }
}

// ---------------- K6a: CAM Gram energy via MFMA, split-bf16 ------------------
__global__ __launch_bounds__(512) void k_cam_energy_m(
    const u16* __restrict__ sc16h, const u16* __restrict__ sc16l,
    float* __restrict__ epart) {
  int t = threadIdx.x;
  int ti = blockIdx.x, kc = blockIdx.y, b = blockIdx.z;
  int lane = t & 63, wave = t >> 6;
  int mi = lane & 15, quad = lane >> 4;
  const u16* fh = sc16h + ((size_t)b << 19);
  const u16* fl = sc16l + ((size_t)b << 19);
  size_t ao = ((size_t)(ti * 16 + mi) << 12) + (kc << 9) + quad * 8;
  size_t bo = ((size_t)(wave * 16 + mi) << 12) + (kc << 9) + quad * 8;
  const u16* ah = fh + ao; const u16* al = fl + ao;
  const u16* bh = fh + bo; const u16* bl = fl + bo;
  f32x4 acc = {};
#pragma unroll
  for (int k = 0; k < 16; ++k) {
    short8 vah = *(const short8*)(ah + k * 32);
    short8 val = *(const short8*)(al + k * 32);
    short8 vbh = *(const short8*)(bh + k * 32);
    short8 vbl = *(const short8*)(bl + k * 32);
    acc = __builtin_amdgcn_mfma_f32_16x16x32_bf16(vah, vbh, acc, 0, 0, 0);
    acc = __builtin_amdgcn_mfma_f32_16x16x32_bf16(vah, vbl, acc, 0, 0, 0);
    acc = __builtin_amdgcn_mfma_f32_16x16x32_bf16(val, vbh, acc, 0, 0, 0);
  }
  float* ep = epart + (((size_t)(kc * 2 + b)) << 14);
#pragma unroll
  for (int r = 0; r < 4; ++r)
    ep[((ti * 16 + quad * 4 + r) << 7) + wave * 16 + mi] = acc[r];
}

// ---------------- K6b: CAM softmax row (reduce 8 partials) -------------------
__global__ void k_cam_softmax(const float* __restrict__ epart, float* __restrict__ attn) {
  int lane = threadIdx.x;
  int c = blockIdx.x, b = blockIdx.y;
  float e0 = 0.f, e1 = 0.f;
#pragma unroll
  for (int kc = 0; kc < 8; ++kc) {
    const float* ep = epart + (((size_t)(kc * 2 + b)) << 14) + (c << 7);
    e0 += ep[lane];
    e1 += ep[lane + 64];
  }
  float mn = fminf(e0, e1);
#pragma unroll
  for (int off = 32; off >= 1; off >>= 1) mn = fminf(mn, __shfl_xor(mn, off));
  float p0 = __expf(fminf(mn - e0, 0.f)), p1 = __expf(fminf(mn - e1, 0.f));
  float s = p0 + p1;
#pragma unroll
  for (int off = 32; off >= 1; off >>= 1) s += __shfl_xor(s, off);
  float inv = 1.f / s;
  float* a = attn + ((b * 128 + c) << 7);
  a[lane] = p0 * inv;
  a[lane + 64] = p1 * inv;
}

// ---------------- K7: CAM out + residual; c-split 16 -------------------------
// grid (16 nb, 16 cg, 2 b): 512 blocks = 2/CU.
__global__ __launch_bounds__(256) void k_cam_out(const float* __restrict__ f,
    const float* __restrict__ attn, const float* __restrict__ gamma,
    float* __restrict__ sc1) {
  __shared__ float at2[128 * 8];
  int t = threadIdx.x;
  int b = blockIdx.z, c0 = blockIdx.y * 8;
  int n = blockIdx.x * 256 + t;
  for (int idx = t; idx < 1024; idx += 256) {
    int d = idx >> 3, cc = idx & 7;
    at2[idx] = attn[((b * 128 + c0 + cc) << 7) + d];
  }
  __syncthreads();
  float acc[8] = {};
  const float* fb = f + ((size_t)b * 128 << 12) + n;
  for (int d = 0; d < 128; ++d) {
    float fv = fb[d << 12];
    const float* ap = at2 + d * 8;
#pragma unroll
    for (int cc = 0; cc < 8; ++cc) acc[cc] = fmaf(ap[cc], fv, acc[cc]);
  }
  float g = gamma[0];
#pragma unroll
  for (int cc = 0; cc < 8; ++cc) {
    size_t o = ((size_t)(b * 128 + c0 + cc) << 12) + n;
    sc1[o] = fmaf(g, acc[cc], f[o]);
  }
}

// ---------------- K8: BN+ReLU + 1x1 conv 128->512 via MFMA -------------------
// sa input = sa0 + sum_q kq*pvq (4-way online-softmax combine, gamma folded).
__global__ __launch_bounds__(256, 2) void k_bout_m(
    const float* __restrict__ sa0, const float* __restrict__ pvpart,
    const float* __restrict__ pmax, const float* __restrict__ psum,
    const float* __restrict__ gamma,
    const float* __restrict__ sc1,
    const float* __restrict__ wa_, const float* __restrict__ ba_,
    const float* __restrict__ ma_, const float* __restrict__ va_,
    const float* __restrict__ wc_, const float* __restrict__ bc_,
    const float* __restrict__ mc_, const float* __restrict__ vc_,
    const u16* __restrict__ W1b, const float* __restrict__ Ba,
    const float* __restrict__ Bc,
    u16* __restrict__ sa2, u16* __restrict__ sc2) {
  __shared__ u16 xl[32 * 136];
  __shared__ float scl[128], shf[128];
  int t = threadIdx.x;
  int n0 = blockIdx.x * 32;
  int b = blockIdx.y, br = blockIdx.z;
  const float* bw = br ? wc_ : wa_;
  const float* bb = br ? bc_ : ba_;
  const float* bm = br ? mc_ : ma_;
  const float* bvv = br ? vc_ : va_;
  if (t < 128) {
    float s = bw[t] * rsqrtf(bvv[t] + 1e-5f);
    scl[t] = s;
    shf[t] = bb[t] - bm[t] * s;
  }
  __syncthreads();
  {
    int nl = t & 31, cio = t >> 5;
    const float* s0 = (br ? sc1 : sa0) + ((size_t)b * 128 << 12) + n0 + nl;
    const float* pq[4];
    float kq[4] = {};
    if (!br) {
      int n = n0 + nl;
      float m[4], s4[4];
#pragma unroll
      for (int q = 0; q < 4; ++q) {
        pq[q] = pvpart + (((size_t)(q * 2 + b) * 128) << 12) + n0 + nl;
        m[q] = pmax[((size_t)(q * 2 + b) << 12) + n];
        s4[q] = psum[((size_t)(q * 2 + b) << 12) + n];
      }
      float M = fmaxf(fmaxf(m[0], m[1]), fmaxf(m[2], m[3]));
      float den = 0.f;
#pragma unroll
      for (int q = 0; q < 4; ++q) { kq[q] = __expf(m[q] - M); den = fmaf(kq[q], s4[q], den); }
      float inv = gamma[0] / den;
#pragma unroll
      for (int q = 0; q < 4; ++q) kq[q] *= inv;
    }
#pragma unroll
    for (int half = 0; half < 2; ++half) {
      short8 v;
#pragma unroll
      for (int i = 0; i < 8; ++i) {
        int ci = cio * 16 + half * 8 + i;
        float xv = s0[(size_t)ci << 12];
        if (!br) {
          size_t po = (size_t)ci << 12;
          xv += kq[0] * pq[0][po] + kq[1] * pq[1][po]
              + kq[2] * pq[2][po] + kq[3] * pq[3][po];
        }
        v[i] = (short)f2bf(fmaxf(fmaf(xv, scl[ci], shf[ci]), 0.f));
      }
      *(short8*)(xl + nl * 136 + cio * 16 + half * 8) = v;
    }
  }
  __syncthreads();
  int lane = t & 63, wave = t >> 6;
  int mi = lane & 15, quad = lane >> 4;
  const u16* wb = W1b + (size_t)br * 65536 + lane * 8;
  f32x4 acc[8][2] = {};
#pragma unroll
  for (int ks = 0; ks < 4; ++ks) {
    short8 b0 = *(const short8*)(xl + mi * 136 + ks * 32 + quad * 8);
    short8 b1 = *(const short8*)(xl + (16 + mi) * 136 + ks * 32 + quad * 8);
#pragma unroll
    for (int ct = 0; ct < 8; ++ct) {
      int cot = wave * 8 + ct;
      short8 a = *(const short8*)(wb + ((size_t)(cot * 4 + ks) << 9));
      acc[ct][0] = __builtin_amdgcn_mfma_f32_16x16x32_bf16(a, b0, acc[ct][0], 0, 0, 0);
      acc[ct][1] = __builtin_amdgcn_mfma_f32_16x16x32_bf16(a, b1, acc[ct][1], 0, 0, 0);
    }
  }
  const float* Bs = br ? Bc : Ba;
  u16* dst = br ? sc2 : sa2;
#pragma unroll
  for (int ct = 0; ct < 8; ++ct)
#pragma unroll
    for (int nh = 0; nh < 2; ++nh)
#pragma unroll
      for (int r = 0; r < 4; ++r) {
        int co = (wave * 8 + ct) * 16 + quad * 4 + r;
        dst[((size_t)(b * 512 + co) << 12) + n0 + nh * 16 + mi] =
            f2bf(acc[ct][nh][r] + Bs[co]);
      }
}

// ---------------- K9: fusion + class heads, atomic-free; n-tile 16 -----------
// grid (256 nb, 2 b): 512 blocks = 2/CU. 16 c-chunks x 32 co.
__global__ __launch_bounds__(256) void k_heads2(const u16* __restrict__ sa2,
    const u16* __restrict__ sc2,
    const float* __restrict__ wf, const float* __restrict__ wa, const float* __restrict__ wc,
    const float* __restrict__ bfb, const float* __restrict__ bab,
    const float* __restrict__ bcb,
    float* __restrict__ outFusion, float* __restrict__ outCls) {
  __shared__ float lw[3 * 5 * 512];
  __shared__ float hs[16][15][16];
  int t = threadIdx.x;
  int b = blockIdx.y, n0 = blockIdx.x * 16;
  for (int idx = t; idx < 7680; idx += 256) {
    int arr = idx / 2560, rest = idx - arr * 2560;
    int cls = rest >> 9, co = rest & 511;
    const float* w = arr == 0 ? wf : (arr == 1 ? wa : wc);
    lw[idx] = w[cls * 512 + co];
  }
  __syncthreads();
  int nl = t & 15, ck = t >> 4;
  float acc[15] = {};
  for (int co = ck * 32; co < ck * 32 + 32; ++co) {
    size_t o = ((size_t)(b * 512 + co) << 12) + n0 + nl;
    float a = bf2f(sa2[o]), c = bf2f(sc2[o]);
    float s = a + c;
    outFusion[o] = s;
    const float* lf = lw + co;
#pragma unroll
    for (int cls = 0; cls < 5; ++cls) {
      acc[cls]      = fmaf(lf[cls * 512], s, acc[cls]);
      acc[5 + cls]  = fmaf(lf[2560 + cls * 512], a, acc[5 + cls]);
      acc[10 + cls] = fmaf(lf[5120 + cls * 512], c, acc[10 + cls]);
    }
  }
#pragma unroll
  for (int k = 0; k < 15; ++k) hs[ck][k][nl] = acc[k];
  __syncthreads();
  for (int idx = t; idx < 240; idx += 256) {
    int k = idx >> 4, nl2 = idx & 15;
    float s = 0.f;
#pragma unroll
    for (int c8 = 0; c8 < 16; ++c8) s += hs[c8][k][nl2];
    int arr = k / 5, cls = k - arr * 5;
    float bias = arr == 0 ? bfb[cls] : (arr == 1 ? bab[cls] : bcb[cls]);
    outCls[arr * 40960 + ((b * 5 + cls) << 12) + n0 + nl2] = s + bias;
  }
}

extern "C" void kernel_launch(void* const* d_in, const int* in_sizes, int n_in,
                              void* d_out, int out_size, void* d_ws, size_t ws_size,
                              hipStream_t stream) {
  (void)in_sizes; (void)n_in; (void)out_size; (void)ws_size;
  const float* x      = (const float*)d_in[0];
  const float* bnaw   = (const float*)d_in[1];
  const float* bnab   = (const float*)d_in[2];
  const float* bnam   = (const float*)d_in[3];
  const float* bnav   = (const float*)d_in[4];
  const float* convaw = (const float*)d_in[5];
  const float* bncw   = (const float*)d_in[6];
  const float* bncb   = (const float*)d_in[7];
  const float* bncm   = (const float*)d_in[8];
  const float* bncv   = (const float*)d_in[9];
  const float* convcw = (const float*)d_in[10];
  const float* pqw    = (const float*)d_in[11];
  const float* pqb    = (const float*)d_in[12];
  const float* pkw    = (const float*)d_in[13];
  const float* pkb    = (const float*)d_in[14];
  const float* pvw    = (const float*)d_in[15];
  const float* pvb    = (const float*)d_in[16];
  const float* pgam   = (const float*)d_in[17];
  const float* cgam   = (const float*)d_in[18];
  const float* bna1w  = (const float*)d_in[19];
  const float* bna1b  = (const float*)d_in[20];
  const float* bna1m  = (const float*)d_in[21];
  const float* bna1v  = (const float*)d_in[22];
  const float* conva1w = (const float*)d_in[23];
  const float* conva1b = (const float*)d_in[24];
  const float* bnc1w  = (const float*)d_in[25];
  const float* bnc1b  = (const float*)d_in[26];
  const float* bnc1m  = (const float*)d_in[27];
  const float* bnc1v  = (const float*)d_in[28];
  const float* convc1w = (const float*)d_in[29];
  const float* convc1b = (const float*)d_in[30];
  const float* outaw  = (const float*)d_in[31];
  const float* outab  = (const float*)d_in[32];
  const float* outcw  = (const float*)d_in[33];
  const float* outcb  = (const float*)d_in[34];
  const float* outfw  = (const float*)d_in[35];
  const float* outfb  = (const float*)d_in[36];

  char* wsb = (char*)d_ws;
  size_t off = 0;
  auto take = [&](size_t bytes) -> void* {
    void* p = wsb + off;
    off += (bytes + 255) & ~(size_t)255;
    return p;
  };
  u16*   Wb    = (u16*)take((size_t)2 * 128 * 9 * 512 * 2);
  u16*   W1b   = (u16*)take((size_t)2 * 512 * 128 * 2);
  u16*   Wqkvb = (u16*)take((size_t)160 * 128 * 2);
  u16*   xa16  = (u16*)take((size_t)2 * 512 * 4096 * 2);
  u16*   xcb16 = (u16*)take((size_t)2 * 512 * 4096 * 2);
  float* sa0   = (float*)take((size_t)2 * 128 * 4096 * 4);
  float* sc0   = (float*)take((size_t)2 * 128 * 4096 * 4);
  u16*   sa_nhwc = (u16*)take((size_t)2 * 4096 * 128 * 2);
  u16*   sc16h = (u16*)take((size_t)2 * 128 * 4096 * 2);
  u16*   sc16l = (u16*)take((size_t)2 * 128 * 4096 * 2);
  float* qb    = (float*)take((size_t)2 * 16 * 4096 * 4);
  u16*   k16t  = (u16*)take((size_t)2 * 4096 * 32 * 2);
  u16*   vt16  = (u16*)take((size_t)2 * 128 * 4096 * 2);
  float* pvpart = (float*)take((size_t)4 * 2 * 128 * 4096 * 4);
  float* pmax  = (float*)take((size_t)4 * 2 * 4096 * 4);
  float* psum  = (float*)take((size_t)4 * 2 * 4096 * 4);
  float* sc1   = (float*)take((size_t)2 * 128 * 4096 * 4);
  float* epart = (float*)take((size_t)8 * 2 * 128 * 128 * 4);
  float* attn  = (float*)take((size_t)2 * 128 * 128 * 4);
  u16*   sa2   = (u16*)take((size_t)2 * 512 * 4096 * 2);
  u16*   sc2   = (u16*)take((size_t)2 * 512 * 4096 * 2);

  float* outF = (float*)d_out;
  float* outCls = outF + (size_t)2 * 512 * 4096;

  k_prep_w<<<4608, 256, 0, stream>>>(convaw, convcw, Wb);
  k_prep_w1<<<512, 256, 0, stream>>>(conva1w, convc1w, W1b);
  k_prep_wqkv<<<80, 256, 0, stream>>>(pqw, pkw, pvw, Wqkvb);
  k_bnrelu2t<<<dim3(64, 2, 4), 256, 0, stream>>>(x, bnaw, bnab, bnam, bnav,
                                                 bncw, bncb, bncm, bncv, xa16, xcb16);
  k_conv3n<<<dim3(64, 4, 2), 256, 0, stream>>>(xa16, xcb16, Wb, sa0, sc0,
                                               sa_nhwc, sc16h, sc16l);
  k_qkv<<<dim3(32, 2), 256, 0, stream>>>(sa_nhwc, Wqkvb, pqb, pkb, pvb,
                                         qb, k16t, vt16);
  k_pam_pv<<<dim3(128, 2, 4), 512, 0, stream>>>(qb, k16t, vt16, pvpart, pmax, psum);
  k_cam_energy_m<<<dim3(8, 8, 2), 512, 0, stream>>>(sc16h, sc16l, epart);
  k_cam_softmax<<<dim3(128, 2), 64, 0, stream>>>(epart, attn);
  k_cam_out<<<dim3(16, 16, 2), 256, 0, stream>>>(sc0, attn, cgam, sc1);
  k_bout_m<<<dim3(128, 2, 2), 256, 0, stream>>>(sa0, pvpart, pmax, psum, pgam, sc1,
      bna1w, bna1b, bna1m, bna1v, bnc1w, bnc1b, bnc1m, bnc1v,
      W1b, conva1b, convc1b, sa2, sc2);
  k_heads2<<<dim3(256, 2), 256, 0, stream>>>(sa2, sc2, outfw, outaw, outcw,
                                             outfb, outab, outcb, outF, outCls);
}